// Round 11
// baseline (167.477 us; speedup 1.0000x reference)
//
#include <hip/hip_runtime.h>
#include <hip/hip_bf16.h>
#include <math.h>

#define BB 2
#define LL 1024
#define DMODEL 1024
#define DINNER 2048
#define NH 16
#define HD 128
#define NS 64
#define CONVDIM 2176
#define DINPROJ 4240
#define QC 64
#define NCH 16
#define LSTR 72   // LDS row stride in ushorts (144 B) -> conflict-free b128 frag reads

typedef short bf16x8 __attribute__((ext_vector_type(8)));
typedef float f32x4 __attribute__((ext_vector_type(4)));

__device__ __forceinline__ unsigned int bfpair(float lo, float hi) {
  unsigned int a = __float_as_uint(lo); a = (a + 0x7fffu + ((a >> 16) & 1u)) >> 16;
  unsigned int b = __float_as_uint(hi); b = (b + 0x7fffu + ((b >> 16) & 1u)) >> 16;
  return a | (b << 16);
}
__device__ __forceinline__ ushort bf1(float f) {
  unsigned int u = __float_as_uint(f);
  return (ushort)((u + 0x7fffu + ((u >> 16) & 1u)) >> 16);
}
__device__ __forceinline__ uint4 pack8(const float* v) {
  return make_uint4(bfpair(v[0], v[1]), bfpair(v[2], v[3]), bfpair(v[4], v[5]), bfpair(v[6], v[7]));
}

// ---- pack helper: fp32 [R][C] row-major -> bf16 tiles [128 rows][32 k], swizzled LDS image ----
__device__ __forceinline__ void pack_tiles(const float* __restrict__ src,
                                           ushort* __restrict__ dst,
                                           int id, int C) {
  const int KT = C >> 5;
  const int tile = id >> 9;
  const int g = id & 511;
  const int r = g >> 2, s = g & 3;
  const int h = (s ^ (r >> 1)) & 3;
  const int tm = tile / KT, tk = tile - tm * KT;
  const int row = tm * 128 + r;
  const int k = tk * 32 + h * 8;
  const float4 a = *(const float4*)(src + (size_t)row * C + k);
  const float4 b = *(const float4*)(src + (size_t)row * C + k + 4);
  uint4 pk;
  pk.x = bfpair(a.x, a.y); pk.y = bfpair(a.z, a.w);
  pk.z = bfpair(b.x, b.y); pk.w = bfpair(b.z, b.w);
  *(uint4*)(dst + (size_t)id * 8) = pk;
}

// ---- phase-1 prep: pack hs, W_in, W_out + dt GEMV, branched on blockIdx ----
#define PREP_HS 1024
#define PREP_WIN 2112
#define PREP_WOUT 1024
__global__ __launch_bounds__(256) void prep_kernel(const float* __restrict__ hs,
                                                   const float* __restrict__ W_in,
                                                   const float* __restrict__ W_out,
                                                   const float* __restrict__ dt_bias,
                                                   ushort* __restrict__ hsP,
                                                   ushort* __restrict__ WinP,
                                                   ushort* __restrict__ WoutP,
                                                   float* __restrict__ dtv) {
  __shared__ float hl[1024];
  __shared__ float part[256];
  const int blk = blockIdx.x;
  const int t = threadIdx.x;
  if (blk < PREP_HS) {
    pack_tiles(hs, hsP, blk * 256 + t, 1024);
  } else if (blk < PREP_HS + PREP_WIN) {
    pack_tiles(W_in, WinP, (blk - PREP_HS) * 256 + t, 1024);
  } else if (blk < PREP_HS + PREP_WIN + PREP_WOUT) {
    pack_tiles(W_out, WoutP, (blk - PREP_HS - PREP_WIN) * 256 + t, 2048);
  } else {
    const int bl = blk - (PREP_HS + PREP_WIN + PREP_WOUT);
    *(float4*)(hl + t * 4) = *(const float4*)(hs + (size_t)bl * 1024 + t * 4);
    __syncthreads();
    const int h = t & 15, ks = t >> 4;
    const float* wrow = W_in + (size_t)(DINNER + CONVDIM + h) * 1024 + ks * 64;
    const float* xs = hl + ks * 64;
    float p = 0.f;
#pragma unroll
    for (int j = 0; j < 64; j += 4) {
      const float4 wv = *(const float4*)(wrow + j);
      const float4 xv = *(const float4*)(xs + j);
      p += wv.x * xv.x + wv.y * xv.y + wv.z * xv.z + wv.w * xv.w;
    }
    part[t] = p;
    __syncthreads();
    if (t < 16) {
      float sum = 0.f;
#pragma unroll
      for (int j = 0; j < 16; ++j) sum += part[t + 16 * j];
      const float x = sum + dt_bias[t];
      dtv[bl * 16 + t] = (x > 20.f) ? x : log1pf(expf(x));
    }
  }
}

// ---- bf16 MFMA GEMM, 128x128 tile, BK=64 (2 k-tiles per stage), optional split-K ----
__global__ __launch_bounds__(256) void mfma_gemm(const ushort* __restrict__ Ap,
                                                 const ushort* __restrict__ Bp,
                                                 float* __restrict__ C,
                                                 int ldC, int KtTot, int Kt2l,
                                                 size_t partStride) {
  __shared__ ushort lds[2][2][8192];   // [buf][A/B][2 x 8KB tiles] = 64 KB
  const int tid = threadIdx.x;
  const int w = tid >> 6, lane = tid & 63;
  const int wr = w >> 1, wc = w & 1;
  const int l15 = lane & 15, lg = lane >> 4;
  const int bm = blockIdx.y * 128, bn = blockIdx.x * 128;
  const ushort* At = Ap + (size_t)blockIdx.y * KtTot * 4096 + (size_t)blockIdx.z * Kt2l * 8192;
  const ushort* Bt = Bp + (size_t)blockIdx.x * KtTot * 4096 + (size_t)blockIdx.z * Kt2l * 8192;
  float* Cz = C + (size_t)blockIdx.z * partStride;

  int offA[4], offB[4];   // byte offsets within an 8KB tile
#pragma unroll
  for (int i = 0; i < 4; ++i) {
    const int r = wr * 64 + i * 16 + l15;
    offA[i] = r * 64 + (((lg ^ (r >> 1)) & 3) << 4);
    const int c = wc * 64 + i * 16 + l15;
    offB[i] = c * 64 + (((lg ^ (c >> 1)) & 3) << 4);
  }
  f32x4 acc[4][4] = {};

#define STAGE(buf, kt2)                                                                  \
  do {                                                                                   \
    const char* ga_ = (const char*)(At + (size_t)(kt2) * 8192);                          \
    const char* gb_ = (const char*)(Bt + (size_t)(kt2) * 8192);                          \
    char* la_ = (char*)&lds[buf][0][0];                                                  \
    char* lb_ = (char*)&lds[buf][1][0];                                                  \
    _Pragma("unroll")                                                                    \
    for (int q = 0; q < 4; ++q) {                                                        \
      __builtin_amdgcn_global_load_lds(                                                  \
          (const __attribute__((address_space(1))) void*)(ga_ + q * 4096 + tid * 16),    \
          (__attribute__((address_space(3))) void*)(la_ + q * 4096 + (w << 10)), 16, 0, 0); \
      __builtin_amdgcn_global_load_lds(                                                  \
          (const __attribute__((address_space(1))) void*)(gb_ + q * 4096 + tid * 16),    \
          (__attribute__((address_space(3))) void*)(lb_ + q * 4096 + (w << 10)), 16, 0, 0); \
    }                                                                                    \
  } while (0)

  STAGE(0, 0);
  __syncthreads();
  int cur = 0;
  for (int kt2 = 0; kt2 < Kt2l; ++kt2) {
    if (kt2 + 1 < Kt2l) STAGE(cur ^ 1, kt2 + 1);
#pragma unroll
    for (int kk = 0; kk < 2; ++kk) {
      bf16x8 af[4], bfr[4];
#pragma unroll
      for (int i = 0; i < 4; ++i)
        af[i] = *(const bf16x8*)((const char*)&lds[cur][0][0] + kk * 8192 + offA[i]);
#pragma unroll
      for (int i = 0; i < 4; ++i)
        bfr[i] = *(const bf16x8*)((const char*)&lds[cur][1][0] + kk * 8192 + offB[i]);
#pragma unroll
      for (int mi = 0; mi < 4; ++mi)
#pragma unroll
        for (int ni = 0; ni < 4; ++ni)
          acc[mi][ni] = __builtin_amdgcn_mfma_f32_16x16x32_bf16(af[mi], bfr[ni], acc[mi][ni], 0, 0, 0);
    }
    __syncthreads();
    cur ^= 1;
  }
#undef STAGE

#pragma unroll
  for (int mi = 0; mi < 4; ++mi) {
    const int row0 = bm + wr * 64 + mi * 16 + lg * 4;
#pragma unroll
    for (int ni = 0; ni < 4; ++ni) {
      const int col = bn + wc * 64 + ni * 16 + l15;
      float* cp = Cz + (size_t)row0 * ldC + col;
      cp[0] = acc[mi][ni][0];
      cp[(size_t)ldC] = acc[mi][ni][1];
      cp[(size_t)2 * ldC] = acc[mi][ni][2];
      cp[(size_t)3 * ldC] = acc[mi][ni][3];
    }
  }
}

// ---- sum 4 split-K partials -> out ----
__global__ __launch_bounds__(256) void reduce4(const float* __restrict__ P,
                                               float* __restrict__ out) {
  const size_t i = ((size_t)blockIdx.x * 256 + threadIdx.x) * 4;
  const size_t st = (size_t)DMODEL * BB * LL;
  float4 a = *(const float4*)(P + i);
  const float4 b = *(const float4*)(P + st + i);
  const float4 c = *(const float4*)(P + 2 * st + i);
  const float4 d = *(const float4*)(P + 3 * st + i);
  a.x += b.x + c.x + d.x;
  a.y += b.y + c.y + d.y;
  a.z += b.z + c.z + d.z;
  a.w += b.w + c.w + d.w;
  *(float4*)(out + i) = a;
}

// ---- causal depthwise conv(4)+SiLU (+ merged cumlog tail blocks) ----
#define CONV_BLKS ((BB * LL * CONVDIM + 255) / 256)
__global__ __launch_bounds__(256) void conv_cumlog(const float* __restrict__ zx,
                                                   const float* __restrict__ conv_w,
                                                   const float* __restrict__ conv_b,
                                                   float* __restrict__ xy,
                                                   float* __restrict__ Bm,
                                                   float* __restrict__ Cm,
                                                   const float* __restrict__ dtv,
                                                   const float* __restrict__ A_log,
                                                   float* __restrict__ clog) {
  const int blk = blockIdx.x;
  if (blk >= CONV_BLKS) {
    const int idx = (blk - CONV_BLKS) * 256 + threadIdx.x;
    if (idx >= BB * NH * NCH) return;
    const int c = idx & (NCH - 1);
    const int bh = idx >> 4;
    const int b = bh >> 4, h = bh & (NH - 1);
    const float A = -__expf(A_log[h]);
    float run = 0.f;
    for (int i = 0; i < QC; ++i) {
      run += A * dtv[(size_t)(b * LL + c * QC + i) * NH + h];
      clog[(size_t)bh * LL + c * QC + i] = run;
    }
    return;
  }
  const int idx = blk * 256 + threadIdx.x;
  const int c = idx % CONVDIM;
  const int bl = idx / CONVDIM;
  const int l = bl & (LL - 1);
  const float w0 = conv_w[c * 4 + 0], w1 = conv_w[c * 4 + 1];
  const float w2 = conv_w[c * 4 + 2], w3 = conv_w[c * 4 + 3];
  const float* base = zx + (size_t)bl * DINPROJ + DINNER + c;
  float acc = conv_b[c];
  acc = fmaf(base[0], w3, acc);
  if (l >= 1) acc = fmaf(base[-1 * DINPROJ], w2, acc);
  if (l >= 2) acc = fmaf(base[-2 * DINPROJ], w1, acc);
  if (l >= 3) acc = fmaf(base[-3 * DINPROJ], w0, acc);
  const float s = acc / (1.f + expf(-acc));
  if (c < DINNER)                    xy[(size_t)bl * DINNER + c] = s;
  else if (c < DINNER + NS)          Bm[bl * NS + (c - DINNER)] = s;
  else                               Cm[bl * NS + (c - DINNER - NS)] = s;
}

// ---- SSD intra-chunk via bf16 MFMA ----
__global__ __launch_bounds__(256) void ssd_intra(const float* __restrict__ xy,
                                                 const float* __restrict__ Bm,
                                                 const float* __restrict__ Cm,
                                                 const float* __restrict__ dtv,
                                                 const float* __restrict__ clog,
                                                 float* __restrict__ zx,
                                                 float* __restrict__ S) {
  __shared__ __align__(16) ushort sC[64 * LSTR];
  __shared__ __align__(16) ushort sB[64 * LSTR];
  __shared__ __align__(16) ushort sBT[64 * LSTR];
  __shared__ __align__(16) ushort sXT[128 * LSTR];
  __shared__ __align__(16) ushort sP[64 * LSTR];
  __shared__ float scl[QC], sdt[QC], swdt[QC];
  const int blk = blockIdx.x;
  const int bh = blk >> 4, c = blk & (NCH - 1);
  const int b = bh >> 4, h = bh & (NH - 1);
  const int t0 = c * QC;
  const int tid = threadIdx.x;
  const int w = tid >> 6, lane = tid & 63, l15 = lane & 15, lg = lane >> 4;

  if (tid < QC) {
    const float cl = clog[(size_t)bh * LL + t0 + tid];
    const float clend = clog[(size_t)bh * LL + t0 + QC - 1];
    const float dt = dtv[(size_t)(b * LL + t0 + tid) * NH + h];
    scl[tid] = cl; sdt[tid] = dt;
    swdt[tid] = __expf(clend - cl) * dt;
  }
  __syncthreads();

  const float* Bg = Bm + (size_t)(b * LL + t0) * NS;
  const float* Cg = Cm + (size_t)(b * LL + t0) * NS;
#pragma unroll
  for (int j = 0; j < 4; ++j) {
    const int f = j * 256 + tid;
    const int r = f >> 4, c4 = f & 15;
    const float4 bv = *(const float4*)(Bg + r * NS + c4 * 4);
    const float4 cv = *(const float4*)(Cg + r * NS + c4 * 4);
    *(uint2*)(sB + r * LSTR + c4 * 4) = make_uint2(bfpair(bv.x, bv.y), bfpair(bv.z, bv.w));
    *(uint2*)(sC + r * LSTR + c4 * 4) = make_uint2(bfpair(cv.x, cv.y), bfpair(cv.z, cv.w));
  }
  {
    const int n = tid & 63, sg = tid >> 6;
    float bw[16];
#pragma unroll
    for (int j = 0; j < 16; ++j) {
      const int s = sg * 16 + j;
      bw[j] = swdt[s] * Bg[(size_t)s * NS + n];
    }
    *(uint4*)(sBT + n * LSTR + sg * 16) = pack8(bw);
    *(uint4*)(sBT + n * LSTR + sg * 16 + 8) = pack8(bw + 8);
  }
  {
    const int p = tid & 127, sh = tid >> 7;
    const float* xg = xy + (size_t)(b * LL + t0 + sh * 32) * DINNER + h * HD + p;
    float xv[32];
#pragma unroll
    for (int j = 0; j < 32; ++j) xv[j] = xg[(size_t)j * DINNER];
#pragma unroll
    for (int q = 0; q < 4; ++q)
      *(uint4*)(sXT + p * LSTR + sh * 32 + q * 8) = pack8(xv + q * 8);
  }
  __syncthreads();

  f32x4 g[4] = {};
#pragma unroll
  for (int ks = 0; ks < 2; ++ks) {
    const bf16x8 ca = *(const bf16x8*)((const char*)sC + (w * 16 + l15) * 144 + ks * 64 + lg * 16);
#pragma unroll
    for (int ni = 0; ni < 4; ++ni) {
      const bf16x8 bb = *(const bf16x8*)((const char*)sB + (ni * 16 + l15) * 144 + ks * 64 + lg * 16);
      g[ni] = __builtin_amdgcn_mfma_f32_16x16x32_bf16(ca, bb, g[ni], 0, 0, 0);
    }
  }
#pragma unroll
  for (int ni = 0; ni < 4; ++ni) {
    const int s = ni * 16 + l15;
    const float cls = scl[s], dts = sdt[s];
#pragma unroll
    for (int j = 0; j < 4; ++j) {
      const int t = w * 16 + lg * 4 + j;
      const float v = (s <= t) ? g[ni][j] * __expf(scl[t] - cls) * dts : 0.f;
      sP[t * LSTR + s] = bf1(v);
    }
  }
  f32x4 sa[2][4] = {};
#pragma unroll
  for (int ks = 0; ks < 2; ++ks) {
    const bf16x8 a0 = *(const bf16x8*)((const char*)sXT + (w * 32 + l15) * 144 + ks * 64 + lg * 16);
    const bf16x8 a1 = *(const bf16x8*)((const char*)sXT + (w * 32 + 16 + l15) * 144 + ks * 64 + lg * 16);
#pragma unroll
    for (int nj = 0; nj < 4; ++nj) {
      const bf16x8 bb = *(const bf16x8*)((const char*)sBT + (nj * 16 + l15) * 144 + ks * 64 + lg * 16);
      sa[0][nj] = __builtin_amdgcn_mfma_f32_16x16x32_bf16(a0, bb, sa[0][nj], 0, 0, 0);
      sa[1][nj] = __builtin_amdgcn_mfma_f32_16x16x32_bf16(a1, bb, sa[1][nj], 0, 0, 0);
    }
  }
  float* Sg = S + (size_t)blk * (HD * NS);
#pragma unroll
  for (int mi = 0; mi < 2; ++mi)
#pragma unroll
    for (int nj = 0; nj < 4; ++nj)
#pragma unroll
      for (int j = 0; j < 4; ++j)
        Sg[(size_t)(w * 32 + mi * 16 + lg * 4 + j) * NS + nj * 16 + l15] = sa[mi][nj][j];
  __syncthreads();

  f32x4 y[8] = {};
#pragma unroll
  for (int ks = 0; ks < 2; ++ks) {
    const bf16x8 pa = *(const bf16x8*)((const char*)sP + (w * 16 + l15) * 144 + ks * 64 + lg * 16);
#pragma unroll
    for (int ni = 0; ni < 8; ++ni) {
      const bf16x8 xb = *(const bf16x8*)((const char*)sXT + (ni * 16 + l15) * 144 + ks * 64 + lg * 16);
      y[ni] = __builtin_amdgcn_mfma_f32_16x16x32_bf16(pa, xb, y[ni], 0, 0, 0);
    }
  }
  float* yg = zx + (size_t)(b * LL + t0) * DINPROJ + DINNER + h * HD;
#pragma unroll
  for (int ni = 0; ni < 8; ++ni)
#pragma unroll
    for (int j = 0; j < 4; ++j)
      yg[(size_t)(w * 16 + lg * 4 + j) * DINPROJ + ni * 16 + l15] = y[ni][j];
}

// ---- inter-chunk scan over chunk states ----
__global__ __launch_bounds__(256) void ssd_scan(float* __restrict__ S,
                                                const float* __restrict__ clog) {
  const int idx = blockIdx.x * 256 + threadIdx.x;
  const int pn = idx & (HD * NS - 1);
  const int bh = idx >> 13;
  float* Sp = S + (size_t)bh * NCH * (HD * NS) + pn;
  const float* cl = clog + (size_t)bh * LL;
  float H = 0.f;
#pragma unroll
  for (int c = 0; c < NCH; ++c) {
    const float dec = __expf(cl[c * QC + QC - 1]);
    const float s = Sp[(size_t)c * (HD * NS)];
    Sp[(size_t)c * (HD * NS)] = H;
    H = dec * H + s;
  }
}

// ---- y = y_intra + exp(cl)*C.H^T + D*x (bf16 MFMA, in place on xy) ----
__global__ __launch_bounds__(256) void ssd_out(float* __restrict__ xy,
                                               const float* __restrict__ zx,
                                               const float* __restrict__ Cm,
                                               const float* __restrict__ clog,
                                               const float* __restrict__ S,
                                               const float* __restrict__ Dp_) {
  __shared__ __align__(16) ushort sC[64 * LSTR];
  __shared__ __align__(16) ushort sH[128 * LSTR];
  __shared__ float sE[QC];
  const int blk = blockIdx.x;
  const int bh = blk >> 4, c = blk & (NCH - 1);
  const int b = bh >> 4, h = bh & (NH - 1);
  const int t0 = c * QC;
  const int tid = threadIdx.x;
  const int w = tid >> 6, lane = tid & 63, l15 = lane & 15, lg = lane >> 4;

  if (tid < QC) sE[tid] = __expf(clog[(size_t)bh * LL + t0 + tid]);
  const float* Cg = Cm + (size_t)(b * LL + t0) * NS;
#pragma unroll
  for (int j = 0; j < 4; ++j) {
    const int f = j * 256 + tid, r = f >> 4, c4 = f & 15;
    const float4 cv = *(const float4*)(Cg + r * NS + c4 * 4);
    *(uint2*)(sC + r * LSTR + c4 * 4) = make_uint2(bfpair(cv.x, cv.y), bfpair(cv.z, cv.w));
  }
  const float* Hg = S + (size_t)blk * (HD * NS);
#pragma unroll
  for (int j = 0; j < 8; ++j) {
    const int f = j * 256 + tid, p = f >> 4, n4 = f & 15;
    const float4 hv = *(const float4*)(Hg + (size_t)p * NS + n4 * 4);
    *(uint2*)(sH + p * LSTR + n4 * 4) = make_uint2(bfpair(hv.x, hv.y), bfpair(hv.z, hv.w));
  }
  __syncthreads();

  f32x4 y2[8] = {};
#pragma unroll
  for (int ks = 0; ks < 2; ++ks) {
    const bf16x8 ca = *(const bf16x8*)((const char*)sC + (w * 16 + l15) * 144 + ks * 64 + lg * 16);
#pragma unroll
    for (int ni = 0; ni < 8; ++ni) {
      const bf16x8 hb = *(const bf16x8*)((const char*)sH + (ni * 16 + l15) * 144 + ks * 64 + lg * 16);
      y2[ni] = __builtin_amdgcn_mfma_f32_16x16x32_bf16(ca, hb, y2[ni], 0, 0, 0);
    }
  }
  const float Dv = Dp_[h];
#pragma unroll
  for (int ni = 0; ni < 8; ++ni) {
    const int p = ni * 16 + l15;
#pragma unroll
    for (int j = 0; j < 4; ++j) {
      const int t = w * 16 + lg * 4 + j;
      const size_t row = (size_t)(b * LL + t0 + t);
      const float yi = zx[row * DINPROJ + DINNER + h * HD + p];
      float* xp = xy + row * DINNER + h * HD + p;
      *xp = yi + sE[t] * y2[ni][j] + Dv * (*xp);
    }
  }
}

// ---- y *= silu(z); RMSNorm; emit packed bf16 128-row tiles for out-proj ----
__global__ __launch_bounds__(256) void gate_norm_pack(const float* __restrict__ xy,
                                                      const float* __restrict__ zx,
                                                      const float* __restrict__ nw,
                                                      ushort* __restrict__ yP) {
  __shared__ float red[4];
  const int m = blockIdx.x;
  const int t = threadIdx.x;
  const float* yrow = xy + (size_t)m * DINNER;
  const float* zrow = zx + (size_t)m * DINPROJ;
  const int e = t * 8;
  const float4 y0 = *(const float4*)(yrow + e), y1 = *(const float4*)(yrow + e + 4);
  const float4 z0 = *(const float4*)(zrow + e), z1 = *(const float4*)(zrow + e + 4);
  float v[8];
  v[0] = y0.x * (z0.x / (1.f + expf(-z0.x)));
  v[1] = y0.y * (z0.y / (1.f + expf(-z0.y)));
  v[2] = y0.z * (z0.z / (1.f + expf(-z0.z)));
  v[3] = y0.w * (z0.w / (1.f + expf(-z0.w)));
  v[4] = y1.x * (z1.x / (1.f + expf(-z1.x)));
  v[5] = y1.y * (z1.y / (1.f + expf(-z1.y)));
  v[6] = y1.z * (z1.z / (1.f + expf(-z1.z)));
  v[7] = y1.w * (z1.w / (1.f + expf(-z1.w)));
  float ss = 0.f;
#pragma unroll
  for (int j = 0; j < 8; ++j) ss += v[j] * v[j];
#pragma unroll
  for (int off = 32; off; off >>= 1) ss += __shfl_down(ss, off);
  const int lane = t & 63, wid = t >> 6;
  if (lane == 0) red[wid] = ss;
  __syncthreads();
  const float tot = red[0] + red[1] + red[2] + red[3];
  const float rstd = rsqrtf(tot * (1.f / DINNER) + 1e-5f);
  const float4 w0 = *(const float4*)(nw + e), w1 = *(const float4*)(nw + e + 4);
  v[0] *= rstd * w0.x; v[1] *= rstd * w0.y; v[2] *= rstd * w0.z; v[3] *= rstd * w0.w;
  v[4] *= rstd * w1.x; v[5] *= rstd * w1.y; v[6] *= rstd * w1.z; v[7] *= rstd * w1.w;
  // 128-row tile pack: tile (m>>7)*64 + (t>>2), row r=m&127, slot s=(t^(r>>1))&3
  const int r = m & 127;
  const int tk = t >> 2;
  const int s = (t ^ (r >> 1)) & 3;
  uint4 pk;
  pk.x = bfpair(v[0], v[1]); pk.y = bfpair(v[2], v[3]);
  pk.z = bfpair(v[4], v[5]); pk.w = bfpair(v[6], v[7]);
  *(uint4*)(yP + (size_t)((m >> 7) * 64 + tk) * 4096 + r * 32 + s * 8) = pk;
}

extern "C" void kernel_launch(void* const* d_in, const int* in_sizes, int n_in,
                              void* d_out, int out_size, void* d_ws, size_t ws_size,
                              hipStream_t stream) {
  const float* hs      = (const float*)d_in[0];
  const float* W_in    = (const float*)d_in[1];
  const float* conv_w  = (const float*)d_in[2];
  const float* conv_b  = (const float*)d_in[3];
  const float* dt_bias = (const float*)d_in[4];
  const float* A_log   = (const float*)d_in[5];
  const float* D_param = (const float*)d_in[6];
  const float* norm_w  = (const float*)d_in[7];
  const float* W_out   = (const float*)d_in[8];
  float* out = (float*)d_out;

  float* ws   = (float*)d_ws;
  float* zx   = ws;                                      // (2048, 4240)
  float* xy   = zx + (size_t)BB * LL * DINPROJ;          // (2048, 2048)
  float* Bm   = xy + (size_t)BB * LL * DINNER;           // (2048, 64)
  float* Cm   = Bm + (size_t)BB * LL * NS;               // (2048, 64)
  float* dtv  = Cm + (size_t)BB * LL * NS;               // (2048, 16)
  float* clog = dtv + (size_t)BB * LL * NH;              // (32, 1024)
  float* S    = clog + (size_t)BB * LL * NH;             // (512, 8192)
  ushort* hsP   = (ushort*)(S + (size_t)512 * 8192);     // 2048x1024 bf16
  ushort* WinP  = hsP + (size_t)2048 * 1024;             // 4224x1024 bf16
  ushort* WoutP = WinP + (size_t)4224 * 1024;            // 1024x2048 bf16
  ushort* yP    = WoutP + (size_t)1024 * 2048;           // 2048x2048 bf16 (128-row tiles)
  float* Cpart  = (float*)(yP + (size_t)2048 * 2048);    // 4 x 2048x1024 fp32

  const int M = BB * LL;

  prep_kernel<<<PREP_HS + PREP_WIN + PREP_WOUT + M, 256, 0, stream>>>(
      hs, W_in, W_out, dt_bias, hsP, WinP, WoutP, dtv);
  mfma_gemm<<<dim3(33, 16), 256, 0, stream>>>(hsP, WinP, zx, DINPROJ, 32, 16, 0);
  conv_cumlog<<<CONV_BLKS + 2, 256, 0, stream>>>(zx, conv_w, conv_b, xy, Bm, Cm, dtv, A_log, clog);
  ssd_intra<<<BB * NH * NCH, 256, 0, stream>>>(xy, Bm, Cm, dtv, clog, zx, S);
  ssd_scan<<<(BB * NH * HD * NS) / 256, 256, 0, stream>>>(S, clog);
  ssd_out<<<BB * NH * NCH, 256, 0, stream>>>(xy, zx, Cm, clog, S, D_param);
  gate_norm_pack<<<M, 256, 0, stream>>>(xy, zx, norm_w, yP);
  mfma_gemm<<<dim3(8, 16, 4), 256, 0, stream>>>(yP, WoutP, Cpart, DMODEL, 64, 8,
                                                (size_t)DMODEL * BB * LL);
  reduce4<<<(BB * LL * DMODEL) / 1024, 256, 0, stream>>>(Cpart, out);
}

// Round 12
// 157.130 us; speedup vs baseline: 1.0659x; 1.0659x over previous
//
#include <hip/hip_runtime.h>
#include <hip/hip_bf16.h>
#include <math.h>

#define BB 2
#define LL 1024
#define DMODEL 1024
#define DINNER 2048
#define NH 16
#define HD 128
#define NS 64
#define CONVDIM 2176
#define DINPROJ 4240
#define QC 64
#define NCH 16
#define LSTR 72   // LDS row stride in ushorts (144 B) -> conflict-free b128 frag reads

typedef short bf16x8 __attribute__((ext_vector_type(8)));
typedef float f32x4 __attribute__((ext_vector_type(4)));

__device__ __forceinline__ unsigned int bfpair(float lo, float hi) {
  unsigned int a = __float_as_uint(lo); a = (a + 0x7fffu + ((a >> 16) & 1u)) >> 16;
  unsigned int b = __float_as_uint(hi); b = (b + 0x7fffu + ((b >> 16) & 1u)) >> 16;
  return a | (b << 16);
}
__device__ __forceinline__ ushort bf1(float f) {
  unsigned int u = __float_as_uint(f);
  return (ushort)((u + 0x7fffu + ((u >> 16) & 1u)) >> 16);
}
__device__ __forceinline__ uint4 pack8(const float* v) {
  return make_uint4(bfpair(v[0], v[1]), bfpair(v[2], v[3]), bfpair(v[4], v[5]), bfpair(v[6], v[7]));
}

// ---- pack helper: fp32 [R][C] row-major -> bf16 tiles [128 rows][32 k], swizzled LDS image ----
__device__ __forceinline__ void pack_tiles(const float* __restrict__ src,
                                           ushort* __restrict__ dst,
                                           int id, int C) {
  const int KT = C >> 5;
  const int tile = id >> 9;
  const int g = id & 511;
  const int r = g >> 2, s = g & 3;
  const int h = (s ^ (r >> 1)) & 3;
  const int tm = tile / KT, tk = tile - tm * KT;
  const int row = tm * 128 + r;
  const int k = tk * 32 + h * 8;
  const float4 a = *(const float4*)(src + (size_t)row * C + k);
  const float4 b = *(const float4*)(src + (size_t)row * C + k + 4);
  uint4 pk;
  pk.x = bfpair(a.x, a.y); pk.y = bfpair(a.z, a.w);
  pk.z = bfpair(b.x, b.y); pk.w = bfpair(b.z, b.w);
  *(uint4*)(dst + (size_t)id * 8) = pk;
}

// ---- phase-1 prep: pack hs, W_in + dt GEMV, branched on blockIdx (W_out moved to gate_norm_pack) ----
#define PREP_HS 1024
#define PREP_WIN 2112
__global__ __launch_bounds__(256) void prep_kernel(const float* __restrict__ hs,
                                                   const float* __restrict__ W_in,
                                                   const float* __restrict__ dt_bias,
                                                   ushort* __restrict__ hsP,
                                                   ushort* __restrict__ WinP,
                                                   float* __restrict__ dtv) {
  __shared__ float hl[1024];
  __shared__ float part[256];
  const int blk = blockIdx.x;
  const int t = threadIdx.x;
  if (blk < PREP_HS) {
    pack_tiles(hs, hsP, blk * 256 + t, 1024);
  } else if (blk < PREP_HS + PREP_WIN) {
    pack_tiles(W_in, WinP, (blk - PREP_HS) * 256 + t, 1024);
  } else {
    const int bl = blk - (PREP_HS + PREP_WIN);
    *(float4*)(hl + t * 4) = *(const float4*)(hs + (size_t)bl * 1024 + t * 4);
    __syncthreads();
    const int h = t & 15, ks = t >> 4;
    const float* wrow = W_in + (size_t)(DINNER + CONVDIM + h) * 1024 + ks * 64;
    const float* xs = hl + ks * 64;
    float p = 0.f;
#pragma unroll
    for (int j = 0; j < 64; j += 4) {
      const float4 wv = *(const float4*)(wrow + j);
      const float4 xv = *(const float4*)(xs + j);
      p += wv.x * xv.x + wv.y * xv.y + wv.z * xv.z + wv.w * xv.w;
    }
    part[t] = p;
    __syncthreads();
    if (t < 16) {
      float sum = 0.f;
#pragma unroll
      for (int j = 0; j < 16; ++j) sum += part[t + 16 * j];
      const float x = sum + dt_bias[t];
      dtv[bl * 16 + t] = (x > 20.f) ? x : log1pf(expf(x));
    }
  }
}

// ---- bf16 MFMA GEMM, 128x128 tile, BK=32, optional split-K via blockIdx.z ----
__global__ __launch_bounds__(256) void mfma_gemm(const ushort* __restrict__ Ap,
                                                 const ushort* __restrict__ Bp,
                                                 float* __restrict__ C,
                                                 int ldC, int KtTot, int Ktl,
                                                 size_t partStride) {
  __shared__ ushort lds[2][2][4096];
  const int tid = threadIdx.x;
  const int w = tid >> 6, lane = tid & 63;
  const int wr = w >> 1, wc = w & 1;
  const int l15 = lane & 15, lg = lane >> 4;
  const int bm = blockIdx.y * 128, bn = blockIdx.x * 128;
  const int kt0 = blockIdx.z * Ktl;
  const ushort* At = Ap + (size_t)blockIdx.y * KtTot * 4096 + (size_t)kt0 * 4096;
  const ushort* Bt = Bp + (size_t)blockIdx.x * KtTot * 4096 + (size_t)kt0 * 4096;
  float* Cz = C + (size_t)blockIdx.z * partStride;

  int offA[4], offB[4];
#pragma unroll
  for (int i = 0; i < 4; ++i) {
    const int r = wr * 64 + i * 16 + l15;
    offA[i] = r * 64 + (((lg ^ (r >> 1)) & 3) << 4);
    const int c = wc * 64 + i * 16 + l15;
    offB[i] = c * 64 + (((lg ^ (c >> 1)) & 3) << 4);
  }
  f32x4 acc[4][4] = {};

#define STAGE(buf, kt)                                                                   \
  do {                                                                                   \
    const char* ga_ = (const char*)(At + (size_t)(kt) * 4096);                           \
    const char* gb_ = (const char*)(Bt + (size_t)(kt) * 4096);                           \
    char* la_ = (char*)&lds[buf][0][0];                                                  \
    char* lb_ = (char*)&lds[buf][1][0];                                                  \
    _Pragma("unroll")                                                                    \
    for (int q = 0; q < 2; ++q) {                                                        \
      __builtin_amdgcn_global_load_lds(                                                  \
          (const __attribute__((address_space(1))) void*)(ga_ + q * 4096 + tid * 16),    \
          (__attribute__((address_space(3))) void*)(la_ + q * 4096 + (w << 10)), 16, 0, 0); \
      __builtin_amdgcn_global_load_lds(                                                  \
          (const __attribute__((address_space(1))) void*)(gb_ + q * 4096 + tid * 16),    \
          (__attribute__((address_space(3))) void*)(lb_ + q * 4096 + (w << 10)), 16, 0, 0); \
    }                                                                                    \
  } while (0)

  STAGE(0, 0);
  __syncthreads();
  int cur = 0;
  for (int kt = 0; kt < Ktl; ++kt) {
    if (kt + 1 < Ktl) STAGE(cur ^ 1, kt + 1);
    bf16x8 af[4], bfr[4];
#pragma unroll
    for (int i = 0; i < 4; ++i) af[i] = *(const bf16x8*)((const char*)&lds[cur][0][0] + offA[i]);
#pragma unroll
    for (int i = 0; i < 4; ++i) bfr[i] = *(const bf16x8*)((const char*)&lds[cur][1][0] + offB[i]);
#pragma unroll
    for (int mi = 0; mi < 4; ++mi)
#pragma unroll
      for (int ni = 0; ni < 4; ++ni)
        acc[mi][ni] = __builtin_amdgcn_mfma_f32_16x16x32_bf16(af[mi], bfr[ni], acc[mi][ni], 0, 0, 0);
    __syncthreads();
    cur ^= 1;
  }
#undef STAGE

#pragma unroll
  for (int mi = 0; mi < 4; ++mi) {
    const int row0 = bm + wr * 64 + mi * 16 + lg * 4;
#pragma unroll
    for (int ni = 0; ni < 4; ++ni) {
      const int col = bn + wc * 64 + ni * 16 + l15;
      float* cp = Cz + (size_t)row0 * ldC + col;
      cp[0] = acc[mi][ni][0];
      cp[(size_t)ldC] = acc[mi][ni][1];
      cp[(size_t)2 * ldC] = acc[mi][ni][2];
      cp[(size_t)3 * ldC] = acc[mi][ni][3];
    }
  }
}

// ---- sum 4 split-K partials -> out ----
__global__ __launch_bounds__(256) void reduce4(const float* __restrict__ P,
                                               float* __restrict__ out) {
  const size_t i = ((size_t)blockIdx.x * 256 + threadIdx.x) * 4;
  const size_t st = (size_t)DMODEL * BB * LL;
  float4 a = *(const float4*)(P + i);
  const float4 b = *(const float4*)(P + st + i);
  const float4 c = *(const float4*)(P + 2 * st + i);
  const float4 d = *(const float4*)(P + 3 * st + i);
  a.x += b.x + c.x + d.x;
  a.y += b.y + c.y + d.y;
  a.z += b.z + c.z + d.z;
  a.w += b.w + c.w + d.w;
  *(float4*)(out + i) = a;
}

// ---- causal depthwise conv(4)+SiLU (+ merged cumlog tail blocks) ----
#define CONV_BLKS ((BB * LL * CONVDIM + 255) / 256)
__global__ __launch_bounds__(256) void conv_cumlog(const float* __restrict__ zx,
                                                   const float* __restrict__ conv_w,
                                                   const float* __restrict__ conv_b,
                                                   float* __restrict__ xy,
                                                   float* __restrict__ Bm,
                                                   float* __restrict__ Cm,
                                                   const float* __restrict__ dtv,
                                                   const float* __restrict__ A_log,
                                                   float* __restrict__ clog) {
  const int blk = blockIdx.x;
  if (blk >= CONV_BLKS) {
    const int idx = (blk - CONV_BLKS) * 256 + threadIdx.x;
    if (idx >= BB * NH * NCH) return;
    const int c = idx & (NCH - 1);
    const int bh = idx >> 4;
    const int b = bh >> 4, h = bh & (NH - 1);
    const float A = -__expf(A_log[h]);
    float run = 0.f;
    for (int i = 0; i < QC; ++i) {
      run += A * dtv[(size_t)(b * LL + c * QC + i) * NH + h];
      clog[(size_t)bh * LL + c * QC + i] = run;
    }
    return;
  }
  const int idx = blk * 256 + threadIdx.x;
  const int c = idx % CONVDIM;
  const int bl = idx / CONVDIM;
  const int l = bl & (LL - 1);
  const float w0 = conv_w[c * 4 + 0], w1 = conv_w[c * 4 + 1];
  const float w2 = conv_w[c * 4 + 2], w3 = conv_w[c * 4 + 3];
  const float* base = zx + (size_t)bl * DINPROJ + DINNER + c;
  float acc = conv_b[c];
  acc = fmaf(base[0], w3, acc);
  if (l >= 1) acc = fmaf(base[-1 * DINPROJ], w2, acc);
  if (l >= 2) acc = fmaf(base[-2 * DINPROJ], w1, acc);
  if (l >= 3) acc = fmaf(base[-3 * DINPROJ], w0, acc);
  const float s = acc / (1.f + expf(-acc));
  if (c < DINNER)                    xy[(size_t)bl * DINNER + c] = s;
  else if (c < DINNER + NS)          Bm[bl * NS + (c - DINNER)] = s;
  else                               Cm[bl * NS + (c - DINNER - NS)] = s;
}

// ---- SSD intra-chunk via bf16 MFMA ----
__global__ __launch_bounds__(256) void ssd_intra(const float* __restrict__ xy,
                                                 const float* __restrict__ Bm,
                                                 const float* __restrict__ Cm,
                                                 const float* __restrict__ dtv,
                                                 const float* __restrict__ clog,
                                                 float* __restrict__ zx,
                                                 float* __restrict__ S) {
  __shared__ __align__(16) ushort sC[64 * LSTR];
  __shared__ __align__(16) ushort sB[64 * LSTR];
  __shared__ __align__(16) ushort sBT[64 * LSTR];
  __shared__ __align__(16) ushort sXT[128 * LSTR];
  __shared__ __align__(16) ushort sP[64 * LSTR];
  __shared__ float scl[QC], sdt[QC], swdt[QC];
  const int blk = blockIdx.x;
  const int bh = blk >> 4, c = blk & (NCH - 1);
  const int b = bh >> 4, h = bh & (NH - 1);
  const int t0 = c * QC;
  const int tid = threadIdx.x;
  const int w = tid >> 6, lane = tid & 63, l15 = lane & 15, lg = lane >> 4;

  if (tid < QC) {
    const float cl = clog[(size_t)bh * LL + t0 + tid];
    const float clend = clog[(size_t)bh * LL + t0 + QC - 1];
    const float dt = dtv[(size_t)(b * LL + t0 + tid) * NH + h];
    scl[tid] = cl; sdt[tid] = dt;
    swdt[tid] = __expf(clend - cl) * dt;
  }
  __syncthreads();

  const float* Bg = Bm + (size_t)(b * LL + t0) * NS;
  const float* Cg = Cm + (size_t)(b * LL + t0) * NS;
#pragma unroll
  for (int j = 0; j < 4; ++j) {
    const int f = j * 256 + tid;
    const int r = f >> 4, c4 = f & 15;
    const float4 bv = *(const float4*)(Bg + r * NS + c4 * 4);
    const float4 cv = *(const float4*)(Cg + r * NS + c4 * 4);
    *(uint2*)(sB + r * LSTR + c4 * 4) = make_uint2(bfpair(bv.x, bv.y), bfpair(bv.z, bv.w));
    *(uint2*)(sC + r * LSTR + c4 * 4) = make_uint2(bfpair(cv.x, cv.y), bfpair(cv.z, cv.w));
  }
  {
    const int n = tid & 63, sg = tid >> 6;
    float bw[16];
#pragma unroll
    for (int j = 0; j < 16; ++j) {
      const int s = sg * 16 + j;
      bw[j] = swdt[s] * Bg[(size_t)s * NS + n];
    }
    *(uint4*)(sBT + n * LSTR + sg * 16) = pack8(bw);
    *(uint4*)(sBT + n * LSTR + sg * 16 + 8) = pack8(bw + 8);
  }
  {
    const int p = tid & 127, sh = tid >> 7;
    const float* xg = xy + (size_t)(b * LL + t0 + sh * 32) * DINNER + h * HD + p;
    float xv[32];
#pragma unroll
    for (int j = 0; j < 32; ++j) xv[j] = xg[(size_t)j * DINNER];
#pragma unroll
    for (int q = 0; q < 4; ++q)
      *(uint4*)(sXT + p * LSTR + sh * 32 + q * 8) = pack8(xv + q * 8);
  }
  __syncthreads();

  f32x4 g[4] = {};
#pragma unroll
  for (int ks = 0; ks < 2; ++ks) {
    const bf16x8 ca = *(const bf16x8*)((const char*)sC + (w * 16 + l15) * 144 + ks * 64 + lg * 16);
#pragma unroll
    for (int ni = 0; ni < 4; ++ni) {
      const bf16x8 bb = *(const bf16x8*)((const char*)sB + (ni * 16 + l15) * 144 + ks * 64 + lg * 16);
      g[ni] = __builtin_amdgcn_mfma_f32_16x16x32_bf16(ca, bb, g[ni], 0, 0, 0);
    }
  }
#pragma unroll
  for (int ni = 0; ni < 4; ++ni) {
    const int s = ni * 16 + l15;
    const float cls = scl[s], dts = sdt[s];
#pragma unroll
    for (int j = 0; j < 4; ++j) {
      const int t = w * 16 + lg * 4 + j;
      const float v = (s <= t) ? g[ni][j] * __expf(scl[t] - cls) * dts : 0.f;
      sP[t * LSTR + s] = bf1(v);
    }
  }
  f32x4 sa[2][4] = {};
#pragma unroll
  for (int ks = 0; ks < 2; ++ks) {
    const bf16x8 a0 = *(const bf16x8*)((const char*)sXT + (w * 32 + l15) * 144 + ks * 64 + lg * 16);
    const bf16x8 a1 = *(const bf16x8*)((const char*)sXT + (w * 32 + 16 + l15) * 144 + ks * 64 + lg * 16);
#pragma unroll
    for (int nj = 0; nj < 4; ++nj) {
      const bf16x8 bb = *(const bf16x8*)((const char*)sBT + (nj * 16 + l15) * 144 + ks * 64 + lg * 16);
      sa[0][nj] = __builtin_amdgcn_mfma_f32_16x16x32_bf16(a0, bb, sa[0][nj], 0, 0, 0);
      sa[1][nj] = __builtin_amdgcn_mfma_f32_16x16x32_bf16(a1, bb, sa[1][nj], 0, 0, 0);
    }
  }
  float* Sg = S + (size_t)blk * (HD * NS);
#pragma unroll
  for (int mi = 0; mi < 2; ++mi)
#pragma unroll
    for (int nj = 0; nj < 4; ++nj)
#pragma unroll
      for (int j = 0; j < 4; ++j)
        Sg[(size_t)(w * 32 + mi * 16 + lg * 4 + j) * NS + nj * 16 + l15] = sa[mi][nj][j];
  __syncthreads();

  f32x4 y[8] = {};
#pragma unroll
  for (int ks = 0; ks < 2; ++ks) {
    const bf16x8 pa = *(const bf16x8*)((const char*)sP + (w * 16 + l15) * 144 + ks * 64 + lg * 16);
#pragma unroll
    for (int ni = 0; ni < 8; ++ni) {
      const bf16x8 xb = *(const bf16x8*)((const char*)sXT + (ni * 16 + l15) * 144 + ks * 64 + lg * 16);
      y[ni] = __builtin_amdgcn_mfma_f32_16x16x32_bf16(pa, xb, y[ni], 0, 0, 0);
    }
  }
  float* yg = zx + (size_t)(b * LL + t0) * DINPROJ + DINNER + h * HD;
#pragma unroll
  for (int ni = 0; ni < 8; ++ni)
#pragma unroll
    for (int j = 0; j < 4; ++j)
      yg[(size_t)(w * 16 + lg * 4 + j) * DINPROJ + ni * 16 + l15] = y[ni][j];
}

// ---- inter-chunk scan over chunk states ----
__global__ __launch_bounds__(256) void ssd_scan(float* __restrict__ S,
                                                const float* __restrict__ clog) {
  const int idx = blockIdx.x * 256 + threadIdx.x;
  const int pn = idx & (HD * NS - 1);
  const int bh = idx >> 13;
  float* Sp = S + (size_t)bh * NCH * (HD * NS) + pn;
  const float* cl = clog + (size_t)bh * LL;
  float H = 0.f;
#pragma unroll
  for (int c = 0; c < NCH; ++c) {
    const float dec = __expf(cl[c * QC + QC - 1]);
    const float s = Sp[(size_t)c * (HD * NS)];
    Sp[(size_t)c * (HD * NS)] = H;
    H = dec * H + s;
  }
}

// ---- y = y_intra + exp(cl)*C.H^T + D*x (bf16 MFMA, in place on xy) ----
__global__ __launch_bounds__(256) void ssd_out(float* __restrict__ xy,
                                               const float* __restrict__ zx,
                                               const float* __restrict__ Cm,
                                               const float* __restrict__ clog,
                                               const float* __restrict__ S,
                                               const float* __restrict__ Dp_) {
  __shared__ __align__(16) ushort sC[64 * LSTR];
  __shared__ __align__(16) ushort sH[128 * LSTR];
  __shared__ float sE[QC];
  const int blk = blockIdx.x;
  const int bh = blk >> 4, c = blk & (NCH - 1);
  const int b = bh >> 4, h = bh & (NH - 1);
  const int t0 = c * QC;
  const int tid = threadIdx.x;
  const int w = tid >> 6, lane = tid & 63, l15 = lane & 15, lg = lane >> 4;

  if (tid < QC) sE[tid] = __expf(clog[(size_t)bh * LL + t0 + tid]);
  const float* Cg = Cm + (size_t)(b * LL + t0) * NS;
#pragma unroll
  for (int j = 0; j < 4; ++j) {
    const int f = j * 256 + tid, r = f >> 4, c4 = f & 15;
    const float4 cv = *(const float4*)(Cg + r * NS + c4 * 4);
    *(uint2*)(sC + r * LSTR + c4 * 4) = make_uint2(bfpair(cv.x, cv.y), bfpair(cv.z, cv.w));
  }
  const float* Hg = S + (size_t)blk * (HD * NS);
#pragma unroll
  for (int j = 0; j < 8; ++j) {
    const int f = j * 256 + tid, p = f >> 4, n4 = f & 15;
    const float4 hv = *(const float4*)(Hg + (size_t)p * NS + n4 * 4);
    *(uint2*)(sH + p * LSTR + n4 * 4) = make_uint2(bfpair(hv.x, hv.y), bfpair(hv.z, hv.w));
  }
  __syncthreads();

  f32x4 y2[8] = {};
#pragma unroll
  for (int ks = 0; ks < 2; ++ks) {
    const bf16x8 ca = *(const bf16x8*)((const char*)sC + (w * 16 + l15) * 144 + ks * 64 + lg * 16);
#pragma unroll
    for (int ni = 0; ni < 8; ++ni) {
      const bf16x8 hb = *(const bf16x8*)((const char*)sH + (ni * 16 + l15) * 144 + ks * 64 + lg * 16);
      y2[ni] = __builtin_amdgcn_mfma_f32_16x16x32_bf16(ca, hb, y2[ni], 0, 0, 0);
    }
  }
  const float Dv = Dp_[h];
#pragma unroll
  for (int ni = 0; ni < 8; ++ni) {
    const int p = ni * 16 + l15;
#pragma unroll
    for (int j = 0; j < 4; ++j) {
      const int t = w * 16 + lg * 4 + j;
      const size_t row = (size_t)(b * LL + t0 + t);
      const float yi = zx[row * DINPROJ + DINNER + h * HD + p];
      float* xp = xy + row * DINNER + h * HD + p;
      *xp = yi + sE[t] * y2[ni][j] + Dv * (*xp);
    }
  }
}

// ---- y *= silu(z); RMSNorm; emit packed bf16 128-row tiles (+ tail blocks pack W_out) ----
#define GN_ROWS (BB * LL)
#define GN_WOUT 1024
__global__ __launch_bounds__(256) void gate_norm_pack(const float* __restrict__ xy,
                                                      const float* __restrict__ zx,
                                                      const float* __restrict__ nw,
                                                      const float* __restrict__ W_out,
                                                      ushort* __restrict__ yP,
                                                      ushort* __restrict__ WoutP) {
  __shared__ float red[4];
  const int m = blockIdx.x;
  const int t = threadIdx.x;
  if (m >= GN_ROWS) {  // tail: pack W_out (1024x2048, 128-row tiles) for the out-proj GEMM
    pack_tiles(W_out, WoutP, (m - GN_ROWS) * 256 + t, 2048);
    return;
  }
  const float* yrow = xy + (size_t)m * DINNER;
  const float* zrow = zx + (size_t)m * DINPROJ;
  const int e = t * 8;
  const float4 y0 = *(const float4*)(yrow + e), y1 = *(const float4*)(yrow + e + 4);
  const float4 z0 = *(const float4*)(zrow + e), z1 = *(const float4*)(zrow + e + 4);
  float v[8];
  v[0] = y0.x * (z0.x / (1.f + expf(-z0.x)));
  v[1] = y0.y * (z0.y / (1.f + expf(-z0.y)));
  v[2] = y0.z * (z0.z / (1.f + expf(-z0.z)));
  v[3] = y0.w * (z0.w / (1.f + expf(-z0.w)));
  v[4] = y1.x * (z1.x / (1.f + expf(-z1.x)));
  v[5] = y1.y * (z1.y / (1.f + expf(-z1.y)));
  v[6] = y1.z * (z1.z / (1.f + expf(-z1.z)));
  v[7] = y1.w * (z1.w / (1.f + expf(-z1.w)));
  float ss = 0.f;
#pragma unroll
  for (int j = 0; j < 8; ++j) ss += v[j] * v[j];
#pragma unroll
  for (int off = 32; off; off >>= 1) ss += __shfl_down(ss, off);
  const int lane = t & 63, wid = t >> 6;
  if (lane == 0) red[wid] = ss;
  __syncthreads();
  const float tot = red[0] + red[1] + red[2] + red[3];
  const float rstd = rsqrtf(tot * (1.f / DINNER) + 1e-5f);
  const float4 w0 = *(const float4*)(nw + e), w1 = *(const float4*)(nw + e + 4);
  v[0] *= rstd * w0.x; v[1] *= rstd * w0.y; v[2] *= rstd * w0.z; v[3] *= rstd * w0.w;
  v[4] *= rstd * w1.x; v[5] *= rstd * w1.y; v[6] *= rstd * w1.z; v[7] *= rstd * w1.w;
  // 128-row tile pack: tile (m>>7)*64 + (t>>2), row r=m&127, slot s=(t^(r>>1))&3
  const int r = m & 127;
  const int tk = t >> 2;
  const int s = (t ^ (r >> 1)) & 3;
  uint4 pk;
  pk.x = bfpair(v[0], v[1]); pk.y = bfpair(v[2], v[3]);
  pk.z = bfpair(v[4], v[5]); pk.w = bfpair(v[6], v[7]);
  *(uint4*)(yP + (size_t)((m >> 7) * 64 + tk) * 4096 + r * 32 + s * 8) = pk;
}

extern "C" void kernel_launch(void* const* d_in, const int* in_sizes, int n_in,
                              void* d_out, int out_size, void* d_ws, size_t ws_size,
                              hipStream_t stream) {
  const float* hs      = (const float*)d_in[0];
  const float* W_in    = (const float*)d_in[1];
  const float* conv_w  = (const float*)d_in[2];
  const float* conv_b  = (const float*)d_in[3];
  const float* dt_bias = (const float*)d_in[4];
  const float* A_log   = (const float*)d_in[5];
  const float* D_param = (const float*)d_in[6];
  const float* norm_w  = (const float*)d_in[7];
  const float* W_out   = (const float*)d_in[8];
  float* out = (float*)d_out;

  float* ws   = (float*)d_ws;
  float* zx   = ws;                                      // (2048, 4240)
  float* xy   = zx + (size_t)BB * LL * DINPROJ;          // (2048, 2048)
  float* Bm   = xy + (size_t)BB * LL * DINNER;           // (2048, 64)
  float* Cm   = Bm + (size_t)BB * LL * NS;               // (2048, 64)
  float* dtv  = Cm + (size_t)BB * LL * NS;               // (2048, 16)
  float* clog = dtv + (size_t)BB * LL * NH;              // (32, 1024)
  float* S    = clog + (size_t)BB * LL * NH;             // (512, 8192)
  ushort* hsP   = (ushort*)(S + (size_t)512 * 8192);     // 2048x1024 bf16
  ushort* WinP  = hsP + (size_t)2048 * 1024;             // 4224x1024 bf16
  ushort* WoutP = WinP + (size_t)4224 * 1024;            // 1024x2048 bf16
  ushort* yP    = WoutP + (size_t)1024 * 2048;           // 2048x2048 bf16 (128-row tiles)
  float* Cpart  = (float*)(yP + (size_t)2048 * 2048);    // 4 x 2048x1024 fp32

  const int M = BB * LL;

  prep_kernel<<<PREP_HS + PREP_WIN + M, 256, 0, stream>>>(
      hs, W_in, dt_bias, hsP, WinP, dtv);
  mfma_gemm<<<dim3(33, 16), 256, 0, stream>>>(hsP, WinP, zx, DINPROJ, 32, 32, 0);
  conv_cumlog<<<CONV_BLKS + 2, 256, 0, stream>>>(zx, conv_w, conv_b, xy, Bm, Cm, dtv, A_log, clog);
  ssd_intra<<<BB * NH * NCH, 256, 0, stream>>>(xy, Bm, Cm, dtv, clog, zx, S);
  ssd_scan<<<(BB * NH * HD * NS) / 256, 256, 0, stream>>>(S, clog);
  ssd_out<<<BB * NH * NCH, 256, 0, stream>>>(xy, zx, Cm, clog, S, D_param);
  gate_norm_pack<<<GN_ROWS + GN_WOUT, 256, 0, stream>>>(xy, zx, norm_w, W_out, yP, WoutP);
  mfma_gemm<<<dim3(8, 16, 4), 256, 0, stream>>>(yP, WoutP, Cpart, DMODEL, 64, 16,
                                                (size_t)DMODEL * BB * LL);
  reduce4<<<(BB * LL * DMODEL) / 1024, 256, 0, stream>>>(Cpart, out);
}

// Round 13
// 154.641 us; speedup vs baseline: 1.0830x; 1.0161x over previous
//
#include <hip/hip_runtime.h>
#include <hip/hip_bf16.h>
#include <math.h>

#define BB 2
#define LL 1024
#define DMODEL 1024
#define DINNER 2048
#define NH 16
#define HD 128
#define NS 64
#define CONVDIM 2176
#define DINPROJ 4240
#define QC 64
#define NCH 16
#define LSTR 72   // LDS row stride in ushorts (144 B) -> conflict-free b128 frag reads

typedef short bf16x8 __attribute__((ext_vector_type(8)));
typedef float f32x4 __attribute__((ext_vector_type(4)));

__device__ __forceinline__ unsigned int bfpair(float lo, float hi) {
  unsigned int a = __float_as_uint(lo); a = (a + 0x7fffu + ((a >> 16) & 1u)) >> 16;
  unsigned int b = __float_as_uint(hi); b = (b + 0x7fffu + ((b >> 16) & 1u)) >> 16;
  return a | (b << 16);
}
__device__ __forceinline__ ushort bf1(float f) {
  unsigned int u = __float_as_uint(f);
  return (ushort)((u + 0x7fffu + ((u >> 16) & 1u)) >> 16);
}
__device__ __forceinline__ float bf2f(unsigned int u) {
  return __uint_as_float(u << 16);
}
__device__ __forceinline__ uint4 pack8(const float* v) {
  return make_uint4(bfpair(v[0], v[1]), bfpair(v[2], v[3]), bfpair(v[4], v[5]), bfpair(v[6], v[7]));
}

// ---- pack helper: fp32 [R][C] row-major -> bf16 tiles [128 rows][32 k], swizzled LDS image ----
__device__ __forceinline__ void pack_tiles(const float* __restrict__ src,
                                           ushort* __restrict__ dst,
                                           int id, int C) {
  const int KT = C >> 5;
  const int tile = id >> 9;
  const int g = id & 511;
  const int r = g >> 2, s = g & 3;
  const int h = (s ^ (r >> 1)) & 3;
  const int tm = tile / KT, tk = tile - tm * KT;
  const int row = tm * 128 + r;
  const int k = tk * 32 + h * 8;
  const float4 a = *(const float4*)(src + (size_t)row * C + k);
  const float4 b = *(const float4*)(src + (size_t)row * C + k + 4);
  uint4 pk;
  pk.x = bfpair(a.x, a.y); pk.y = bfpair(a.z, a.w);
  pk.z = bfpair(b.x, b.y); pk.w = bfpair(b.z, b.w);
  *(uint4*)(dst + (size_t)id * 8) = pk;
}

// ---- phase-1 prep: pack hs, W_in + dt GEMV, branched on blockIdx ----
#define PREP_HS 1024
#define PREP_WIN 2112
__global__ __launch_bounds__(256) void prep_kernel(const float* __restrict__ hs,
                                                   const float* __restrict__ W_in,
                                                   const float* __restrict__ dt_bias,
                                                   ushort* __restrict__ hsP,
                                                   ushort* __restrict__ WinP,
                                                   float* __restrict__ dtv) {
  __shared__ float hl[1024];
  __shared__ float part[256];
  const int blk = blockIdx.x;
  const int t = threadIdx.x;
  if (blk < PREP_HS) {
    pack_tiles(hs, hsP, blk * 256 + t, 1024);
  } else if (blk < PREP_HS + PREP_WIN) {
    pack_tiles(W_in, WinP, (blk - PREP_HS) * 256 + t, 1024);
  } else {
    const int bl = blk - (PREP_HS + PREP_WIN);
    *(float4*)(hl + t * 4) = *(const float4*)(hs + (size_t)bl * 1024 + t * 4);
    __syncthreads();
    const int h = t & 15, ks = t >> 4;
    const float* wrow = W_in + (size_t)(DINNER + CONVDIM + h) * 1024 + ks * 64;
    const float* xs = hl + ks * 64;
    float p = 0.f;
#pragma unroll
    for (int j = 0; j < 64; j += 4) {
      const float4 wv = *(const float4*)(wrow + j);
      const float4 xv = *(const float4*)(xs + j);
      p += wv.x * xv.x + wv.y * xv.y + wv.z * xv.z + wv.w * xv.w;
    }
    part[t] = p;
    __syncthreads();
    if (t < 16) {
      float sum = 0.f;
#pragma unroll
      for (int j = 0; j < 16; ++j) sum += part[t + 16 * j];
      const float x = sum + dt_bias[t];
      dtv[bl * 16 + t] = (x > 20.f) ? x : log1pf(expf(x));
    }
  }
}

// ---- bf16 MFMA GEMM, 128x128 tile, BK=32, fp32 output (in-proj) ----
__global__ __launch_bounds__(256) void mfma_gemm(const ushort* __restrict__ Ap,
                                                 const ushort* __restrict__ Bp,
                                                 float* __restrict__ C,
                                                 int ldC, int KtTot, int Ktl) {
  __shared__ ushort lds[2][2][4096];
  const int tid = threadIdx.x;
  const int w = tid >> 6, lane = tid & 63;
  const int wr = w >> 1, wc = w & 1;
  const int l15 = lane & 15, lg = lane >> 4;
  const int bm = blockIdx.y * 128, bn = blockIdx.x * 128;
  const ushort* At = Ap + (size_t)blockIdx.y * KtTot * 4096;
  const ushort* Bt = Bp + (size_t)blockIdx.x * KtTot * 4096;

  int offA[4], offB[4];
#pragma unroll
  for (int i = 0; i < 4; ++i) {
    const int r = wr * 64 + i * 16 + l15;
    offA[i] = r * 64 + (((lg ^ (r >> 1)) & 3) << 4);
    const int c = wc * 64 + i * 16 + l15;
    offB[i] = c * 64 + (((lg ^ (c >> 1)) & 3) << 4);
  }
  f32x4 acc[4][4] = {};

#define STAGE(buf, kt)                                                                   \
  do {                                                                                   \
    const char* ga_ = (const char*)(At + (size_t)(kt) * 4096);                           \
    const char* gb_ = (const char*)(Bt + (size_t)(kt) * 4096);                           \
    char* la_ = (char*)&lds[buf][0][0];                                                  \
    char* lb_ = (char*)&lds[buf][1][0];                                                  \
    _Pragma("unroll")                                                                    \
    for (int q = 0; q < 2; ++q) {                                                        \
      __builtin_amdgcn_global_load_lds(                                                  \
          (const __attribute__((address_space(1))) void*)(ga_ + q * 4096 + tid * 16),    \
          (__attribute__((address_space(3))) void*)(la_ + q * 4096 + (w << 10)), 16, 0, 0); \
      __builtin_amdgcn_global_load_lds(                                                  \
          (const __attribute__((address_space(1))) void*)(gb_ + q * 4096 + tid * 16),    \
          (__attribute__((address_space(3))) void*)(lb_ + q * 4096 + (w << 10)), 16, 0, 0); \
    }                                                                                    \
  } while (0)

  STAGE(0, 0);
  __syncthreads();
  int cur = 0;
  for (int kt = 0; kt < Ktl; ++kt) {
    if (kt + 1 < Ktl) STAGE(cur ^ 1, kt + 1);
    bf16x8 af[4], bfr[4];
#pragma unroll
    for (int i = 0; i < 4; ++i) af[i] = *(const bf16x8*)((const char*)&lds[cur][0][0] + offA[i]);
#pragma unroll
    for (int i = 0; i < 4; ++i) bfr[i] = *(const bf16x8*)((const char*)&lds[cur][1][0] + offB[i]);
#pragma unroll
    for (int mi = 0; mi < 4; ++mi)
#pragma unroll
      for (int ni = 0; ni < 4; ++ni)
        acc[mi][ni] = __builtin_amdgcn_mfma_f32_16x16x32_bf16(af[mi], bfr[ni], acc[mi][ni], 0, 0, 0);
    __syncthreads();
    cur ^= 1;
  }

#pragma unroll
  for (int mi = 0; mi < 4; ++mi) {
    const int row0 = bm + wr * 64 + mi * 16 + lg * 4;
#pragma unroll
    for (int ni = 0; ni < 4; ++ni) {
      const int col = bn + wc * 64 + ni * 16 + l15;
      float* cp = C + (size_t)row0 * ldC + col;
      cp[0] = acc[mi][ni][0];
      cp[(size_t)ldC] = acc[mi][ni][1];
      cp[(size_t)2 * ldC] = acc[mi][ni][2];
      cp[(size_t)3 * ldC] = acc[mi][ni][3];
    }
  }
}

// ---- same GEMM but split-K with bf16 partial output (out-proj) ----
__global__ __launch_bounds__(256) void mfma_gemm_p16(const ushort* __restrict__ Ap,
                                                     const ushort* __restrict__ Bp,
                                                     ushort* __restrict__ C,
                                                     int ldC, int KtTot, int Ktl,
                                                     size_t partStride) {
  __shared__ ushort lds[2][2][4096];
  const int tid = threadIdx.x;
  const int w = tid >> 6, lane = tid & 63;
  const int wr = w >> 1, wc = w & 1;
  const int l15 = lane & 15, lg = lane >> 4;
  const int bm = blockIdx.y * 128, bn = blockIdx.x * 128;
  const int kt0 = blockIdx.z * Ktl;
  const ushort* At = Ap + (size_t)blockIdx.y * KtTot * 4096 + (size_t)kt0 * 4096;
  const ushort* Bt = Bp + (size_t)blockIdx.x * KtTot * 4096 + (size_t)kt0 * 4096;
  ushort* Cz = C + (size_t)blockIdx.z * partStride;

  int offA[4], offB[4];
#pragma unroll
  for (int i = 0; i < 4; ++i) {
    const int r = wr * 64 + i * 16 + l15;
    offA[i] = r * 64 + (((lg ^ (r >> 1)) & 3) << 4);
    const int c = wc * 64 + i * 16 + l15;
    offB[i] = c * 64 + (((lg ^ (c >> 1)) & 3) << 4);
  }
  f32x4 acc[4][4] = {};

  STAGE(0, 0);
  __syncthreads();
  int cur = 0;
  for (int kt = 0; kt < Ktl; ++kt) {
    if (kt + 1 < Ktl) STAGE(cur ^ 1, kt + 1);
    bf16x8 af[4], bfr[4];
#pragma unroll
    for (int i = 0; i < 4; ++i) af[i] = *(const bf16x8*)((const char*)&lds[cur][0][0] + offA[i]);
#pragma unroll
    for (int i = 0; i < 4; ++i) bfr[i] = *(const bf16x8*)((const char*)&lds[cur][1][0] + offB[i]);
#pragma unroll
    for (int mi = 0; mi < 4; ++mi)
#pragma unroll
      for (int ni = 0; ni < 4; ++ni)
        acc[mi][ni] = __builtin_amdgcn_mfma_f32_16x16x32_bf16(af[mi], bfr[ni], acc[mi][ni], 0, 0, 0);
    __syncthreads();
    cur ^= 1;
  }
#undef STAGE

#pragma unroll
  for (int mi = 0; mi < 4; ++mi) {
    const int row0 = bm + wr * 64 + mi * 16 + lg * 4;
#pragma unroll
    for (int ni = 0; ni < 4; ++ni) {
      const int col = bn + wc * 64 + ni * 16 + l15;
      ushort* cp = Cz + (size_t)row0 * ldC + col;
      cp[0] = bf1(acc[mi][ni][0]);
      cp[(size_t)ldC] = bf1(acc[mi][ni][1]);
      cp[(size_t)2 * ldC] = bf1(acc[mi][ni][2]);
      cp[(size_t)3 * ldC] = bf1(acc[mi][ni][3]);
    }
  }
}

// ---- sum 4 bf16 split-K partials -> fp32 out (8 elems/thread) ----
__global__ __launch_bounds__(256) void reduce4b(const ushort* __restrict__ P,
                                                float* __restrict__ out) {
  const size_t i = ((size_t)blockIdx.x * 256 + threadIdx.x) * 8;
  const size_t st = (size_t)DMODEL * BB * LL;
  float s[8] = {};
#pragma unroll
  for (int z = 0; z < 4; ++z) {
    const uint4 v = *(const uint4*)(P + z * st + i);
    s[0] += bf2f(v.x & 0xffffu); s[1] += bf2f(v.x >> 16);
    s[2] += bf2f(v.y & 0xffffu); s[3] += bf2f(v.y >> 16);
    s[4] += bf2f(v.z & 0xffffu); s[5] += bf2f(v.z >> 16);
    s[6] += bf2f(v.w & 0xffffu); s[7] += bf2f(v.w >> 16);
  }
  *(float4*)(out + i)     = make_float4(s[0], s[1], s[2], s[3]);
  *(float4*)(out + i + 4) = make_float4(s[4], s[5], s[6], s[7]);
}

// ---- causal depthwise conv(4)+SiLU (+ merged cumlog tail blocks) ----
#define CONV_BLKS ((BB * LL * CONVDIM + 255) / 256)
__global__ __launch_bounds__(256) void conv_cumlog(const float* __restrict__ zx,
                                                   const float* __restrict__ conv_w,
                                                   const float* __restrict__ conv_b,
                                                   float* __restrict__ xy,
                                                   float* __restrict__ Bm,
                                                   float* __restrict__ Cm,
                                                   const float* __restrict__ dtv,
                                                   const float* __restrict__ A_log,
                                                   float* __restrict__ clog) {
  const int blk = blockIdx.x;
  if (blk >= CONV_BLKS) {
    const int idx = (blk - CONV_BLKS) * 256 + threadIdx.x;
    if (idx >= BB * NH * NCH) return;
    const int c = idx & (NCH - 1);
    const int bh = idx >> 4;
    const int b = bh >> 4, h = bh & (NH - 1);
    const float A = -__expf(A_log[h]);
    float run = 0.f;
    for (int i = 0; i < QC; ++i) {
      run += A * dtv[(size_t)(b * LL + c * QC + i) * NH + h];
      clog[(size_t)bh * LL + c * QC + i] = run;
    }
    return;
  }
  const int idx = blk * 256 + threadIdx.x;
  const int c = idx % CONVDIM;
  const int bl = idx / CONVDIM;
  const int l = bl & (LL - 1);
  const float w0 = conv_w[c * 4 + 0], w1 = conv_w[c * 4 + 1];
  const float w2 = conv_w[c * 4 + 2], w3 = conv_w[c * 4 + 3];
  const float* base = zx + (size_t)bl * DINPROJ + DINNER + c;
  float acc = conv_b[c];
  acc = fmaf(base[0], w3, acc);
  if (l >= 1) acc = fmaf(base[-1 * DINPROJ], w2, acc);
  if (l >= 2) acc = fmaf(base[-2 * DINPROJ], w1, acc);
  if (l >= 3) acc = fmaf(base[-3 * DINPROJ], w0, acc);
  const float s = acc / (1.f + expf(-acc));
  if (c < DINNER)                    xy[(size_t)bl * DINNER + c] = s;
  else if (c < DINNER + NS)          Bm[bl * NS + (c - DINNER)] = s;
  else                               Cm[bl * NS + (c - DINNER - NS)] = s;
}

// ---- SSD intra-chunk via bf16 MFMA ----
__global__ __launch_bounds__(256) void ssd_intra(const float* __restrict__ xy,
                                                 const float* __restrict__ Bm,
                                                 const float* __restrict__ Cm,
                                                 const float* __restrict__ dtv,
                                                 const float* __restrict__ clog,
                                                 float* __restrict__ zx,
                                                 float* __restrict__ S) {
  __shared__ __align__(16) ushort sC[64 * LSTR];
  __shared__ __align__(16) ushort sB[64 * LSTR];
  __shared__ __align__(16) ushort sBT[64 * LSTR];
  __shared__ __align__(16) ushort sXT[128 * LSTR];
  __shared__ __align__(16) ushort sP[64 * LSTR];
  __shared__ float scl[QC], sdt[QC], swdt[QC];
  const int blk = blockIdx.x;
  const int bh = blk >> 4, c = blk & (NCH - 1);
  const int b = bh >> 4, h = bh & (NH - 1);
  const int t0 = c * QC;
  const int tid = threadIdx.x;
  const int w = tid >> 6, lane = tid & 63, l15 = lane & 15, lg = lane >> 4;

  if (tid < QC) {
    const float cl = clog[(size_t)bh * LL + t0 + tid];
    const float clend = clog[(size_t)bh * LL + t0 + QC - 1];
    const float dt = dtv[(size_t)(b * LL + t0 + tid) * NH + h];
    scl[tid] = cl; sdt[tid] = dt;
    swdt[tid] = __expf(clend - cl) * dt;
  }
  __syncthreads();

  const float* Bg = Bm + (size_t)(b * LL + t0) * NS;
  const float* Cg = Cm + (size_t)(b * LL + t0) * NS;
#pragma unroll
  for (int j = 0; j < 4; ++j) {
    const int f = j * 256 + tid;
    const int r = f >> 4, c4 = f & 15;
    const float4 bv = *(const float4*)(Bg + r * NS + c4 * 4);
    const float4 cv = *(const float4*)(Cg + r * NS + c4 * 4);
    *(uint2*)(sB + r * LSTR + c4 * 4) = make_uint2(bfpair(bv.x, bv.y), bfpair(bv.z, bv.w));
    *(uint2*)(sC + r * LSTR + c4 * 4) = make_uint2(bfpair(cv.x, cv.y), bfpair(cv.z, cv.w));
  }
  {
    const int n = tid & 63, sg = tid >> 6;
    float bw[16];
#pragma unroll
    for (int j = 0; j < 16; ++j) {
      const int s = sg * 16 + j;
      bw[j] = swdt[s] * Bg[(size_t)s * NS + n];
    }
    *(uint4*)(sBT + n * LSTR + sg * 16) = pack8(bw);
    *(uint4*)(sBT + n * LSTR + sg * 16 + 8) = pack8(bw + 8);
  }
  {
    const int p = tid & 127, sh = tid >> 7;
    const float* xg = xy + (size_t)(b * LL + t0 + sh * 32) * DINNER + h * HD + p;
    float xv[32];
#pragma unroll
    for (int j = 0; j < 32; ++j) xv[j] = xg[(size_t)j * DINNER];
#pragma unroll
    for (int q = 0; q < 4; ++q)
      *(uint4*)(sXT + p * LSTR + sh * 32 + q * 8) = pack8(xv + q * 8);
  }
  __syncthreads();

  f32x4 g[4] = {};
#pragma unroll
  for (int ks = 0; ks < 2; ++ks) {
    const bf16x8 ca = *(const bf16x8*)((const char*)sC + (w * 16 + l15) * 144 + ks * 64 + lg * 16);
#pragma unroll
    for (int ni = 0; ni < 4; ++ni) {
      const bf16x8 bb = *(const bf16x8*)((const char*)sB + (ni * 16 + l15) * 144 + ks * 64 + lg * 16);
      g[ni] = __builtin_amdgcn_mfma_f32_16x16x32_bf16(ca, bb, g[ni], 0, 0, 0);
    }
  }
#pragma unroll
  for (int ni = 0; ni < 4; ++ni) {
    const int s = ni * 16 + l15;
    const float cls = scl[s], dts = sdt[s];
#pragma unroll
    for (int j = 0; j < 4; ++j) {
      const int t = w * 16 + lg * 4 + j;
      const float v = (s <= t) ? g[ni][j] * __expf(scl[t] - cls) * dts : 0.f;
      sP[t * LSTR + s] = bf1(v);
    }
  }
  f32x4 sa[2][4] = {};
#pragma unroll
  for (int ks = 0; ks < 2; ++ks) {
    const bf16x8 a0 = *(const bf16x8*)((const char*)sXT + (w * 32 + l15) * 144 + ks * 64 + lg * 16);
    const bf16x8 a1 = *(const bf16x8*)((const char*)sXT + (w * 32 + 16 + l15) * 144 + ks * 64 + lg * 16);
#pragma unroll
    for (int nj = 0; nj < 4; ++nj) {
      const bf16x8 bb = *(const bf16x8*)((const char*)sBT + (nj * 16 + l15) * 144 + ks * 64 + lg * 16);
      sa[0][nj] = __builtin_amdgcn_mfma_f32_16x16x32_bf16(a0, bb, sa[0][nj], 0, 0, 0);
      sa[1][nj] = __builtin_amdgcn_mfma_f32_16x16x32_bf16(a1, bb, sa[1][nj], 0, 0, 0);
    }
  }
  float* Sg = S + (size_t)blk * (HD * NS);
#pragma unroll
  for (int mi = 0; mi < 2; ++mi)
#pragma unroll
    for (int nj = 0; nj < 4; ++nj)
#pragma unroll
      for (int j = 0; j < 4; ++j)
        Sg[(size_t)(w * 32 + mi * 16 + lg * 4 + j) * NS + nj * 16 + l15] = sa[mi][nj][j];
  __syncthreads();

  f32x4 y[8] = {};
#pragma unroll
  for (int ks = 0; ks < 2; ++ks) {
    const bf16x8 pa = *(const bf16x8*)((const char*)sP + (w * 16 + l15) * 144 + ks * 64 + lg * 16);
#pragma unroll
    for (int ni = 0; ni < 8; ++ni) {
      const bf16x8 xb = *(const bf16x8*)((const char*)sXT + (ni * 16 + l15) * 144 + ks * 64 + lg * 16);
      y[ni] = __builtin_amdgcn_mfma_f32_16x16x32_bf16(pa, xb, y[ni], 0, 0, 0);
    }
  }
  float* yg = zx + (size_t)(b * LL + t0) * DINPROJ + DINNER + h * HD;
#pragma unroll
  for (int ni = 0; ni < 8; ++ni)
#pragma unroll
    for (int j = 0; j < 4; ++j)
      yg[(size_t)(w * 16 + lg * 4 + j) * DINPROJ + ni * 16 + l15] = y[ni][j];
}

// ---- inter-chunk scan over chunk states ----
__global__ __launch_bounds__(256) void ssd_scan(float* __restrict__ S,
                                                const float* __restrict__ clog) {
  const int idx = blockIdx.x * 256 + threadIdx.x;
  const int pn = idx & (HD * NS - 1);
  const int bh = idx >> 13;
  float* Sp = S + (size_t)bh * NCH * (HD * NS) + pn;
  const float* cl = clog + (size_t)bh * LL;
  float H = 0.f;
#pragma unroll
  for (int c = 0; c < NCH; ++c) {
    const float dec = __expf(cl[c * QC + QC - 1]);
    const float s = Sp[(size_t)c * (HD * NS)];
    Sp[(size_t)c * (HD * NS)] = H;
    H = dec * H + s;
  }
}

// ---- y = y_intra + exp(cl)*C.H^T + D*x (bf16 MFMA, in place on xy) ----
__global__ __launch_bounds__(256) void ssd_out(float* __restrict__ xy,
                                               const float* __restrict__ zx,
                                               const float* __restrict__ Cm,
                                               const float* __restrict__ clog,
                                               const float* __restrict__ S,
                                               const float* __restrict__ Dp_) {
  __shared__ __align__(16) ushort sC[64 * LSTR];
  __shared__ __align__(16) ushort sH[128 * LSTR];
  __shared__ float sE[QC];
  const int blk = blockIdx.x;
  const int bh = blk >> 4, c = blk & (NCH - 1);
  const int b = bh >> 4, h = bh & (NH - 1);
  const int t0 = c * QC;
  const int tid = threadIdx.x;
  const int w = tid >> 6, lane = tid & 63, l15 = lane & 15, lg = lane >> 4;

  if (tid < QC) sE[tid] = __expf(clog[(size_t)bh * LL + t0 + tid]);
  const float* Cg = Cm + (size_t)(b * LL + t0) * NS;
#pragma unroll
  for (int j = 0; j < 4; ++j) {
    const int f = j * 256 + tid, r = f >> 4, c4 = f & 15;
    const float4 cv = *(const float4*)(Cg + r * NS + c4 * 4);
    *(uint2*)(sC + r * LSTR + c4 * 4) = make_uint2(bfpair(cv.x, cv.y), bfpair(cv.z, cv.w));
  }
  const float* Hg = S + (size_t)blk * (HD * NS);
#pragma unroll
  for (int j = 0; j < 8; ++j) {
    const int f = j * 256 + tid, p = f >> 4, n4 = f & 15;
    const float4 hv = *(const float4*)(Hg + (size_t)p * NS + n4 * 4);
    *(uint2*)(sH + p * LSTR + n4 * 4) = make_uint2(bfpair(hv.x, hv.y), bfpair(hv.z, hv.w));
  }
  __syncthreads();

  f32x4 y2[8] = {};
#pragma unroll
  for (int ks = 0; ks < 2; ++ks) {
    const bf16x8 ca = *(const bf16x8*)((const char*)sC + (w * 16 + l15) * 144 + ks * 64 + lg * 16);
#pragma unroll
    for (int ni = 0; ni < 8; ++ni) {
      const bf16x8 hb = *(const bf16x8*)((const char*)sH + (ni * 16 + l15) * 144 + ks * 64 + lg * 16);
      y2[ni] = __builtin_amdgcn_mfma_f32_16x16x32_bf16(ca, hb, y2[ni], 0, 0, 0);
    }
  }
  const float Dv = Dp_[h];
#pragma unroll
  for (int ni = 0; ni < 8; ++ni) {
    const int p = ni * 16 + l15;
#pragma unroll
    for (int j = 0; j < 4; ++j) {
      const int t = w * 16 + lg * 4 + j;
      const size_t row = (size_t)(b * LL + t0 + t);
      const float yi = zx[row * DINPROJ + DINNER + h * HD + p];
      float* xp = xy + row * DINNER + h * HD + p;
      *xp = yi + sE[t] * y2[ni][j] + Dv * (*xp);
    }
  }
}

// ---- y *= silu(z); RMSNorm; emit packed bf16 128-row tiles (+ tail blocks pack W_out) ----
#define GN_ROWS (BB * LL)
#define GN_WOUT 1024
__global__ __launch_bounds__(256) void gate_norm_pack(const float* __restrict__ xy,
                                                      const float* __restrict__ zx,
                                                      const float* __restrict__ nw,
                                                      const float* __restrict__ W_out,
                                                      ushort* __restrict__ yP,
                                                      ushort* __restrict__ WoutP) {
  __shared__ float red[4];
  const int m = blockIdx.x;
  const int t = threadIdx.x;
  if (m >= GN_ROWS) {
    pack_tiles(W_out, WoutP, (m - GN_ROWS) * 256 + t, 2048);
    return;
  }
  const float* yrow = xy + (size_t)m * DINNER;
  const float* zrow = zx + (size_t)m * DINPROJ;
  const int e = t * 8;
  const float4 y0 = *(const float4*)(yrow + e), y1 = *(const float4*)(yrow + e + 4);
  const float4 z0 = *(const float4*)(zrow + e), z1 = *(const float4*)(zrow + e + 4);
  float v[8];
  v[0] = y0.x * (z0.x / (1.f + expf(-z0.x)));
  v[1] = y0.y * (z0.y / (1.f + expf(-z0.y)));
  v[2] = y0.z * (z0.z / (1.f + expf(-z0.z)));
  v[3] = y0.w * (z0.w / (1.f + expf(-z0.w)));
  v[4] = y1.x * (z1.x / (1.f + expf(-z1.x)));
  v[5] = y1.y * (z1.y / (1.f + expf(-z1.y)));
  v[6] = y1.z * (z1.z / (1.f + expf(-z1.z)));
  v[7] = y1.w * (z1.w / (1.f + expf(-z1.w)));
  float ss = 0.f;
#pragma unroll
  for (int j = 0; j < 8; ++j) ss += v[j] * v[j];
#pragma unroll
  for (int off = 32; off; off >>= 1) ss += __shfl_down(ss, off);
  const int lane = t & 63, wid = t >> 6;
  if (lane == 0) red[wid] = ss;
  __syncthreads();
  const float tot = red[0] + red[1] + red[2] + red[3];
  const float rstd = rsqrtf(tot * (1.f / DINNER) + 1e-5f);
  const float4 w0 = *(const float4*)(nw + e), w1 = *(const float4*)(nw + e + 4);
  v[0] *= rstd * w0.x; v[1] *= rstd * w0.y; v[2] *= rstd * w0.z; v[3] *= rstd * w0.w;
  v[4] *= rstd * w1.x; v[5] *= rstd * w1.y; v[6] *= rstd * w1.z; v[7] *= rstd * w1.w;
  const int r = m & 127;
  const int tk = t >> 2;
  const int s = (t ^ (r >> 1)) & 3;
  uint4 pk;
  pk.x = bfpair(v[0], v[1]); pk.y = bfpair(v[2], v[3]);
  pk.z = bfpair(v[4], v[5]); pk.w = bfpair(v[6], v[7]);
  *(uint4*)(yP + (size_t)((m >> 7) * 64 + tk) * 4096 + r * 32 + s * 8) = pk;
}

extern "C" void kernel_launch(void* const* d_in, const int* in_sizes, int n_in,
                              void* d_out, int out_size, void* d_ws, size_t ws_size,
                              hipStream_t stream) {
  const float* hs      = (const float*)d_in[0];
  const float* W_in    = (const float*)d_in[1];
  const float* conv_w  = (const float*)d_in[2];
  const float* conv_b  = (const float*)d_in[3];
  const float* dt_bias = (const float*)d_in[4];
  const float* A_log   = (const float*)d_in[5];
  const float* D_param = (const float*)d_in[6];
  const float* norm_w  = (const float*)d_in[7];
  const float* W_out   = (const float*)d_in[8];
  float* out = (float*)d_out;

  float* ws   = (float*)d_ws;
  float* zx   = ws;                                      // (2048, 4240)
  float* xy   = zx + (size_t)BB * LL * DINPROJ;          // (2048, 2048)
  float* Bm   = xy + (size_t)BB * LL * DINNER;           // (2048, 64)
  float* Cm   = Bm + (size_t)BB * LL * NS;               // (2048, 64)
  float* dtv  = Cm + (size_t)BB * LL * NS;               // (2048, 16)
  float* clog = dtv + (size_t)BB * LL * NH;              // (32, 1024)
  float* S    = clog + (size_t)BB * LL * NH;             // (512, 8192)
  ushort* hsP   = (ushort*)(S + (size_t)512 * 8192);     // 2048x1024 bf16
  ushort* WinP  = hsP + (size_t)2048 * 1024;             // 4224x1024 bf16
  ushort* WoutP = WinP + (size_t)4224 * 1024;            // 1024x2048 bf16
  ushort* yP    = WoutP + (size_t)1024 * 2048;           // 2048x2048 bf16 (128-row tiles)
  ushort* CpartB = yP + (size_t)2048 * 2048;             // 4 x 2048x1024 bf16 = 16.8 MB

  const int M = BB * LL;

  prep_kernel<<<PREP_HS + PREP_WIN + M, 256, 0, stream>>>(
      hs, W_in, dt_bias, hsP, WinP, dtv);
  mfma_gemm<<<dim3(33, 16), 256, 0, stream>>>(hsP, WinP, zx, DINPROJ, 32, 32);
  conv_cumlog<<<CONV_BLKS + 2, 256, 0, stream>>>(zx, conv_w, conv_b, xy, Bm, Cm, dtv, A_log, clog);
  ssd_intra<<<BB * NH * NCH, 256, 0, stream>>>(xy, Bm, Cm, dtv, clog, zx, S);
  ssd_scan<<<(BB * NH * HD * NS) / 256, 256, 0, stream>>>(S, clog);
  ssd_out<<<BB * NH * NCH, 256, 0, stream>>>(xy, zx, Cm, clog, S, D_param);
  gate_norm_pack<<<GN_ROWS + GN_WOUT, 256, 0, stream>>>(xy, zx, norm_w, W_out, yP, WoutP);
  mfma_gemm_p16<<<dim3(8, 16, 4), 256, 0, stream>>>(yP, WoutP, CpartB, DMODEL, 64, 16,
                                                    (size_t)DMODEL * BB * LL);
  reduce4b<<<(BB * LL * DMODEL) / 2048, 256, 0, stream>>>(CpartB, out);
}

// Round 14
// 147.803 us; speedup vs baseline: 1.1331x; 1.0463x over previous
//
#include <hip/hip_runtime.h>
#include <hip/hip_bf16.h>
#include <math.h>

#define BB 2
#define LL 1024
#define DMODEL 1024
#define DINNER 2048
#define NH 16
#define HD 128
#define NS 64
#define CONVDIM 2176
#define DINPROJ 4240
#define QC 64
#define NCH 16
#define LSTR 72   // LDS row stride in ushorts (144 B) -> conflict-free b128 frag reads

typedef short bf16x8 __attribute__((ext_vector_type(8)));
typedef float f32x4 __attribute__((ext_vector_type(4)));

__device__ __forceinline__ unsigned int bfpair(float lo, float hi) {
  unsigned int a = __float_as_uint(lo); a = (a + 0x7fffu + ((a >> 16) & 1u)) >> 16;
  unsigned int b = __float_as_uint(hi); b = (b + 0x7fffu + ((b >> 16) & 1u)) >> 16;
  return a | (b << 16);
}
__device__ __forceinline__ ushort bf1(float f) {
  unsigned int u = __float_as_uint(f);
  return (ushort)((u + 0x7fffu + ((u >> 16) & 1u)) >> 16);
}
__device__ __forceinline__ float bf2f(unsigned int u) {
  return __uint_as_float(u << 16);
}
__device__ __forceinline__ uint4 pack8(const float* v) {
  return make_uint4(bfpair(v[0], v[1]), bfpair(v[2], v[3]), bfpair(v[4], v[5]), bfpair(v[6], v[7]));
}

// ---- pack helper: fp32 [R][C] row-major -> bf16 tiles [128 rows][32 k], swizzled LDS image ----
__device__ __forceinline__ void pack_tiles(const float* __restrict__ src,
                                           ushort* __restrict__ dst,
                                           int id, int C) {
  const int KT = C >> 5;
  const int tile = id >> 9;
  const int g = id & 511;
  const int r = g >> 2, s = g & 3;
  const int h = (s ^ (r >> 1)) & 3;
  const int tm = tile / KT, tk = tile - tm * KT;
  const int row = tm * 128 + r;
  const int k = tk * 32 + h * 8;
  const float4 a = *(const float4*)(src + (size_t)row * C + k);
  const float4 b = *(const float4*)(src + (size_t)row * C + k + 4);
  uint4 pk;
  pk.x = bfpair(a.x, a.y); pk.y = bfpair(a.z, a.w);
  pk.z = bfpair(b.x, b.y); pk.w = bfpair(b.z, b.w);
  *(uint4*)(dst + (size_t)id * 8) = pk;
}

// ---- phase-1 prep: pack hs, W_in + dt GEMV, branched on blockIdx ----
#define PREP_HS 1024
#define PREP_WIN 2112
__global__ __launch_bounds__(256) void prep_kernel(const float* __restrict__ hs,
                                                   const float* __restrict__ W_in,
                                                   const float* __restrict__ dt_bias,
                                                   ushort* __restrict__ hsP,
                                                   ushort* __restrict__ WinP,
                                                   float* __restrict__ dtv) {
  __shared__ float hl[1024];
  __shared__ float part[256];
  const int blk = blockIdx.x;
  const int t = threadIdx.x;
  if (blk < PREP_HS) {
    pack_tiles(hs, hsP, blk * 256 + t, 1024);
  } else if (blk < PREP_HS + PREP_WIN) {
    pack_tiles(W_in, WinP, (blk - PREP_HS) * 256 + t, 1024);
  } else {
    const int bl = blk - (PREP_HS + PREP_WIN);
    *(float4*)(hl + t * 4) = *(const float4*)(hs + (size_t)bl * 1024 + t * 4);
    __syncthreads();
    const int h = t & 15, ks = t >> 4;
    const float* wrow = W_in + (size_t)(DINNER + CONVDIM + h) * 1024 + ks * 64;
    const float* xs = hl + ks * 64;
    float p = 0.f;
#pragma unroll
    for (int j = 0; j < 64; j += 4) {
      const float4 wv = *(const float4*)(wrow + j);
      const float4 xv = *(const float4*)(xs + j);
      p += wv.x * xv.x + wv.y * xv.y + wv.z * xv.z + wv.w * xv.w;
    }
    part[t] = p;
    __syncthreads();
    if (t < 16) {
      float sum = 0.f;
#pragma unroll
      for (int j = 0; j < 16; ++j) sum += part[t + 16 * j];
      const float x = sum + dt_bias[t];
      dtv[bl * 16 + t] = (x > 20.f) ? x : log1pf(expf(x));
    }
  }
}

// ---- bf16 MFMA GEMM, 128x128 tile, BK=32, bf16 output, optional split-K ----
// used for in-proj (grid.z=1, partStride=0, C=zx bf16) and out-proj (split-K=4 partials)
__global__ __launch_bounds__(256) void mfma_gemm_p16(const ushort* __restrict__ Ap,
                                                     const ushort* __restrict__ Bp,
                                                     ushort* __restrict__ C,
                                                     int ldC, int KtTot, int Ktl,
                                                     size_t partStride) {
  __shared__ ushort lds[2][2][4096];
  const int tid = threadIdx.x;
  const int w = tid >> 6, lane = tid & 63;
  const int wr = w >> 1, wc = w & 1;
  const int l15 = lane & 15, lg = lane >> 4;
  const int bm = blockIdx.y * 128, bn = blockIdx.x * 128;
  const int kt0 = blockIdx.z * Ktl;
  const ushort* At = Ap + (size_t)blockIdx.y * KtTot * 4096 + (size_t)kt0 * 4096;
  const ushort* Bt = Bp + (size_t)blockIdx.x * KtTot * 4096 + (size_t)kt0 * 4096;
  ushort* Cz = C + (size_t)blockIdx.z * partStride;

  int offA[4], offB[4];
#pragma unroll
  for (int i = 0; i < 4; ++i) {
    const int r = wr * 64 + i * 16 + l15;
    offA[i] = r * 64 + (((lg ^ (r >> 1)) & 3) << 4);
    const int c = wc * 64 + i * 16 + l15;
    offB[i] = c * 64 + (((lg ^ (c >> 1)) & 3) << 4);
  }
  f32x4 acc[4][4] = {};

#define STAGE(buf, kt)                                                                   \
  do {                                                                                   \
    const char* ga_ = (const char*)(At + (size_t)(kt) * 4096);                           \
    const char* gb_ = (const char*)(Bt + (size_t)(kt) * 4096);                           \
    char* la_ = (char*)&lds[buf][0][0];                                                  \
    char* lb_ = (char*)&lds[buf][1][0];                                                  \
    _Pragma("unroll")                                                                    \
    for (int q = 0; q < 2; ++q) {                                                        \
      __builtin_amdgcn_global_load_lds(                                                  \
          (const __attribute__((address_space(1))) void*)(ga_ + q * 4096 + tid * 16),    \
          (__attribute__((address_space(3))) void*)(la_ + q * 4096 + (w << 10)), 16, 0, 0); \
      __builtin_amdgcn_global_load_lds(                                                  \
          (const __attribute__((address_space(1))) void*)(gb_ + q * 4096 + tid * 16),    \
          (__attribute__((address_space(3))) void*)(lb_ + q * 4096 + (w << 10)), 16, 0, 0); \
    }                                                                                    \
  } while (0)

  STAGE(0, 0);
  __syncthreads();
  int cur = 0;
  for (int kt = 0; kt < Ktl; ++kt) {
    if (kt + 1 < Ktl) STAGE(cur ^ 1, kt + 1);
    bf16x8 af[4], bfr[4];
#pragma unroll
    for (int i = 0; i < 4; ++i) af[i] = *(const bf16x8*)((const char*)&lds[cur][0][0] + offA[i]);
#pragma unroll
    for (int i = 0; i < 4; ++i) bfr[i] = *(const bf16x8*)((const char*)&lds[cur][1][0] + offB[i]);
#pragma unroll
    for (int mi = 0; mi < 4; ++mi)
#pragma unroll
      for (int ni = 0; ni < 4; ++ni)
        acc[mi][ni] = __builtin_amdgcn_mfma_f32_16x16x32_bf16(af[mi], bfr[ni], acc[mi][ni], 0, 0, 0);
    __syncthreads();
    cur ^= 1;
  }
#undef STAGE

#pragma unroll
  for (int mi = 0; mi < 4; ++mi) {
    const int row0 = bm + wr * 64 + mi * 16 + lg * 4;
#pragma unroll
    for (int ni = 0; ni < 4; ++ni) {
      const int col = bn + wc * 64 + ni * 16 + l15;
      ushort* cp = Cz + (size_t)row0 * ldC + col;
      cp[0] = bf1(acc[mi][ni][0]);
      cp[(size_t)ldC] = bf1(acc[mi][ni][1]);
      cp[(size_t)2 * ldC] = bf1(acc[mi][ni][2]);
      cp[(size_t)3 * ldC] = bf1(acc[mi][ni][3]);
    }
  }
}

// ---- sum 4 bf16 split-K partials -> fp32 out (8 elems/thread) ----
__global__ __launch_bounds__(256) void reduce4b(const ushort* __restrict__ P,
                                                float* __restrict__ out) {
  const size_t i = ((size_t)blockIdx.x * 256 + threadIdx.x) * 8;
  const size_t st = (size_t)DMODEL * BB * LL;
  float s[8] = {};
#pragma unroll
  for (int z = 0; z < 4; ++z) {
    const uint4 v = *(const uint4*)(P + z * st + i);
    s[0] += bf2f(v.x & 0xffffu); s[1] += bf2f(v.x >> 16);
    s[2] += bf2f(v.y & 0xffffu); s[3] += bf2f(v.y >> 16);
    s[4] += bf2f(v.z & 0xffffu); s[5] += bf2f(v.z >> 16);
    s[6] += bf2f(v.w & 0xffffu); s[7] += bf2f(v.w >> 16);
  }
  *(float4*)(out + i)     = make_float4(s[0], s[1], s[2], s[3]);
  *(float4*)(out + i + 4) = make_float4(s[4], s[5], s[6], s[7]);
}

// ---- causal depthwise conv(4)+SiLU over bf16 zx (+ merged cumlog tail blocks) ----
#define CONV_BLKS ((BB * LL * CONVDIM + 255) / 256)
__global__ __launch_bounds__(256) void conv_cumlog(const ushort* __restrict__ zx,
                                                   const float* __restrict__ conv_w,
                                                   const float* __restrict__ conv_b,
                                                   float* __restrict__ xy,
                                                   float* __restrict__ Bm,
                                                   float* __restrict__ Cm,
                                                   const float* __restrict__ dtv,
                                                   const float* __restrict__ A_log,
                                                   float* __restrict__ clog) {
  const int blk = blockIdx.x;
  if (blk >= CONV_BLKS) {
    const int idx = (blk - CONV_BLKS) * 256 + threadIdx.x;
    if (idx >= BB * NH * NCH) return;
    const int c = idx & (NCH - 1);
    const int bh = idx >> 4;
    const int b = bh >> 4, h = bh & (NH - 1);
    const float A = -__expf(A_log[h]);
    float run = 0.f;
    for (int i = 0; i < QC; ++i) {
      run += A * dtv[(size_t)(b * LL + c * QC + i) * NH + h];
      clog[(size_t)bh * LL + c * QC + i] = run;
    }
    return;
  }
  const int idx = blk * 256 + threadIdx.x;
  const int c = idx % CONVDIM;
  const int bl = idx / CONVDIM;
  const int l = bl & (LL - 1);
  const float w0 = conv_w[c * 4 + 0], w1 = conv_w[c * 4 + 1];
  const float w2 = conv_w[c * 4 + 2], w3 = conv_w[c * 4 + 3];
  const ushort* base = zx + (size_t)bl * DINPROJ + DINNER + c;
  float acc = conv_b[c];
  acc = fmaf(bf2f(base[0]), w3, acc);
  if (l >= 1) acc = fmaf(bf2f(base[-1 * DINPROJ]), w2, acc);
  if (l >= 2) acc = fmaf(bf2f(base[-2 * DINPROJ]), w1, acc);
  if (l >= 3) acc = fmaf(bf2f(base[-3 * DINPROJ]), w0, acc);
  const float s = acc / (1.f + expf(-acc));
  if (c < DINNER)                    xy[(size_t)bl * DINNER + c] = s;
  else if (c < DINNER + NS)          Bm[bl * NS + (c - DINNER)] = s;
  else                               Cm[bl * NS + (c - DINNER - NS)] = s;
}

// ---- SSD intra-chunk via bf16 MFMA; y_intra -> dedicated fp32 yI ----
__global__ __launch_bounds__(256) void ssd_intra(const float* __restrict__ xy,
                                                 const float* __restrict__ Bm,
                                                 const float* __restrict__ Cm,
                                                 const float* __restrict__ dtv,
                                                 const float* __restrict__ clog,
                                                 float* __restrict__ yI,
                                                 float* __restrict__ S) {
  __shared__ __align__(16) ushort sC[64 * LSTR];
  __shared__ __align__(16) ushort sB[64 * LSTR];
  __shared__ __align__(16) ushort sBT[64 * LSTR];
  __shared__ __align__(16) ushort sXT[128 * LSTR];
  __shared__ __align__(16) ushort sP[64 * LSTR];
  __shared__ float scl[QC], sdt[QC], swdt[QC];
  const int blk = blockIdx.x;
  const int bh = blk >> 4, c = blk & (NCH - 1);
  const int b = bh >> 4, h = bh & (NH - 1);
  const int t0 = c * QC;
  const int tid = threadIdx.x;
  const int w = tid >> 6, lane = tid & 63, l15 = lane & 15, lg = lane >> 4;

  if (tid < QC) {
    const float cl = clog[(size_t)bh * LL + t0 + tid];
    const float clend = clog[(size_t)bh * LL + t0 + QC - 1];
    const float dt = dtv[(size_t)(b * LL + t0 + tid) * NH + h];
    scl[tid] = cl; sdt[tid] = dt;
    swdt[tid] = __expf(clend - cl) * dt;
  }
  __syncthreads();

  const float* Bg = Bm + (size_t)(b * LL + t0) * NS;
  const float* Cg = Cm + (size_t)(b * LL + t0) * NS;
#pragma unroll
  for (int j = 0; j < 4; ++j) {
    const int f = j * 256 + tid;
    const int r = f >> 4, c4 = f & 15;
    const float4 bv = *(const float4*)(Bg + r * NS + c4 * 4);
    const float4 cv = *(const float4*)(Cg + r * NS + c4 * 4);
    *(uint2*)(sB + r * LSTR + c4 * 4) = make_uint2(bfpair(bv.x, bv.y), bfpair(bv.z, bv.w));
    *(uint2*)(sC + r * LSTR + c4 * 4) = make_uint2(bfpair(cv.x, cv.y), bfpair(cv.z, cv.w));
  }
  {
    const int n = tid & 63, sg = tid >> 6;
    float bw[16];
#pragma unroll
    for (int j = 0; j < 16; ++j) {
      const int s = sg * 16 + j;
      bw[j] = swdt[s] * Bg[(size_t)s * NS + n];
    }
    *(uint4*)(sBT + n * LSTR + sg * 16) = pack8(bw);
    *(uint4*)(sBT + n * LSTR + sg * 16 + 8) = pack8(bw + 8);
  }
  {
    const int p = tid & 127, sh = tid >> 7;
    const float* xg = xy + (size_t)(b * LL + t0 + sh * 32) * DINNER + h * HD + p;
    float xv[32];
#pragma unroll
    for (int j = 0; j < 32; ++j) xv[j] = xg[(size_t)j * DINNER];
#pragma unroll
    for (int q = 0; q < 4; ++q)
      *(uint4*)(sXT + p * LSTR + sh * 32 + q * 8) = pack8(xv + q * 8);
  }
  __syncthreads();

  f32x4 g[4] = {};
#pragma unroll
  for (int ks = 0; ks < 2; ++ks) {
    const bf16x8 ca = *(const bf16x8*)((const char*)sC + (w * 16 + l15) * 144 + ks * 64 + lg * 16);
#pragma unroll
    for (int ni = 0; ni < 4; ++ni) {
      const bf16x8 bb = *(const bf16x8*)((const char*)sB + (ni * 16 + l15) * 144 + ks * 64 + lg * 16);
      g[ni] = __builtin_amdgcn_mfma_f32_16x16x32_bf16(ca, bb, g[ni], 0, 0, 0);
    }
  }
#pragma unroll
  for (int ni = 0; ni < 4; ++ni) {
    const int s = ni * 16 + l15;
    const float cls = scl[s], dts = sdt[s];
#pragma unroll
    for (int j = 0; j < 4; ++j) {
      const int t = w * 16 + lg * 4 + j;
      const float v = (s <= t) ? g[ni][j] * __expf(scl[t] - cls) * dts : 0.f;
      sP[t * LSTR + s] = bf1(v);
    }
  }
  f32x4 sa[2][4] = {};
#pragma unroll
  for (int ks = 0; ks < 2; ++ks) {
    const bf16x8 a0 = *(const bf16x8*)((const char*)sXT + (w * 32 + l15) * 144 + ks * 64 + lg * 16);
    const bf16x8 a1 = *(const bf16x8*)((const char*)sXT + (w * 32 + 16 + l15) * 144 + ks * 64 + lg * 16);
#pragma unroll
    for (int nj = 0; nj < 4; ++nj) {
      const bf16x8 bb = *(const bf16x8*)((const char*)sBT + (nj * 16 + l15) * 144 + ks * 64 + lg * 16);
      sa[0][nj] = __builtin_amdgcn_mfma_f32_16x16x32_bf16(a0, bb, sa[0][nj], 0, 0, 0);
      sa[1][nj] = __builtin_amdgcn_mfma_f32_16x16x32_bf16(a1, bb, sa[1][nj], 0, 0, 0);
    }
  }
  float* Sg = S + (size_t)blk * (HD * NS);
#pragma unroll
  for (int mi = 0; mi < 2; ++mi)
#pragma unroll
    for (int nj = 0; nj < 4; ++nj)
#pragma unroll
      for (int j = 0; j < 4; ++j)
        Sg[(size_t)(w * 32 + mi * 16 + lg * 4 + j) * NS + nj * 16 + l15] = sa[mi][nj][j];
  __syncthreads();

  f32x4 y[8] = {};
#pragma unroll
  for (int ks = 0; ks < 2; ++ks) {
    const bf16x8 pa = *(const bf16x8*)((const char*)sP + (w * 16 + l15) * 144 + ks * 64 + lg * 16);
#pragma unroll
    for (int ni = 0; ni < 8; ++ni) {
      const bf16x8 xb = *(const bf16x8*)((const char*)sXT + (ni * 16 + l15) * 144 + ks * 64 + lg * 16);
      y[ni] = __builtin_amdgcn_mfma_f32_16x16x32_bf16(pa, xb, y[ni], 0, 0, 0);
    }
  }
  float* yg = yI + (size_t)(b * LL + t0) * DINNER + h * HD;
#pragma unroll
  for (int ni = 0; ni < 8; ++ni)
#pragma unroll
    for (int j = 0; j < 4; ++j)
      yg[(size_t)(w * 16 + lg * 4 + j) * DINNER + ni * 16 + l15] = y[ni][j];
}

// ---- inter-chunk scan over chunk states ----
__global__ __launch_bounds__(256) void ssd_scan(float* __restrict__ S,
                                                const float* __restrict__ clog) {
  const int idx = blockIdx.x * 256 + threadIdx.x;
  const int pn = idx & (HD * NS - 1);
  const int bh = idx >> 13;
  float* Sp = S + (size_t)bh * NCH * (HD * NS) + pn;
  const float* cl = clog + (size_t)bh * LL;
  float H = 0.f;
#pragma unroll
  for (int c = 0; c < NCH; ++c) {
    const float dec = __expf(cl[c * QC + QC - 1]);
    const float s = Sp[(size_t)c * (HD * NS)];
    Sp[(size_t)c * (HD * NS)] = H;
    H = dec * H + s;
  }
}

// ---- y = yI + exp(cl)*C.H^T + D*x (bf16 MFMA, in place on xy) ----
__global__ __launch_bounds__(256) void ssd_out(float* __restrict__ xy,
                                               const float* __restrict__ yI,
                                               const float* __restrict__ Cm,
                                               const float* __restrict__ clog,
                                               const float* __restrict__ S,
                                               const float* __restrict__ Dp_) {
  __shared__ __align__(16) ushort sC[64 * LSTR];
  __shared__ __align__(16) ushort sH[128 * LSTR];
  __shared__ float sE[QC];
  const int blk = blockIdx.x;
  const int bh = blk >> 4, c = blk & (NCH - 1);
  const int b = bh >> 4, h = bh & (NH - 1);
  const int t0 = c * QC;
  const int tid = threadIdx.x;
  const int w = tid >> 6, lane = tid & 63, l15 = lane & 15, lg = lane >> 4;

  if (tid < QC) sE[tid] = __expf(clog[(size_t)bh * LL + t0 + tid]);
  const float* Cg = Cm + (size_t)(b * LL + t0) * NS;
#pragma unroll
  for (int j = 0; j < 4; ++j) {
    const int f = j * 256 + tid, r = f >> 4, c4 = f & 15;
    const float4 cv = *(const float4*)(Cg + r * NS + c4 * 4);
    *(uint2*)(sC + r * LSTR + c4 * 4) = make_uint2(bfpair(cv.x, cv.y), bfpair(cv.z, cv.w));
  }
  const float* Hg = S + (size_t)blk * (HD * NS);
#pragma unroll
  for (int j = 0; j < 8; ++j) {
    const int f = j * 256 + tid, p = f >> 4, n4 = f & 15;
    const float4 hv = *(const float4*)(Hg + (size_t)p * NS + n4 * 4);
    *(uint2*)(sH + p * LSTR + n4 * 4) = make_uint2(bfpair(hv.x, hv.y), bfpair(hv.z, hv.w));
  }
  __syncthreads();

  f32x4 y2[8] = {};
#pragma unroll
  for (int ks = 0; ks < 2; ++ks) {
    const bf16x8 ca = *(const bf16x8*)((const char*)sC + (w * 16 + l15) * 144 + ks * 64 + lg * 16);
#pragma unroll
    for (int ni = 0; ni < 8; ++ni) {
      const bf16x8 hb = *(const bf16x8*)((const char*)sH + (ni * 16 + l15) * 144 + ks * 64 + lg * 16);
      y2[ni] = __builtin_amdgcn_mfma_f32_16x16x32_bf16(ca, hb, y2[ni], 0, 0, 0);
    }
  }
  const float Dv = Dp_[h];
#pragma unroll
  for (int ni = 0; ni < 8; ++ni) {
    const int p = ni * 16 + l15;
#pragma unroll
    for (int j = 0; j < 4; ++j) {
      const int t = w * 16 + lg * 4 + j;
      const size_t row = (size_t)(b * LL + t0 + t);
      const float yi = yI[row * DINNER + h * HD + p];
      float* xp = xy + row * DINNER + h * HD + p;
      *xp = yi + sE[t] * y2[ni][j] + Dv * (*xp);
    }
  }
}

// ---- y *= silu(z); RMSNorm; emit packed bf16 128-row tiles (+ tail blocks pack W_out) ----
#define GN_ROWS (BB * LL)
#define GN_WOUT 1024
__global__ __launch_bounds__(256) void gate_norm_pack(const float* __restrict__ xy,
                                                      const ushort* __restrict__ zx,
                                                      const float* __restrict__ nw,
                                                      const float* __restrict__ W_out,
                                                      ushort* __restrict__ yP,
                                                      ushort* __restrict__ WoutP) {
  __shared__ float red[4];
  const int m = blockIdx.x;
  const int t = threadIdx.x;
  if (m >= GN_ROWS) {
    pack_tiles(W_out, WoutP, (m - GN_ROWS) * 256 + t, 2048);
    return;
  }
  const float* yrow = xy + (size_t)m * DINNER;
  const ushort* zrow = zx + (size_t)m * DINPROJ;
  const int e = t * 8;
  const float4 y0 = *(const float4*)(yrow + e), y1 = *(const float4*)(yrow + e + 4);
  const uint4 zv = *(const uint4*)(zrow + e);
  float z[8];
  z[0] = bf2f(zv.x & 0xffffu); z[1] = bf2f(zv.x >> 16);
  z[2] = bf2f(zv.y & 0xffffu); z[3] = bf2f(zv.y >> 16);
  z[4] = bf2f(zv.z & 0xffffu); z[5] = bf2f(zv.z >> 16);
  z[6] = bf2f(zv.w & 0xffffu); z[7] = bf2f(zv.w >> 16);
  float v[8];
  const float yv[8] = {y0.x, y0.y, y0.z, y0.w, y1.x, y1.y, y1.z, y1.w};
#pragma unroll
  for (int j = 0; j < 8; ++j) v[j] = yv[j] * (z[j] / (1.f + __expf(-z[j])));
  float ss = 0.f;
#pragma unroll
  for (int j = 0; j < 8; ++j) ss += v[j] * v[j];
#pragma unroll
  for (int off = 32; off; off >>= 1) ss += __shfl_down(ss, off);
  const int lane = t & 63, wid = t >> 6;
  if (lane == 0) red[wid] = ss;
  __syncthreads();
  const float tot = red[0] + red[1] + red[2] + red[3];
  const float rstd = rsqrtf(tot * (1.f / DINNER) + 1e-5f);
  const float4 w0 = *(const float4*)(nw + e), w1 = *(const float4*)(nw + e + 4);
  v[0] *= rstd * w0.x; v[1] *= rstd * w0.y; v[2] *= rstd * w0.z; v[3] *= rstd * w0.w;
  v[4] *= rstd * w1.x; v[5] *= rstd * w1.y; v[6] *= rstd * w1.z; v[7] *= rstd * w1.w;
  const int r = m & 127;
  const int tk = t >> 2;
  const int s = (t ^ (r >> 1)) & 3;
  uint4 pk;
  pk.x = bfpair(v[0], v[1]); pk.y = bfpair(v[2], v[3]);
  pk.z = bfpair(v[4], v[5]); pk.w = bfpair(v[6], v[7]);
  *(uint4*)(yP + (size_t)((m >> 7) * 64 + tk) * 4096 + r * 32 + s * 8) = pk;
}

extern "C" void kernel_launch(void* const* d_in, const int* in_sizes, int n_in,
                              void* d_out, int out_size, void* d_ws, size_t ws_size,
                              hipStream_t stream) {
  const float* hs      = (const float*)d_in[0];
  const float* W_in    = (const float*)d_in[1];
  const float* conv_w  = (const float*)d_in[2];
  const float* conv_b  = (const float*)d_in[3];
  const float* dt_bias = (const float*)d_in[4];
  const float* A_log   = (const float*)d_in[5];
  const float* D_param = (const float*)d_in[6];
  const float* norm_w  = (const float*)d_in[7];
  const float* W_out   = (const float*)d_in[8];
  float* out = (float*)d_out;

  // layout: fp32 region first, then bf16 buffers
  float* ws   = (float*)d_ws;
  float* xy   = ws;                                      // (2048, 2048) fp32: x after conv, y after ssd_out
  float* yI   = xy + (size_t)BB * LL * DINNER;           // (2048, 2048) fp32 y_intra
  float* Bm   = yI + (size_t)BB * LL * DINNER;           // (2048, 64)
  float* Cm   = Bm + (size_t)BB * LL * NS;               // (2048, 64)
  float* dtv  = Cm + (size_t)BB * LL * NS;               // (2048, 16)
  float* clog = dtv + (size_t)BB * LL * NH;              // (32, 1024)
  float* S    = clog + (size_t)BB * LL * NH;             // (512, 8192)
  ushort* zx    = (ushort*)(S + (size_t)512 * 8192);     // (2048, 4240) bf16 in-proj out
  ushort* hsP   = zx + (size_t)BB * LL * DINPROJ;        // 2048x1024 bf16 tiles
  ushort* WinP  = hsP + (size_t)2048 * 1024;             // 4224x1024 bf16 tiles
  ushort* WoutP = WinP + (size_t)4224 * 1024;            // 1024x2048 bf16 tiles
  ushort* yP    = WoutP + (size_t)1024 * 2048;           // 2048x2048 bf16 (128-row tiles)
  ushort* CpartB = yP + (size_t)2048 * 2048;             // 4 x 2048x1024 bf16

  const int M = BB * LL;

  prep_kernel<<<PREP_HS + PREP_WIN + M, 256, 0, stream>>>(
      hs, W_in, dt_bias, hsP, WinP, dtv);
  mfma_gemm_p16<<<dim3(33, 16, 1), 256, 0, stream>>>(hsP, WinP, zx, DINPROJ, 32, 32, 0);
  conv_cumlog<<<CONV_BLKS + 2, 256, 0, stream>>>(zx, conv_w, conv_b, xy, Bm, Cm, dtv, A_log, clog);
  ssd_intra<<<BB * NH * NCH, 256, 0, stream>>>(xy, Bm, Cm, dtv, clog, yI, S);
  ssd_scan<<<(BB * NH * HD * NS) / 256, 256, 0, stream>>>(S, clog);
  ssd_out<<<BB * NH * NCH, 256, 0, stream>>>(xy, yI, Cm, clog, S, D_param);
  gate_norm_pack<<<GN_ROWS + GN_WOUT, 256, 0, stream>>>(xy, zx, norm_w, W_out, yP, WoutP);
  mfma_gemm_p16<<<dim3(8, 16, 4), 256, 0, stream>>>(yP, WoutP, CpartB, DMODEL, 64, 16,
                                                    (size_t)DMODEL * BB * LL);
  reduce4b<<<(BB * LL * DMODEL) / 2048, 256, 0, stream>>>(CpartB, out);
}

// Round 15
// 143.017 us; speedup vs baseline: 1.1710x; 1.0335x over previous
//
#include <hip/hip_runtime.h>
#include <hip/hip_bf16.h>
#include <math.h>

#define BB 2
#define LL 1024
#define DMODEL 1024
#define DINNER 2048
#define NH 16
#define HD 128
#define NS 64
#define CONVDIM 2176
#define DINPROJ 4240
#define QC 64
#define NCH 16
#define LSTR 72   // LDS row stride in ushorts (144 B) -> conflict-free b128 frag reads

typedef short bf16x8 __attribute__((ext_vector_type(8)));
typedef float f32x4 __attribute__((ext_vector_type(4)));

__device__ __forceinline__ unsigned int bfpair(float lo, float hi) {
  unsigned int a = __float_as_uint(lo); a = (a + 0x7fffu + ((a >> 16) & 1u)) >> 16;
  unsigned int b = __float_as_uint(hi); b = (b + 0x7fffu + ((b >> 16) & 1u)) >> 16;
  return a | (b << 16);
}
__device__ __forceinline__ ushort bf1(float f) {
  unsigned int u = __float_as_uint(f);
  return (ushort)((u + 0x7fffu + ((u >> 16) & 1u)) >> 16);
}
__device__ __forceinline__ float bf2f(unsigned int u) {
  return __uint_as_float(u << 16);
}
__device__ __forceinline__ uint4 pack8(const float* v) {
  return make_uint4(bfpair(v[0], v[1]), bfpair(v[2], v[3]), bfpair(v[4], v[5]), bfpair(v[6], v[7]));
}

// ---- pack helper: fp32 [R][C] row-major -> bf16 tiles [128 rows][32 k], swizzled LDS image ----
__device__ __forceinline__ void pack_tiles(const float* __restrict__ src,
                                           ushort* __restrict__ dst,
                                           int id, int C) {
  const int KT = C >> 5;
  const int tile = id >> 9;
  const int g = id & 511;
  const int r = g >> 2, s = g & 3;
  const int h = (s ^ (r >> 1)) & 3;
  const int tm = tile / KT, tk = tile - tm * KT;
  const int row = tm * 128 + r;
  const int k = tk * 32 + h * 8;
  const float4 a = *(const float4*)(src + (size_t)row * C + k);
  const float4 b = *(const float4*)(src + (size_t)row * C + k + 4);
  uint4 pk;
  pk.x = bfpair(a.x, a.y); pk.y = bfpair(a.z, a.w);
  pk.z = bfpair(b.x, b.y); pk.w = bfpair(b.z, b.w);
  *(uint4*)(dst + (size_t)id * 8) = pk;
}

// ---- phase-1 prep: pack hs, W_in + dt GEMV, branched on blockIdx ----
#define PREP_HS 1024
#define PREP_WIN 2112
__global__ __launch_bounds__(256) void prep_kernel(const float* __restrict__ hs,
                                                   const float* __restrict__ W_in,
                                                   const float* __restrict__ dt_bias,
                                                   ushort* __restrict__ hsP,
                                                   ushort* __restrict__ WinP,
                                                   float* __restrict__ dtv) {
  __shared__ float hl[1024];
  __shared__ float part[256];
  const int blk = blockIdx.x;
  const int t = threadIdx.x;
  if (blk < PREP_HS) {
    pack_tiles(hs, hsP, blk * 256 + t, 1024);
  } else if (blk < PREP_HS + PREP_WIN) {
    pack_tiles(W_in, WinP, (blk - PREP_HS) * 256 + t, 1024);
  } else {
    const int bl = blk - (PREP_HS + PREP_WIN);
    *(float4*)(hl + t * 4) = *(const float4*)(hs + (size_t)bl * 1024 + t * 4);
    __syncthreads();
    const int h = t & 15, ks = t >> 4;
    const float* wrow = W_in + (size_t)(DINNER + CONVDIM + h) * 1024 + ks * 64;
    const float* xs = hl + ks * 64;
    float p = 0.f;
#pragma unroll
    for (int j = 0; j < 64; j += 4) {
      const float4 wv = *(const float4*)(wrow + j);
      const float4 xv = *(const float4*)(xs + j);
      p += wv.x * xv.x + wv.y * xv.y + wv.z * xv.z + wv.w * xv.w;
    }
    part[t] = p;
    __syncthreads();
    if (t < 16) {
      float sum = 0.f;
#pragma unroll
      for (int j = 0; j < 16; ++j) sum += part[t + 16 * j];
      const float x = sum + dt_bias[t];
      dtv[bl * 16 + t] = (x > 20.f) ? x : log1pf(expf(x));
    }
  }
}

// ---- bf16 MFMA GEMM, 128x128 tile, BK=32, bf16 output, optional split-K ----
__global__ __launch_bounds__(256) void mfma_gemm_p16(const ushort* __restrict__ Ap,
                                                     const ushort* __restrict__ Bp,
                                                     ushort* __restrict__ C,
                                                     int ldC, int KtTot, int Ktl,
                                                     size_t partStride) {
  __shared__ ushort lds[2][2][4096];
  const int tid = threadIdx.x;
  const int w = tid >> 6, lane = tid & 63;
  const int wr = w >> 1, wc = w & 1;
  const int l15 = lane & 15, lg = lane >> 4;
  const int bm = blockIdx.y * 128, bn = blockIdx.x * 128;
  const int kt0 = blockIdx.z * Ktl;
  const ushort* At = Ap + (size_t)blockIdx.y * KtTot * 4096 + (size_t)kt0 * 4096;
  const ushort* Bt = Bp + (size_t)blockIdx.x * KtTot * 4096 + (size_t)kt0 * 4096;
  ushort* Cz = C + (size_t)blockIdx.z * partStride;

  int offA[4], offB[4];
#pragma unroll
  for (int i = 0; i < 4; ++i) {
    const int r = wr * 64 + i * 16 + l15;
    offA[i] = r * 64 + (((lg ^ (r >> 1)) & 3) << 4);
    const int c = wc * 64 + i * 16 + l15;
    offB[i] = c * 64 + (((lg ^ (c >> 1)) & 3) << 4);
  }
  f32x4 acc[4][4] = {};

#define STAGE(buf, kt)                                                                   \
  do {                                                                                   \
    const char* ga_ = (const char*)(At + (size_t)(kt) * 4096);                           \
    const char* gb_ = (const char*)(Bt + (size_t)(kt) * 4096);                           \
    char* la_ = (char*)&lds[buf][0][0];                                                  \
    char* lb_ = (char*)&lds[buf][1][0];                                                  \
    _Pragma("unroll")                                                                    \
    for (int q = 0; q < 2; ++q) {                                                        \
      __builtin_amdgcn_global_load_lds(                                                  \
          (const __attribute__((address_space(1))) void*)(ga_ + q * 4096 + tid * 16),    \
          (__attribute__((address_space(3))) void*)(la_ + q * 4096 + (w << 10)), 16, 0, 0); \
      __builtin_amdgcn_global_load_lds(                                                  \
          (const __attribute__((address_space(1))) void*)(gb_ + q * 4096 + tid * 16),    \
          (__attribute__((address_space(3))) void*)(lb_ + q * 4096 + (w << 10)), 16, 0, 0); \
    }                                                                                    \
  } while (0)

  STAGE(0, 0);
  __syncthreads();
  int cur = 0;
  for (int kt = 0; kt < Ktl; ++kt) {
    if (kt + 1 < Ktl) STAGE(cur ^ 1, kt + 1);
    bf16x8 af[4], bfr[4];
#pragma unroll
    for (int i = 0; i < 4; ++i) af[i] = *(const bf16x8*)((const char*)&lds[cur][0][0] + offA[i]);
#pragma unroll
    for (int i = 0; i < 4; ++i) bfr[i] = *(const bf16x8*)((const char*)&lds[cur][1][0] + offB[i]);
#pragma unroll
    for (int mi = 0; mi < 4; ++mi)
#pragma unroll
      for (int ni = 0; ni < 4; ++ni)
        acc[mi][ni] = __builtin_amdgcn_mfma_f32_16x16x32_bf16(af[mi], bfr[ni], acc[mi][ni], 0, 0, 0);
    __syncthreads();
    cur ^= 1;
  }
#undef STAGE

#pragma unroll
  for (int mi = 0; mi < 4; ++mi) {
    const int row0 = bm + wr * 64 + mi * 16 + lg * 4;
#pragma unroll
    for (int ni = 0; ni < 4; ++ni) {
      const int col = bn + wc * 64 + ni * 16 + l15;
      ushort* cp = Cz + (size_t)row0 * ldC + col;
      cp[0] = bf1(acc[mi][ni][0]);
      cp[(size_t)ldC] = bf1(acc[mi][ni][1]);
      cp[(size_t)2 * ldC] = bf1(acc[mi][ni][2]);
      cp[(size_t)3 * ldC] = bf1(acc[mi][ni][3]);
    }
  }
}

// ---- sum 4 bf16 split-K partials -> fp32 out (8 elems/thread) ----
__global__ __launch_bounds__(256) void reduce4b(const ushort* __restrict__ P,
                                                float* __restrict__ out) {
  const size_t i = ((size_t)blockIdx.x * 256 + threadIdx.x) * 8;
  const size_t st = (size_t)DMODEL * BB * LL;
  float s[8] = {};
#pragma unroll
  for (int z = 0; z < 4; ++z) {
    const uint4 v = *(const uint4*)(P + z * st + i);
    s[0] += bf2f(v.x & 0xffffu); s[1] += bf2f(v.x >> 16);
    s[2] += bf2f(v.y & 0xffffu); s[3] += bf2f(v.y >> 16);
    s[4] += bf2f(v.z & 0xffffu); s[5] += bf2f(v.z >> 16);
    s[6] += bf2f(v.w & 0xffffu); s[7] += bf2f(v.w >> 16);
  }
  *(float4*)(out + i)     = make_float4(s[0], s[1], s[2], s[3]);
  *(float4*)(out + i + 4) = make_float4(s[4], s[5], s[6], s[7]);
}

// ---- causal depthwise conv(4)+SiLU over bf16 zx; x -> bf16 xyB (+ merged cumlog tail) ----
#define CONV_BLKS ((BB * LL * CONVDIM + 255) / 256)
__global__ __launch_bounds__(256) void conv_cumlog(const ushort* __restrict__ zx,
                                                   const float* __restrict__ conv_w,
                                                   const float* __restrict__ conv_b,
                                                   ushort* __restrict__ xyB,
                                                   float* __restrict__ Bm,
                                                   float* __restrict__ Cm,
                                                   const float* __restrict__ dtv,
                                                   const float* __restrict__ A_log,
                                                   float* __restrict__ clog) {
  const int blk = blockIdx.x;
  if (blk >= CONV_BLKS) {
    const int idx = (blk - CONV_BLKS) * 256 + threadIdx.x;
    if (idx >= BB * NH * NCH) return;
    const int c = idx & (NCH - 1);
    const int bh = idx >> 4;
    const int b = bh >> 4, h = bh & (NH - 1);
    const float A = -__expf(A_log[h]);
    float run = 0.f;
    for (int i = 0; i < QC; ++i) {
      run += A * dtv[(size_t)(b * LL + c * QC + i) * NH + h];
      clog[(size_t)bh * LL + c * QC + i] = run;
    }
    return;
  }
  const int idx = blk * 256 + threadIdx.x;
  const int c = idx % CONVDIM;
  const int bl = idx / CONVDIM;
  const int l = bl & (LL - 1);
  const float w0 = conv_w[c * 4 + 0], w1 = conv_w[c * 4 + 1];
  const float w2 = conv_w[c * 4 + 2], w3 = conv_w[c * 4 + 3];
  const ushort* base = zx + (size_t)bl * DINPROJ + DINNER + c;
  float acc = conv_b[c];
  acc = fmaf(bf2f(base[0]), w3, acc);
  if (l >= 1) acc = fmaf(bf2f(base[-1 * DINPROJ]), w2, acc);
  if (l >= 2) acc = fmaf(bf2f(base[-2 * DINPROJ]), w1, acc);
  if (l >= 3) acc = fmaf(bf2f(base[-3 * DINPROJ]), w0, acc);
  const float s = acc / (1.f + expf(-acc));
  if (c < DINNER)                    xyB[(size_t)bl * DINNER + c] = bf1(s);
  else if (c < DINNER + NS)          Bm[bl * NS + (c - DINNER)] = s;
  else                               Cm[bl * NS + (c - DINNER - NS)] = s;
}

// ---- SSD intra-chunk via bf16 MFMA; bf16 x in, bf16 y_intra out ----
__global__ __launch_bounds__(256) void ssd_intra(const ushort* __restrict__ xyB,
                                                 const float* __restrict__ Bm,
                                                 const float* __restrict__ Cm,
                                                 const float* __restrict__ dtv,
                                                 const float* __restrict__ clog,
                                                 ushort* __restrict__ yIB,
                                                 float* __restrict__ S) {
  __shared__ __align__(16) ushort sC[64 * LSTR];
  __shared__ __align__(16) ushort sB[64 * LSTR];
  __shared__ __align__(16) ushort sBT[64 * LSTR];
  __shared__ __align__(16) ushort sXT[128 * LSTR];
  __shared__ __align__(16) ushort sP[64 * LSTR];
  __shared__ float scl[QC], sdt[QC], swdt[QC];
  const int blk = blockIdx.x;
  const int bh = blk >> 4, c = blk & (NCH - 1);
  const int b = bh >> 4, h = bh & (NH - 1);
  const int t0 = c * QC;
  const int tid = threadIdx.x;
  const int w = tid >> 6, lane = tid & 63, l15 = lane & 15, lg = lane >> 4;

  if (tid < QC) {
    const float cl = clog[(size_t)bh * LL + t0 + tid];
    const float clend = clog[(size_t)bh * LL + t0 + QC - 1];
    const float dt = dtv[(size_t)(b * LL + t0 + tid) * NH + h];
    scl[tid] = cl; sdt[tid] = dt;
    swdt[tid] = __expf(clend - cl) * dt;
  }
  __syncthreads();

  const float* Bg = Bm + (size_t)(b * LL + t0) * NS;
  const float* Cg = Cm + (size_t)(b * LL + t0) * NS;
#pragma unroll
  for (int j = 0; j < 4; ++j) {
    const int f = j * 256 + tid;
    const int r = f >> 4, c4 = f & 15;
    const float4 bv = *(const float4*)(Bg + r * NS + c4 * 4);
    const float4 cv = *(const float4*)(Cg + r * NS + c4 * 4);
    *(uint2*)(sB + r * LSTR + c4 * 4) = make_uint2(bfpair(bv.x, bv.y), bfpair(bv.z, bv.w));
    *(uint2*)(sC + r * LSTR + c4 * 4) = make_uint2(bfpair(cv.x, cv.y), bfpair(cv.z, cv.w));
  }
  {
    const int n = tid & 63, sg = tid >> 6;
    float bw[16];
#pragma unroll
    for (int j = 0; j < 16; ++j) {
      const int s = sg * 16 + j;
      bw[j] = swdt[s] * Bg[(size_t)s * NS + n];
    }
    *(uint4*)(sBT + n * LSTR + sg * 16) = pack8(bw);
    *(uint4*)(sBT + n * LSTR + sg * 16 + 8) = pack8(bw + 8);
  }
  {
    const int p = tid & 127, sh = tid >> 7;
    const ushort* xg = xyB + (size_t)(b * LL + t0 + sh * 32) * DINNER + h * HD + p;
    ushort xv[32];
#pragma unroll
    for (int j = 0; j < 32; ++j) xv[j] = xg[(size_t)j * DINNER];
#pragma unroll
    for (int q = 0; q < 4; ++q) {
      uint4 pk;
      pk.x = (unsigned)xv[q * 8 + 0] | ((unsigned)xv[q * 8 + 1] << 16);
      pk.y = (unsigned)xv[q * 8 + 2] | ((unsigned)xv[q * 8 + 3] << 16);
      pk.z = (unsigned)xv[q * 8 + 4] | ((unsigned)xv[q * 8 + 5] << 16);
      pk.w = (unsigned)xv[q * 8 + 6] | ((unsigned)xv[q * 8 + 7] << 16);
      *(uint4*)(sXT + p * LSTR + sh * 32 + q * 8) = pk;
    }
  }
  __syncthreads();

  f32x4 g[4] = {};
#pragma unroll
  for (int ks = 0; ks < 2; ++ks) {
    const bf16x8 ca = *(const bf16x8*)((const char*)sC + (w * 16 + l15) * 144 + ks * 64 + lg * 16);
#pragma unroll
    for (int ni = 0; ni < 4; ++ni) {
      const bf16x8 bb = *(const bf16x8*)((const char*)sB + (ni * 16 + l15) * 144 + ks * 64 + lg * 16);
      g[ni] = __builtin_amdgcn_mfma_f32_16x16x32_bf16(ca, bb, g[ni], 0, 0, 0);
    }
  }
#pragma unroll
  for (int ni = 0; ni < 4; ++ni) {
    const int s = ni * 16 + l15;
    const float cls = scl[s], dts = sdt[s];
#pragma unroll
    for (int j = 0; j < 4; ++j) {
      const int t = w * 16 + lg * 4 + j;
      const float v = (s <= t) ? g[ni][j] * __expf(scl[t] - cls) * dts : 0.f;
      sP[t * LSTR + s] = bf1(v);
    }
  }
  f32x4 sa[2][4] = {};
#pragma unroll
  for (int ks = 0; ks < 2; ++ks) {
    const bf16x8 a0 = *(const bf16x8*)((const char*)sXT + (w * 32 + l15) * 144 + ks * 64 + lg * 16);
    const bf16x8 a1 = *(const bf16x8*)((const char*)sXT + (w * 32 + 16 + l15) * 144 + ks * 64 + lg * 16);
#pragma unroll
    for (int nj = 0; nj < 4; ++nj) {
      const bf16x8 bb = *(const bf16x8*)((const char*)sBT + (nj * 16 + l15) * 144 + ks * 64 + lg * 16);
      sa[0][nj] = __builtin_amdgcn_mfma_f32_16x16x32_bf16(a0, bb, sa[0][nj], 0, 0, 0);
      sa[1][nj] = __builtin_amdgcn_mfma_f32_16x16x32_bf16(a1, bb, sa[1][nj], 0, 0, 0);
    }
  }
  float* Sg = S + (size_t)blk * (HD * NS);
#pragma unroll
  for (int mi = 0; mi < 2; ++mi)
#pragma unroll
    for (int nj = 0; nj < 4; ++nj)
#pragma unroll
      for (int j = 0; j < 4; ++j)
        Sg[(size_t)(w * 32 + mi * 16 + lg * 4 + j) * NS + nj * 16 + l15] = sa[mi][nj][j];
  __syncthreads();

  f32x4 y[8] = {};
#pragma unroll
  for (int ks = 0; ks < 2; ++ks) {
    const bf16x8 pa = *(const bf16x8*)((const char*)sP + (w * 16 + l15) * 144 + ks * 64 + lg * 16);
#pragma unroll
    for (int ni = 0; ni < 8; ++ni) {
      const bf16x8 xb = *(const bf16x8*)((const char*)sXT + (ni * 16 + l15) * 144 + ks * 64 + lg * 16);
      y[ni] = __builtin_amdgcn_mfma_f32_16x16x32_bf16(pa, xb, y[ni], 0, 0, 0);
    }
  }
  ushort* yg = yIB + (size_t)(b * LL + t0) * DINNER + h * HD;
#pragma unroll
  for (int ni = 0; ni < 8; ++ni)
#pragma unroll
    for (int j = 0; j < 4; ++j)
      yg[(size_t)(w * 16 + lg * 4 + j) * DINNER + ni * 16 + l15] = bf1(y[ni][j]);
}

// ---- inter-chunk scan over chunk states ----
__global__ __launch_bounds__(256) void ssd_scan(float* __restrict__ S,
                                                const float* __restrict__ clog) {
  const int idx = blockIdx.x * 256 + threadIdx.x;
  const int pn = idx & (HD * NS - 1);
  const int bh = idx >> 13;
  float* Sp = S + (size_t)bh * NCH * (HD * NS) + pn;
  const float* cl = clog + (size_t)bh * LL;
  float H = 0.f;
#pragma unroll
  for (int c = 0; c < NCH; ++c) {
    const float dec = __expf(cl[c * QC + QC - 1]);
    const float s = Sp[(size_t)c * (HD * NS)];
    Sp[(size_t)c * (HD * NS)] = H;
    H = dec * H + s;
  }
}

// ---- y = yI + exp(cl)*C.H^T + D*x (bf16 MFMA); in-place bf16 on xyB ----
__global__ __launch_bounds__(256) void ssd_out(ushort* __restrict__ xyB,
                                               const ushort* __restrict__ yIB,
                                               const float* __restrict__ Cm,
                                               const float* __restrict__ clog,
                                               const float* __restrict__ S,
                                               const float* __restrict__ Dp_) {
  __shared__ __align__(16) ushort sC[64 * LSTR];
  __shared__ __align__(16) ushort sH[128 * LSTR];
  __shared__ float sE[QC];
  const int blk = blockIdx.x;
  const int bh = blk >> 4, c = blk & (NCH - 1);
  const int b = bh >> 4, h = bh & (NH - 1);
  const int t0 = c * QC;
  const int tid = threadIdx.x;
  const int w = tid >> 6, lane = tid & 63, l15 = lane & 15, lg = lane >> 4;

  if (tid < QC) sE[tid] = __expf(clog[(size_t)bh * LL + t0 + tid]);
  const float* Cg = Cm + (size_t)(b * LL + t0) * NS;
#pragma unroll
  for (int j = 0; j < 4; ++j) {
    const int f = j * 256 + tid, r = f >> 4, c4 = f & 15;
    const float4 cv = *(const float4*)(Cg + r * NS + c4 * 4);
    *(uint2*)(sC + r * LSTR + c4 * 4) = make_uint2(bfpair(cv.x, cv.y), bfpair(cv.z, cv.w));
  }
  const float* Hg = S + (size_t)blk * (HD * NS);
#pragma unroll
  for (int j = 0; j < 8; ++j) {
    const int f = j * 256 + tid, p = f >> 4, n4 = f & 15;
    const float4 hv = *(const float4*)(Hg + (size_t)p * NS + n4 * 4);
    *(uint2*)(sH + p * LSTR + n4 * 4) = make_uint2(bfpair(hv.x, hv.y), bfpair(hv.z, hv.w));
  }
  __syncthreads();

  f32x4 y2[8] = {};
#pragma unroll
  for (int ks = 0; ks < 2; ++ks) {
    const bf16x8 ca = *(const bf16x8*)((const char*)sC + (w * 16 + l15) * 144 + ks * 64 + lg * 16);
#pragma unroll
    for (int ni = 0; ni < 8; ++ni) {
      const bf16x8 hb = *(const bf16x8*)((const char*)sH + (ni * 16 + l15) * 144 + ks * 64 + lg * 16);
      y2[ni] = __builtin_amdgcn_mfma_f32_16x16x32_bf16(ca, hb, y2[ni], 0, 0, 0);
    }
  }
  const float Dv = Dp_[h];
#pragma unroll
  for (int ni = 0; ni < 8; ++ni) {
    const int p = ni * 16 + l15;
#pragma unroll
    for (int j = 0; j < 4; ++j) {
      const int t = w * 16 + lg * 4 + j;
      const size_t row = (size_t)(b * LL + t0 + t);
      const float yi = bf2f(yIB[row * DINNER + h * HD + p]);
      ushort* xp = xyB + row * DINNER + h * HD + p;
      const float xval = bf2f(*xp);
      *xp = bf1(yi + sE[t] * y2[ni][j] + Dv * xval);
    }
  }
}

// ---- y *= silu(z); RMSNorm; emit packed bf16 128-row tiles (+ tail blocks pack W_out) ----
#define GN_ROWS (BB * LL)
#define GN_WOUT 1024
__global__ __launch_bounds__(256) void gate_norm_pack(const ushort* __restrict__ xyB,
                                                      const ushort* __restrict__ zx,
                                                      const float* __restrict__ nw,
                                                      const float* __restrict__ W_out,
                                                      ushort* __restrict__ yP,
                                                      ushort* __restrict__ WoutP) {
  __shared__ float red[4];
  const int m = blockIdx.x;
  const int t = threadIdx.x;
  if (m >= GN_ROWS) {
    pack_tiles(W_out, WoutP, (m - GN_ROWS) * 256 + t, 2048);
    return;
  }
  const ushort* yrow = xyB + (size_t)m * DINNER;
  const ushort* zrow = zx + (size_t)m * DINPROJ;
  const int e = t * 8;
  const uint4 yv4 = *(const uint4*)(yrow + e);
  const uint4 zv = *(const uint4*)(zrow + e);
  float yv[8], z[8];
  yv[0] = bf2f(yv4.x & 0xffffu); yv[1] = bf2f(yv4.x >> 16);
  yv[2] = bf2f(yv4.y & 0xffffu); yv[3] = bf2f(yv4.y >> 16);
  yv[4] = bf2f(yv4.z & 0xffffu); yv[5] = bf2f(yv4.z >> 16);
  yv[6] = bf2f(yv4.w & 0xffffu); yv[7] = bf2f(yv4.w >> 16);
  z[0] = bf2f(zv.x & 0xffffu); z[1] = bf2f(zv.x >> 16);
  z[2] = bf2f(zv.y & 0xffffu); z[3] = bf2f(zv.y >> 16);
  z[4] = bf2f(zv.z & 0xffffu); z[5] = bf2f(zv.z >> 16);
  z[6] = bf2f(zv.w & 0xffffu); z[7] = bf2f(zv.w >> 16);
  float v[8];
#pragma unroll
  for (int j = 0; j < 8; ++j) v[j] = yv[j] * (z[j] / (1.f + __expf(-z[j])));
  float ss = 0.f;
#pragma unroll
  for (int j = 0; j < 8; ++j) ss += v[j] * v[j];
#pragma unroll
  for (int off = 32; off; off >>= 1) ss += __shfl_down(ss, off);
  const int lane = t & 63, wid = t >> 6;
  if (lane == 0) red[wid] = ss;
  __syncthreads();
  const float tot = red[0] + red[1] + red[2] + red[3];
  const float rstd = rsqrtf(tot * (1.f / DINNER) + 1e-5f);
  const float4 w0 = *(const float4*)(nw + e), w1 = *(const float4*)(nw + e + 4);
  v[0] *= rstd * w0.x; v[1] *= rstd * w0.y; v[2] *= rstd * w0.z; v[3] *= rstd * w0.w;
  v[4] *= rstd * w1.x; v[5] *= rstd * w1.y; v[6] *= rstd * w1.z; v[7] *= rstd * w1.w;
  const int r = m & 127;
  const int tk = t >> 2;
  const int s = (t ^ (r >> 1)) & 3;
  uint4 pk;
  pk.x = bfpair(v[0], v[1]); pk.y = bfpair(v[2], v[3]);
  pk.z = bfpair(v[4], v[5]); pk.w = bfpair(v[6], v[7]);
  *(uint4*)(yP + (size_t)((m >> 7) * 64 + tk) * 4096 + r * 32 + s * 8) = pk;
}

extern "C" void kernel_launch(void* const* d_in, const int* in_sizes, int n_in,
                              void* d_out, int out_size, void* d_ws, size_t ws_size,
                              hipStream_t stream) {
  const float* hs      = (const float*)d_in[0];
  const float* W_in    = (const float*)d_in[1];
  const float* conv_w  = (const float*)d_in[2];
  const float* conv_b  = (const float*)d_in[3];
  const float* dt_bias = (const float*)d_in[4];
  const float* A_log   = (const float*)d_in[5];
  const float* D_param = (const float*)d_in[6];
  const float* norm_w  = (const float*)d_in[7];
  const float* W_out   = (const float*)d_in[8];
  float* out = (float*)d_out;

  // fp32 region first, then bf16 buffers
  float* ws   = (float*)d_ws;
  float* Bm   = ws;                                      // (2048, 64)
  float* Cm   = Bm + (size_t)BB * LL * NS;               // (2048, 64)
  float* dtv  = Cm + (size_t)BB * LL * NS;               // (2048, 16)
  float* clog = dtv + (size_t)BB * LL * NH;              // (32, 1024)
  float* S    = clog + (size_t)BB * LL * NH;             // (512, 8192)
  ushort* zx    = (ushort*)(S + (size_t)512 * 8192);     // (2048, 4240) bf16 in-proj out
  ushort* xyB   = zx + (size_t)BB * LL * DINPROJ;        // (2048, 2048) bf16 x -> y
  ushort* yIB   = xyB + (size_t)BB * LL * DINNER;        // (2048, 2048) bf16 y_intra
  ushort* hsP   = yIB + (size_t)BB * LL * DINNER;        // 2048x1024 bf16 tiles
  ushort* WinP  = hsP + (size_t)2048 * 1024;             // 4224x1024 bf16 tiles
  ushort* WoutP = WinP + (size_t)4224 * 1024;            // 1024x2048 bf16 tiles
  ushort* yP    = WoutP + (size_t)1024 * 2048;           // 2048x2048 bf16 (128-row tiles)
  ushort* CpartB = yP + (size_t)2048 * 2048;             // 4 x 2048x1024 bf16

  const int M = BB * LL;

  prep_kernel<<<PREP_HS + PREP_WIN + M, 256, 0, stream>>>(
      hs, W_in, dt_bias, hsP, WinP, dtv);
  mfma_gemm_p16<<<dim3(33, 16, 1), 256, 0, stream>>>(hsP, WinP, zx, DINPROJ, 32, 32, 0);
  conv_cumlog<<<CONV_BLKS + 2, 256, 0, stream>>>(zx, conv_w, conv_b, xyB, Bm, Cm, dtv, A_log, clog);
  ssd_intra<<<BB * NH * NCH, 256, 0, stream>>>(xyB, Bm, Cm, dtv, clog, yIB, S);
  ssd_scan<<<(BB * NH * HD * NS) / 256, 256, 0, stream>>>(S, clog);
  ssd_out<<<BB * NH * NCH, 256, 0, stream>>>(xyB, yIB, Cm, clog, S, D_param);
  gate_norm_pack<<<GN_ROWS + GN_WOUT, 256, 0, stream>>>(xyB, zx, norm_w, W_out, yP, WoutP);
  mfma_gemm_p16<<<dim3(8, 16, 4), 256, 0, stream>>>(yP, WoutP, CpartB, DMODEL, 64, 16,
                                                    (size_t)DMODEL * BB * LL);
  reduce4b<<<(BB * LL * DMODEL) / 2048, 256, 0, stream>>>(CpartB, out);
}

// Round 16
// 139.668 us; speedup vs baseline: 1.1991x; 1.0240x over previous
//
#include <hip/hip_runtime.h>
#include <hip/hip_bf16.h>
#include <math.h>

#define BB 2
#define LL 1024
#define DMODEL 1024
#define DINNER 2048
#define NH 16
#define HD 128
#define NS 64
#define CONVDIM 2176
#define DINPROJ 4240
#define QC 64
#define NCH 16
#define LSTR 72   // LDS row stride in ushorts (144 B) -> conflict-free b128 frag reads

typedef short bf16x8 __attribute__((ext_vector_type(8)));
typedef float f32x4 __attribute__((ext_vector_type(4)));

__device__ __forceinline__ unsigned int bfpair(float lo, float hi) {
  unsigned int a = __float_as_uint(lo); a = (a + 0x7fffu + ((a >> 16) & 1u)) >> 16;
  unsigned int b = __float_as_uint(hi); b = (b + 0x7fffu + ((b >> 16) & 1u)) >> 16;
  return a | (b << 16);
}
__device__ __forceinline__ ushort bf1(float f) {
  unsigned int u = __float_as_uint(f);
  return (ushort)((u + 0x7fffu + ((u >> 16) & 1u)) >> 16);
}
__device__ __forceinline__ float bf2f(unsigned int u) {
  return __uint_as_float(u << 16);
}
__device__ __forceinline__ uint4 pack8(const float* v) {
  return make_uint4(bfpair(v[0], v[1]), bfpair(v[2], v[3]), bfpair(v[4], v[5]), bfpair(v[6], v[7]));
}

// ---- pack helper: fp32 [R][C] row-major -> bf16 tiles [128 rows][32 k], swizzled LDS image ----
__device__ __forceinline__ void pack_tiles(const float* __restrict__ src,
                                           ushort* __restrict__ dst,
                                           int id, int C) {
  const int KT = C >> 5;
  const int tile = id >> 9;
  const int g = id & 511;
  const int r = g >> 2, s = g & 3;
  const int h = (s ^ (r >> 1)) & 3;
  const int tm = tile / KT, tk = tile - tm * KT;
  const int row = tm * 128 + r;
  const int k = tk * 32 + h * 8;
  const float4 a = *(const float4*)(src + (size_t)row * C + k);
  const float4 b = *(const float4*)(src + (size_t)row * C + k + 4);
  uint4 pk;
  pk.x = bfpair(a.x, a.y); pk.y = bfpair(a.z, a.w);
  pk.z = bfpair(b.x, b.y); pk.w = bfpair(b.z, b.w);
  *(uint4*)(dst + (size_t)id * 8) = pk;
}

// ---- phase-1 prep: pack hs, W_in + dt GEMV, branched on blockIdx ----
#define PREP_HS 1024
#define PREP_WIN 2112
__global__ __launch_bounds__(256) void prep_kernel(const float* __restrict__ hs,
                                                   const float* __restrict__ W_in,
                                                   const float* __restrict__ dt_bias,
                                                   ushort* __restrict__ hsP,
                                                   ushort* __restrict__ WinP,
                                                   float* __restrict__ dtv) {
  __shared__ float hl[1024];
  __shared__ float part[256];
  const int blk = blockIdx.x;
  const int t = threadIdx.x;
  if (blk < PREP_HS) {
    pack_tiles(hs, hsP, blk * 256 + t, 1024);
  } else if (blk < PREP_HS + PREP_WIN) {
    pack_tiles(W_in, WinP, (blk - PREP_HS) * 256 + t, 1024);
  } else {
    const int bl = blk - (PREP_HS + PREP_WIN);
    *(float4*)(hl + t * 4) = *(const float4*)(hs + (size_t)bl * 1024 + t * 4);
    __syncthreads();
    const int h = t & 15, ks = t >> 4;
    const float* wrow = W_in + (size_t)(DINNER + CONVDIM + h) * 1024 + ks * 64;
    const float* xs = hl + ks * 64;
    float p = 0.f;
#pragma unroll
    for (int j = 0; j < 64; j += 4) {
      const float4 wv = *(const float4*)(wrow + j);
      const float4 xv = *(const float4*)(xs + j);
      p += wv.x * xv.x + wv.y * xv.y + wv.z * xv.z + wv.w * xv.w;
    }
    part[t] = p;
    __syncthreads();
    if (t < 16) {
      float sum = 0.f;
#pragma unroll
      for (int j = 0; j < 16; ++j) sum += part[t + 16 * j];
      const float x = sum + dt_bias[t];
      dtv[bl * 16 + t] = (x > 20.f) ? x : log1pf(expf(x));
    }
  }
}

// ---- bf16 MFMA GEMM, 128x128 tile, BK=32, bf16 output, optional split-K ----
__global__ __launch_bounds__(256) void mfma_gemm_p16(const ushort* __restrict__ Ap,
                                                     const ushort* __restrict__ Bp,
                                                     ushort* __restrict__ C,
                                                     int ldC, int KtTot, int Ktl,
                                                     size_t partStride) {
  __shared__ ushort lds[2][2][4096];
  const int tid = threadIdx.x;
  const int w = tid >> 6, lane = tid & 63;
  const int wr = w >> 1, wc = w & 1;
  const int l15 = lane & 15, lg = lane >> 4;
  const int bm = blockIdx.y * 128, bn = blockIdx.x * 128;
  const int kt0 = blockIdx.z * Ktl;
  const ushort* At = Ap + (size_t)blockIdx.y * KtTot * 4096 + (size_t)kt0 * 4096;
  const ushort* Bt = Bp + (size_t)blockIdx.x * KtTot * 4096 + (size_t)kt0 * 4096;
  ushort* Cz = C + (size_t)blockIdx.z * partStride;

  int offA[4], offB[4];
#pragma unroll
  for (int i = 0; i < 4; ++i) {
    const int r = wr * 64 + i * 16 + l15;
    offA[i] = r * 64 + (((lg ^ (r >> 1)) & 3) << 4);
    const int c = wc * 64 + i * 16 + l15;
    offB[i] = c * 64 + (((lg ^ (c >> 1)) & 3) << 4);
  }
  f32x4 acc[4][4] = {};

#define STAGE(buf, kt)                                                                   \
  do {                                                                                   \
    const char* ga_ = (const char*)(At + (size_t)(kt) * 4096);                           \
    const char* gb_ = (const char*)(Bt + (size_t)(kt) * 4096);                           \
    char* la_ = (char*)&lds[buf][0][0];                                                  \
    char* lb_ = (char*)&lds[buf][1][0];                                                  \
    _Pragma("unroll")                                                                    \
    for (int q = 0; q < 2; ++q) {                                                        \
      __builtin_amdgcn_global_load_lds(                                                  \
          (const __attribute__((address_space(1))) void*)(ga_ + q * 4096 + tid * 16),    \
          (__attribute__((address_space(3))) void*)(la_ + q * 4096 + (w << 10)), 16, 0, 0); \
      __builtin_amdgcn_global_load_lds(                                                  \
          (const __attribute__((address_space(1))) void*)(gb_ + q * 4096 + tid * 16),    \
          (__attribute__((address_space(3))) void*)(lb_ + q * 4096 + (w << 10)), 16, 0, 0); \
    }                                                                                    \
  } while (0)

  STAGE(0, 0);
  __syncthreads();
  int cur = 0;
  for (int kt = 0; kt < Ktl; ++kt) {
    if (kt + 1 < Ktl) STAGE(cur ^ 1, kt + 1);
    bf16x8 af[4], bfr[4];
#pragma unroll
    for (int i = 0; i < 4; ++i) af[i] = *(const bf16x8*)((const char*)&lds[cur][0][0] + offA[i]);
#pragma unroll
    for (int i = 0; i < 4; ++i) bfr[i] = *(const bf16x8*)((const char*)&lds[cur][1][0] + offB[i]);
#pragma unroll
    for (int mi = 0; mi < 4; ++mi)
#pragma unroll
      for (int ni = 0; ni < 4; ++ni)
        acc[mi][ni] = __builtin_amdgcn_mfma_f32_16x16x32_bf16(af[mi], bfr[ni], acc[mi][ni], 0, 0, 0);
    __syncthreads();
    cur ^= 1;
  }
#undef STAGE

#pragma unroll
  for (int mi = 0; mi < 4; ++mi) {
    const int row0 = bm + wr * 64 + mi * 16 + lg * 4;
#pragma unroll
    for (int ni = 0; ni < 4; ++ni) {
      const int col = bn + wc * 64 + ni * 16 + l15;
      ushort* cp = Cz + (size_t)row0 * ldC + col;
      cp[0] = bf1(acc[mi][ni][0]);
      cp[(size_t)ldC] = bf1(acc[mi][ni][1]);
      cp[(size_t)2 * ldC] = bf1(acc[mi][ni][2]);
      cp[(size_t)3 * ldC] = bf1(acc[mi][ni][3]);
    }
  }
}

// ---- sum 4 bf16 split-K partials -> fp32 out (8 elems/thread) ----
__global__ __launch_bounds__(256) void reduce4b(const ushort* __restrict__ P,
                                                float* __restrict__ out) {
  const size_t i = ((size_t)blockIdx.x * 256 + threadIdx.x) * 8;
  const size_t st = (size_t)DMODEL * BB * LL;
  float s[8] = {};
#pragma unroll
  for (int z = 0; z < 4; ++z) {
    const uint4 v = *(const uint4*)(P + z * st + i);
    s[0] += bf2f(v.x & 0xffffu); s[1] += bf2f(v.x >> 16);
    s[2] += bf2f(v.y & 0xffffu); s[3] += bf2f(v.y >> 16);
    s[4] += bf2f(v.z & 0xffffu); s[5] += bf2f(v.z >> 16);
    s[6] += bf2f(v.w & 0xffffu); s[7] += bf2f(v.w >> 16);
  }
  *(float4*)(out + i)     = make_float4(s[0], s[1], s[2], s[3]);
  *(float4*)(out + i + 4) = make_float4(s[4], s[5], s[6], s[7]);
}

// ---- causal depthwise conv(4)+SiLU over bf16 zx; x -> bf16 xyB (+ merged cumlog tail) ----
#define CONV_BLKS ((BB * LL * CONVDIM + 255) / 256)
__global__ __launch_bounds__(256) void conv_cumlog(const ushort* __restrict__ zx,
                                                   const float* __restrict__ conv_w,
                                                   const float* __restrict__ conv_b,
                                                   ushort* __restrict__ xyB,
                                                   float* __restrict__ Bm,
                                                   float* __restrict__ Cm,
                                                   const float* __restrict__ dtv,
                                                   const float* __restrict__ A_log,
                                                   float* __restrict__ clog) {
  const int blk = blockIdx.x;
  if (blk >= CONV_BLKS) {
    const int idx = (blk - CONV_BLKS) * 256 + threadIdx.x;
    if (idx >= BB * NH * NCH) return;
    const int c = idx & (NCH - 1);
    const int bh = idx >> 4;
    const int b = bh >> 4, h = bh & (NH - 1);
    const float A = -__expf(A_log[h]);
    float run = 0.f;
    for (int i = 0; i < QC; ++i) {
      run += A * dtv[(size_t)(b * LL + c * QC + i) * NH + h];
      clog[(size_t)bh * LL + c * QC + i] = run;
    }
    return;
  }
  const int idx = blk * 256 + threadIdx.x;
  const int c = idx % CONVDIM;
  const int bl = idx / CONVDIM;
  const int l = bl & (LL - 1);
  const float w0 = conv_w[c * 4 + 0], w1 = conv_w[c * 4 + 1];
  const float w2 = conv_w[c * 4 + 2], w3 = conv_w[c * 4 + 3];
  const ushort* base = zx + (size_t)bl * DINPROJ + DINNER + c;
  float acc = conv_b[c];
  acc = fmaf(bf2f(base[0]), w3, acc);
  if (l >= 1) acc = fmaf(bf2f(base[-1 * DINPROJ]), w2, acc);
  if (l >= 2) acc = fmaf(bf2f(base[-2 * DINPROJ]), w1, acc);
  if (l >= 3) acc = fmaf(bf2f(base[-3 * DINPROJ]), w0, acc);
  const float s = acc / (1.f + expf(-acc));
  if (c < DINNER)                    xyB[(size_t)bl * DINNER + c] = bf1(s);
  else if (c < DINNER + NS)          Bm[bl * NS + (c - DINNER)] = s;
  else                               Cm[bl * NS + (c - DINNER - NS)] = s;
}

// ---- SSD intra-chunk via bf16 MFMA; bf16 x in, bf16 y_intra + bf16 chunk-state out ----
__global__ __launch_bounds__(256) void ssd_intra(const ushort* __restrict__ xyB,
                                                 const float* __restrict__ Bm,
                                                 const float* __restrict__ Cm,
                                                 const float* __restrict__ dtv,
                                                 const float* __restrict__ clog,
                                                 ushort* __restrict__ yIB,
                                                 ushort* __restrict__ SB) {
  __shared__ __align__(16) ushort sC[64 * LSTR];
  __shared__ __align__(16) ushort sB[64 * LSTR];
  __shared__ __align__(16) ushort sBT[64 * LSTR];
  __shared__ __align__(16) ushort sXT[128 * LSTR];
  __shared__ __align__(16) ushort sP[64 * LSTR];
  __shared__ float scl[QC], sdt[QC], swdt[QC];
  const int blk = blockIdx.x;
  const int bh = blk >> 4, c = blk & (NCH - 1);
  const int b = bh >> 4, h = bh & (NH - 1);
  const int t0 = c * QC;
  const int tid = threadIdx.x;
  const int w = tid >> 6, lane = tid & 63, l15 = lane & 15, lg = lane >> 4;

  if (tid < QC) {
    const float cl = clog[(size_t)bh * LL + t0 + tid];
    const float clend = clog[(size_t)bh * LL + t0 + QC - 1];
    const float dt = dtv[(size_t)(b * LL + t0 + tid) * NH + h];
    scl[tid] = cl; sdt[tid] = dt;
    swdt[tid] = __expf(clend - cl) * dt;
  }
  __syncthreads();

  const float* Bg = Bm + (size_t)(b * LL + t0) * NS;
  const float* Cg = Cm + (size_t)(b * LL + t0) * NS;
#pragma unroll
  for (int j = 0; j < 4; ++j) {
    const int f = j * 256 + tid;
    const int r = f >> 4, c4 = f & 15;
    const float4 bv = *(const float4*)(Bg + r * NS + c4 * 4);
    const float4 cv = *(const float4*)(Cg + r * NS + c4 * 4);
    *(uint2*)(sB + r * LSTR + c4 * 4) = make_uint2(bfpair(bv.x, bv.y), bfpair(bv.z, bv.w));
    *(uint2*)(sC + r * LSTR + c4 * 4) = make_uint2(bfpair(cv.x, cv.y), bfpair(cv.z, cv.w));
  }
  {
    const int n = tid & 63, sg = tid >> 6;
    float bw[16];
#pragma unroll
    for (int j = 0; j < 16; ++j) {
      const int s = sg * 16 + j;
      bw[j] = swdt[s] * Bg[(size_t)s * NS + n];
    }
    *(uint4*)(sBT + n * LSTR + sg * 16) = pack8(bw);
    *(uint4*)(sBT + n * LSTR + sg * 16 + 8) = pack8(bw + 8);
  }
  {
    const int p = tid & 127, sh = tid >> 7;
    const ushort* xg = xyB + (size_t)(b * LL + t0 + sh * 32) * DINNER + h * HD + p;
    ushort xv[32];
#pragma unroll
    for (int j = 0; j < 32; ++j) xv[j] = xg[(size_t)j * DINNER];
#pragma unroll
    for (int q = 0; q < 4; ++q) {
      uint4 pk;
      pk.x = (unsigned)xv[q * 8 + 0] | ((unsigned)xv[q * 8 + 1] << 16);
      pk.y = (unsigned)xv[q * 8 + 2] | ((unsigned)xv[q * 8 + 3] << 16);
      pk.z = (unsigned)xv[q * 8 + 4] | ((unsigned)xv[q * 8 + 5] << 16);
      pk.w = (unsigned)xv[q * 8 + 6] | ((unsigned)xv[q * 8 + 7] << 16);
      *(uint4*)(sXT + p * LSTR + sh * 32 + q * 8) = pk;
    }
  }
  __syncthreads();

  f32x4 g[4] = {};
#pragma unroll
  for (int ks = 0; ks < 2; ++ks) {
    const bf16x8 ca = *(const bf16x8*)((const char*)sC + (w * 16 + l15) * 144 + ks * 64 + lg * 16);
#pragma unroll
    for (int ni = 0; ni < 4; ++ni) {
      const bf16x8 bb = *(const bf16x8*)((const char*)sB + (ni * 16 + l15) * 144 + ks * 64 + lg * 16);
      g[ni] = __builtin_amdgcn_mfma_f32_16x16x32_bf16(ca, bb, g[ni], 0, 0, 0);
    }
  }
#pragma unroll
  for (int ni = 0; ni < 4; ++ni) {
    const int s = ni * 16 + l15;
    const float cls = scl[s], dts = sdt[s];
#pragma unroll
    for (int j = 0; j < 4; ++j) {
      const int t = w * 16 + lg * 4 + j;
      const float v = (s <= t) ? g[ni][j] * __expf(scl[t] - cls) * dts : 0.f;
      sP[t * LSTR + s] = bf1(v);
    }
  }
  f32x4 sa[2][4] = {};
#pragma unroll
  for (int ks = 0; ks < 2; ++ks) {
    const bf16x8 a0 = *(const bf16x8*)((const char*)sXT + (w * 32 + l15) * 144 + ks * 64 + lg * 16);
    const bf16x8 a1 = *(const bf16x8*)((const char*)sXT + (w * 32 + 16 + l15) * 144 + ks * 64 + lg * 16);
#pragma unroll
    for (int nj = 0; nj < 4; ++nj) {
      const bf16x8 bb = *(const bf16x8*)((const char*)sBT + (nj * 16 + l15) * 144 + ks * 64 + lg * 16);
      sa[0][nj] = __builtin_amdgcn_mfma_f32_16x16x32_bf16(a0, bb, sa[0][nj], 0, 0, 0);
      sa[1][nj] = __builtin_amdgcn_mfma_f32_16x16x32_bf16(a1, bb, sa[1][nj], 0, 0, 0);
    }
  }
  ushort* Sg = SB + (size_t)blk * (HD * NS);
#pragma unroll
  for (int mi = 0; mi < 2; ++mi)
#pragma unroll
    for (int nj = 0; nj < 4; ++nj)
#pragma unroll
      for (int j = 0; j < 4; ++j)
        Sg[(size_t)(w * 32 + mi * 16 + lg * 4 + j) * NS + nj * 16 + l15] = bf1(sa[mi][nj][j]);
  __syncthreads();

  f32x4 y[8] = {};
#pragma unroll
  for (int ks = 0; ks < 2; ++ks) {
    const bf16x8 pa = *(const bf16x8*)((const char*)sP + (w * 16 + l15) * 144 + ks * 64 + lg * 16);
#pragma unroll
    for (int ni = 0; ni < 8; ++ni) {
      const bf16x8 xb = *(const bf16x8*)((const char*)sXT + (ni * 16 + l15) * 144 + ks * 64 + lg * 16);
      y[ni] = __builtin_amdgcn_mfma_f32_16x16x32_bf16(pa, xb, y[ni], 0, 0, 0);
    }
  }
  ushort* yg = yIB + (size_t)(b * LL + t0) * DINNER + h * HD;
#pragma unroll
  for (int ni = 0; ni < 8; ++ni)
#pragma unroll
    for (int j = 0; j < 4; ++j)
      yg[(size_t)(w * 16 + lg * 4 + j) * DINNER + ni * 16 + l15] = bf1(y[ni][j]);
}

// ---- inter-chunk scan over bf16 chunk states (fp32 accumulator in registers) ----
__global__ __launch_bounds__(256) void ssd_scan(ushort* __restrict__ SB,
                                                const float* __restrict__ clog) {
  const int idx = blockIdx.x * 256 + threadIdx.x;
  const int pn = idx & (HD * NS - 1);
  const int bh = idx >> 13;
  ushort* Sp = SB + (size_t)bh * NCH * (HD * NS) + pn;
  const float* cl = clog + (size_t)bh * LL;
  float H = 0.f;
#pragma unroll
  for (int c = 0; c < NCH; ++c) {
    const float dec = __expf(cl[c * QC + QC - 1]);
    const float s = bf2f(Sp[(size_t)c * (HD * NS)]);
    Sp[(size_t)c * (HD * NS)] = bf1(H);
    H = dec * H + s;
  }
}

// ---- y = yI + exp(cl)*C.H^T + D*x (bf16 MFMA); in-place bf16 on xyB ----
__global__ __launch_bounds__(256) void ssd_out(ushort* __restrict__ xyB,
                                               const ushort* __restrict__ yIB,
                                               const float* __restrict__ Cm,
                                               const float* __restrict__ clog,
                                               const ushort* __restrict__ SB,
                                               const float* __restrict__ Dp_) {
  __shared__ __align__(16) ushort sC[64 * LSTR];
  __shared__ __align__(16) ushort sH[128 * LSTR];
  __shared__ float sE[QC];
  const int blk = blockIdx.x;
  const int bh = blk >> 4, c = blk & (NCH - 1);
  const int b = bh >> 4, h = bh & (NH - 1);
  const int t0 = c * QC;
  const int tid = threadIdx.x;
  const int w = tid >> 6, lane = tid & 63, l15 = lane & 15, lg = lane >> 4;

  if (tid < QC) sE[tid] = __expf(clog[(size_t)bh * LL + t0 + tid]);
  const float* Cg = Cm + (size_t)(b * LL + t0) * NS;
#pragma unroll
  for (int j = 0; j < 4; ++j) {
    const int f = j * 256 + tid, r = f >> 4, c4 = f & 15;
    const float4 cv = *(const float4*)(Cg + r * NS + c4 * 4);
    *(uint2*)(sC + r * LSTR + c4 * 4) = make_uint2(bfpair(cv.x, cv.y), bfpair(cv.z, cv.w));
  }
  const ushort* Hg = SB + (size_t)blk * (HD * NS);
#pragma unroll
  for (int j = 0; j < 8; ++j) {
    const int f = j * 256 + tid, p = f >> 4, n4 = f & 15;
    const uint2 hv = *(const uint2*)(Hg + (size_t)p * NS + n4 * 4);
    *(uint2*)(sH + p * LSTR + n4 * 4) = hv;
  }
  __syncthreads();

  f32x4 y2[8] = {};
#pragma unroll
  for (int ks = 0; ks < 2; ++ks) {
    const bf16x8 ca = *(const bf16x8*)((const char*)sC + (w * 16 + l15) * 144 + ks * 64 + lg * 16);
#pragma unroll
    for (int ni = 0; ni < 8; ++ni) {
      const bf16x8 hb = *(const bf16x8*)((const char*)sH + (ni * 16 + l15) * 144 + ks * 64 + lg * 16);
      y2[ni] = __builtin_amdgcn_mfma_f32_16x16x32_bf16(ca, hb, y2[ni], 0, 0, 0);
    }
  }
  const float Dv = Dp_[h];
#pragma unroll
  for (int ni = 0; ni < 8; ++ni) {
    const int p = ni * 16 + l15;
#pragma unroll
    for (int j = 0; j < 4; ++j) {
      const int t = w * 16 + lg * 4 + j;
      const size_t row = (size_t)(b * LL + t0 + t);
      const float yi = bf2f(yIB[row * DINNER + h * HD + p]);
      ushort* xp = xyB + row * DINNER + h * HD + p;
      const float xval = bf2f(*xp);
      *xp = bf1(yi + sE[t] * y2[ni][j] + Dv * xval);
    }
  }
}

// ---- y *= silu(z); RMSNorm; emit packed bf16 128-row tiles (+ tail blocks pack W_out) ----
#define GN_ROWS (BB * LL)
#define GN_WOUT 1024
__global__ __launch_bounds__(256) void gate_norm_pack(const ushort* __restrict__ xyB,
                                                      const ushort* __restrict__ zx,
                                                      const float* __restrict__ nw,
                                                      const float* __restrict__ W_out,
                                                      ushort* __restrict__ yP,
                                                      ushort* __restrict__ WoutP) {
  __shared__ float red[4];
  const int m = blockIdx.x;
  const int t = threadIdx.x;
  if (m >= GN_ROWS) {
    pack_tiles(W_out, WoutP, (m - GN_ROWS) * 256 + t, 2048);
    return;
  }
  const ushort* yrow = xyB + (size_t)m * DINNER;
  const ushort* zrow = zx + (size_t)m * DINPROJ;
  const int e = t * 8;
  const uint4 yv4 = *(const uint4*)(yrow + e);
  const uint4 zv = *(const uint4*)(zrow + e);
  float yv[8], z[8];
  yv[0] = bf2f(yv4.x & 0xffffu); yv[1] = bf2f(yv4.x >> 16);
  yv[2] = bf2f(yv4.y & 0xffffu); yv[3] = bf2f(yv4.y >> 16);
  yv[4] = bf2f(yv4.z & 0xffffu); yv[5] = bf2f(yv4.z >> 16);
  yv[6] = bf2f(yv4.w & 0xffffu); yv[7] = bf2f(yv4.w >> 16);
  z[0] = bf2f(zv.x & 0xffffu); z[1] = bf2f(zv.x >> 16);
  z[2] = bf2f(zv.y & 0xffffu); z[3] = bf2f(zv.y >> 16);
  z[4] = bf2f(zv.z & 0xffffu); z[5] = bf2f(zv.z >> 16);
  z[6] = bf2f(zv.w & 0xffffu); z[7] = bf2f(zv.w >> 16);
  float v[8];
#pragma unroll
  for (int j = 0; j < 8; ++j) v[j] = yv[j] * (z[j] / (1.f + __expf(-z[j])));
  float ss = 0.f;
#pragma unroll
  for (int j = 0; j < 8; ++j) ss += v[j] * v[j];
#pragma unroll
  for (int off = 32; off; off >>= 1) ss += __shfl_down(ss, off);
  const int lane = t & 63, wid = t >> 6;
  if (lane == 0) red[wid] = ss;
  __syncthreads();
  const float tot = red[0] + red[1] + red[2] + red[3];
  const float rstd = rsqrtf(tot * (1.f / DINNER) + 1e-5f);
  const float4 w0 = *(const float4*)(nw + e), w1 = *(const float4*)(nw + e + 4);
  v[0] *= rstd * w0.x; v[1] *= rstd * w0.y; v[2] *= rstd * w0.z; v[3] *= rstd * w0.w;
  v[4] *= rstd * w1.x; v[5] *= rstd * w1.y; v[6] *= rstd * w1.z; v[7] *= rstd * w1.w;
  const int r = m & 127;
  const int tk = t >> 2;
  const int s = (t ^ (r >> 1)) & 3;
  uint4 pk;
  pk.x = bfpair(v[0], v[1]); pk.y = bfpair(v[2], v[3]);
  pk.z = bfpair(v[4], v[5]); pk.w = bfpair(v[6], v[7]);
  *(uint4*)(yP + (size_t)((m >> 7) * 64 + tk) * 4096 + r * 32 + s * 8) = pk;
}

extern "C" void kernel_launch(void* const* d_in, const int* in_sizes, int n_in,
                              void* d_out, int out_size, void* d_ws, size_t ws_size,
                              hipStream_t stream) {
  const float* hs      = (const float*)d_in[0];
  const float* W_in    = (const float*)d_in[1];
  const float* conv_w  = (const float*)d_in[2];
  const float* conv_b  = (const float*)d_in[3];
  const float* dt_bias = (const float*)d_in[4];
  const float* A_log   = (const float*)d_in[5];
  const float* D_param = (const float*)d_in[6];
  const float* norm_w  = (const float*)d_in[7];
  const float* W_out   = (const float*)d_in[8];
  float* out = (float*)d_out;

  // fp32 region first, then bf16 buffers
  float* ws   = (float*)d_ws;
  float* Bm   = ws;                                      // (2048, 64)
  float* Cm   = Bm + (size_t)BB * LL * NS;               // (2048, 64)
  float* dtv  = Cm + (size_t)BB * LL * NS;               // (2048, 16)
  float* clog = dtv + (size_t)BB * LL * NH;              // (32, 1024)
  ushort* SB    = (ushort*)(clog + (size_t)BB * LL * NH); // (512, 8192) bf16 chunk states
  ushort* zx    = SB + (size_t)512 * 8192;               // (2048, 4240) bf16 in-proj out
  ushort* xyB   = zx + (size_t)BB * LL * DINPROJ;        // (2048, 2048) bf16 x -> y
  ushort* yIB   = xyB + (size_t)BB * LL * DINNER;        // (2048, 2048) bf16 y_intra
  ushort* hsP   = yIB + (size_t)BB * LL * DINNER;        // 2048x1024 bf16 tiles
  ushort* WinP  = hsP + (size_t)2048 * 1024;             // 4224x1024 bf16 tiles
  ushort* WoutP = WinP + (size_t)4224 * 1024;            // 1024x2048 bf16 tiles
  ushort* yP    = WoutP + (size_t)1024 * 2048;           // 2048x2048 bf16 (128-row tiles)
  ushort* CpartB = yP + (size_t)2048 * 2048;             // 4 x 2048x1024 bf16

  const int M = BB * LL;

  prep_kernel<<<PREP_HS + PREP_WIN + M, 256, 0, stream>>>(
      hs, W_in, dt_bias, hsP, WinP, dtv);
  mfma_gemm_p16<<<dim3(33, 16, 1), 256, 0, stream>>>(hsP, WinP, zx, DINPROJ, 32, 32, 0);
  conv_cumlog<<<CONV_BLKS + 2, 256, 0, stream>>>(zx, conv_w, conv_b, xyB, Bm, Cm, dtv, A_log, clog);
  ssd_intra<<<BB * NH * NCH, 256, 0, stream>>>(xyB, Bm, Cm, dtv, clog, yIB, SB);
  ssd_scan<<<(BB * NH * HD * NS) / 256, 256, 0, stream>>>(SB, clog);
  ssd_out<<<BB * NH * NCH, 256, 0, stream>>>(xyB, yIB, Cm, clog, SB, D_param);
  gate_norm_pack<<<GN_ROWS + GN_WOUT, 256, 0, stream>>>(xyB, zx, norm_w, W_out, yP, WoutP);
  mfma_gemm_p16<<<dim3(8, 16, 4), 256, 0, stream>>>(yP, WoutP, CpartB, DMODEL, 64, 16,
                                                    (size_t)DMODEL * BB * LL);
  reduce4b<<<(BB * LL * DMODEL) / 2048, 256, 0, stream>>>(CpartB, out);
}

// Round 17
// 138.270 us; speedup vs baseline: 1.2112x; 1.0101x over previous
//
#include <hip/hip_runtime.h>
#include <hip/hip_bf16.h>
#include <math.h>

#define BB 2
#define LL 1024
#define DMODEL 1024
#define DINNER 2048
#define NH 16
#define HD 128
#define NS 64
#define CONVDIM 2176
#define DINPROJ 4240
#define QC 64
#define NCH 16
#define LSTR 72   // LDS row stride in ushorts (144 B) -> conflict-free b128 frag reads

typedef short bf16x8 __attribute__((ext_vector_type(8)));
typedef float f32x4 __attribute__((ext_vector_type(4)));

__device__ __forceinline__ unsigned int bfpair(float lo, float hi) {
  unsigned int a = __float_as_uint(lo); a = (a + 0x7fffu + ((a >> 16) & 1u)) >> 16;
  unsigned int b = __float_as_uint(hi); b = (b + 0x7fffu + ((b >> 16) & 1u)) >> 16;
  return a | (b << 16);
}
__device__ __forceinline__ ushort bf1(float f) {
  unsigned int u = __float_as_uint(f);
  return (ushort)((u + 0x7fffu + ((u >> 16) & 1u)) >> 16);
}
__device__ __forceinline__ float bf2f(unsigned int u) {
  return __uint_as_float(u << 16);
}
__device__ __forceinline__ uint4 pack8(const float* v) {
  return make_uint4(bfpair(v[0], v[1]), bfpair(v[2], v[3]), bfpair(v[4], v[5]), bfpair(v[6], v[7]));
}

// ---- pack helper: fp32 [R][C] row-major -> bf16 tiles [128 rows][32 k], swizzled LDS image ----
__device__ __forceinline__ void pack_tiles(const float* __restrict__ src,
                                           ushort* __restrict__ dst,
                                           int id, int C) {
  const int KT = C >> 5;
  const int tile = id >> 9;
  const int g = id & 511;
  const int r = g >> 2, s = g & 3;
  const int h = (s ^ (r >> 1)) & 3;
  const int tm = tile / KT, tk = tile - tm * KT;
  const int row = tm * 128 + r;
  const int k = tk * 32 + h * 8;
  const float4 a = *(const float4*)(src + (size_t)row * C + k);
  const float4 b = *(const float4*)(src + (size_t)row * C + k + 4);
  uint4 pk;
  pk.x = bfpair(a.x, a.y); pk.y = bfpair(a.z, a.w);
  pk.z = bfpair(b.x, b.y); pk.w = bfpair(b.z, b.w);
  *(uint4*)(dst + (size_t)id * 8) = pk;
}

// ---- phase-1 prep: pack hs, W_in + dt GEMV, branched on blockIdx ----
#define PREP_HS 1024
#define PREP_WIN 2112
__global__ __launch_bounds__(256) void prep_kernel(const float* __restrict__ hs,
                                                   const float* __restrict__ W_in,
                                                   const float* __restrict__ dt_bias,
                                                   ushort* __restrict__ hsP,
                                                   ushort* __restrict__ WinP,
                                                   float* __restrict__ dtv) {
  __shared__ float hl[1024];
  __shared__ float part[256];
  const int blk = blockIdx.x;
  const int t = threadIdx.x;
  if (blk < PREP_HS) {
    pack_tiles(hs, hsP, blk * 256 + t, 1024);
  } else if (blk < PREP_HS + PREP_WIN) {
    pack_tiles(W_in, WinP, (blk - PREP_HS) * 256 + t, 1024);
  } else {
    const int bl = blk - (PREP_HS + PREP_WIN);
    *(float4*)(hl + t * 4) = *(const float4*)(hs + (size_t)bl * 1024 + t * 4);
    __syncthreads();
    const int h = t & 15, ks = t >> 4;
    const float* wrow = W_in + (size_t)(DINNER + CONVDIM + h) * 1024 + ks * 64;
    const float* xs = hl + ks * 64;
    float p = 0.f;
#pragma unroll
    for (int j = 0; j < 64; j += 4) {
      const float4 wv = *(const float4*)(wrow + j);
      const float4 xv = *(const float4*)(xs + j);
      p += wv.x * xv.x + wv.y * xv.y + wv.z * xv.z + wv.w * xv.w;
    }
    part[t] = p;
    __syncthreads();
    if (t < 16) {
      float sum = 0.f;
#pragma unroll
      for (int j = 0; j < 16; ++j) sum += part[t + 16 * j];
      const float x = sum + dt_bias[t];
      dtv[bl * 16 + t] = (x > 20.f) ? x : log1pf(expf(x));
    }
  }
}

// ---- bf16 MFMA GEMM, 128x128 tile, BK=32, bf16 output, optional split-K,
//      XCD-aware chunked block swizzle (grid.x*grid.y must be %8==0) ----
__global__ __launch_bounds__(256) void mfma_gemm_p16(const ushort* __restrict__ Ap,
                                                     const ushort* __restrict__ Bp,
                                                     ushort* __restrict__ C,
                                                     int ldC, int KtTot, int Ktl,
                                                     size_t partStride, int gx) {
  __shared__ ushort lds[2][2][4096];
  const int tid = threadIdx.x;
  const int w = tid >> 6, lane = tid & 63;
  const int wr = w >> 1, wc = w & 1;
  const int l15 = lane & 15, lg = lane >> 4;
  // chunked XCD swizzle: orig linear id -> (xcd = id%8) gets contiguous chunk
  const int nwg = gx * gridDim.y;
  const int lin = blockIdx.y * gx + blockIdx.x;
  const int cpx = nwg >> 3;                       // blocks per XCD (nwg % 8 == 0)
  const int swz = (lin & 7) * cpx + (lin >> 3);
  const int bx = swz % gx, by = swz / gx;
  const int bm = by * 128, bn = bx * 128;
  const int kt0 = blockIdx.z * Ktl;
  const ushort* At = Ap + (size_t)by * KtTot * 4096 + (size_t)kt0 * 4096;
  const ushort* Bt = Bp + (size_t)bx * KtTot * 4096 + (size_t)kt0 * 4096;
  ushort* Cz = C + (size_t)blockIdx.z * partStride;

  int offA[4], offB[4];
#pragma unroll
  for (int i = 0; i < 4; ++i) {
    const int r = wr * 64 + i * 16 + l15;
    offA[i] = r * 64 + (((lg ^ (r >> 1)) & 3) << 4);
    const int c = wc * 64 + i * 16 + l15;
    offB[i] = c * 64 + (((lg ^ (c >> 1)) & 3) << 4);
  }
  f32x4 acc[4][4] = {};

#define STAGE(buf, kt)                                                                   \
  do {                                                                                   \
    const char* ga_ = (const char*)(At + (size_t)(kt) * 4096);                           \
    const char* gb_ = (const char*)(Bt + (size_t)(kt) * 4096);                           \
    char* la_ = (char*)&lds[buf][0][0];                                                  \
    char* lb_ = (char*)&lds[buf][1][0];                                                  \
    _Pragma("unroll")                                                                    \
    for (int q = 0; q < 2; ++q) {                                                        \
      __builtin_amdgcn_global_load_lds(                                                  \
          (const __attribute__((address_space(1))) void*)(ga_ + q * 4096 + tid * 16),    \
          (__attribute__((address_space(3))) void*)(la_ + q * 4096 + (w << 10)), 16, 0, 0); \
      __builtin_amdgcn_global_load_lds(                                                  \
          (const __attribute__((address_space(1))) void*)(gb_ + q * 4096 + tid * 16),    \
          (__attribute__((address_space(3))) void*)(lb_ + q * 4096 + (w << 10)), 16, 0, 0); \
    }                                                                                    \
  } while (0)

  STAGE(0, 0);
  __syncthreads();
  int cur = 0;
  for (int kt = 0; kt < Ktl; ++kt) {
    if (kt + 1 < Ktl) STAGE(cur ^ 1, kt + 1);
    bf16x8 af[4], bfr[4];
#pragma unroll
    for (int i = 0; i < 4; ++i) af[i] = *(const bf16x8*)((const char*)&lds[cur][0][0] + offA[i]);
#pragma unroll
    for (int i = 0; i < 4; ++i) bfr[i] = *(const bf16x8*)((const char*)&lds[cur][1][0] + offB[i]);
#pragma unroll
    for (int mi = 0; mi < 4; ++mi)
#pragma unroll
      for (int ni = 0; ni < 4; ++ni)
        acc[mi][ni] = __builtin_amdgcn_mfma_f32_16x16x32_bf16(af[mi], bfr[ni], acc[mi][ni], 0, 0, 0);
    __syncthreads();
    cur ^= 1;
  }
#undef STAGE

#pragma unroll
  for (int mi = 0; mi < 4; ++mi) {
    const int row0 = bm + wr * 64 + mi * 16 + lg * 4;
#pragma unroll
    for (int ni = 0; ni < 4; ++ni) {
      const int col = bn + wc * 64 + ni * 16 + l15;
      ushort* cp = Cz + (size_t)row0 * ldC + col;
      cp[0] = bf1(acc[mi][ni][0]);
      cp[(size_t)ldC] = bf1(acc[mi][ni][1]);
      cp[(size_t)2 * ldC] = bf1(acc[mi][ni][2]);
      cp[(size_t)3 * ldC] = bf1(acc[mi][ni][3]);
    }
  }
}

// ---- sum 4 bf16 split-K partials -> fp32 out (8 elems/thread) ----
__global__ __launch_bounds__(256) void reduce4b(const ushort* __restrict__ P,
                                                float* __restrict__ out) {
  const size_t i = ((size_t)blockIdx.x * 256 + threadIdx.x) * 8;
  const size_t st = (size_t)DMODEL * BB * LL;
  float s[8] = {};
#pragma unroll
  for (int z = 0; z < 4; ++z) {
    const uint4 v = *(const uint4*)(P + z * st + i);
    s[0] += bf2f(v.x & 0xffffu); s[1] += bf2f(v.x >> 16);
    s[2] += bf2f(v.y & 0xffffu); s[3] += bf2f(v.y >> 16);
    s[4] += bf2f(v.z & 0xffffu); s[5] += bf2f(v.z >> 16);
    s[6] += bf2f(v.w & 0xffffu); s[7] += bf2f(v.w >> 16);
  }
  *(float4*)(out + i)     = make_float4(s[0], s[1], s[2], s[3]);
  *(float4*)(out + i + 4) = make_float4(s[4], s[5], s[6], s[7]);
}

// ---- causal depthwise conv(4)+SiLU over bf16 zx; x -> bf16 xyB (+ merged cumlog tail) ----
#define CONV_BLKS ((BB * LL * CONVDIM + 255) / 256)
__global__ __launch_bounds__(256) void conv_cumlog(const ushort* __restrict__ zx,
                                                   const float* __restrict__ conv_w,
                                                   const float* __restrict__ conv_b,
                                                   ushort* __restrict__ xyB,
                                                   float* __restrict__ Bm,
                                                   float* __restrict__ Cm,
                                                   const float* __restrict__ dtv,
                                                   const float* __restrict__ A_log,
                                                   float* __restrict__ clog) {
  const int blk = blockIdx.x;
  if (blk >= CONV_BLKS) {
    const int idx = (blk - CONV_BLKS) * 256 + threadIdx.x;
    if (idx >= BB * NH * NCH) return;
    const int c = idx & (NCH - 1);
    const int bh = idx >> 4;
    const int b = bh >> 4, h = bh & (NH - 1);
    const float A = -__expf(A_log[h]);
    float run = 0.f;
    for (int i = 0; i < QC; ++i) {
      run += A * dtv[(size_t)(b * LL + c * QC + i) * NH + h];
      clog[(size_t)bh * LL + c * QC + i] = run;
    }
    return;
  }
  const int idx = blk * 256 + threadIdx.x;
  const int c = idx % CONVDIM;
  const int bl = idx / CONVDIM;
  const int l = bl & (LL - 1);
  const float w0 = conv_w[c * 4 + 0], w1 = conv_w[c * 4 + 1];
  const float w2 = conv_w[c * 4 + 2], w3 = conv_w[c * 4 + 3];
  const ushort* base = zx + (size_t)bl * DINPROJ + DINNER + c;
  float acc = conv_b[c];
  acc = fmaf(bf2f(base[0]), w3, acc);
  if (l >= 1) acc = fmaf(bf2f(base[-1 * DINPROJ]), w2, acc);
  if (l >= 2) acc = fmaf(bf2f(base[-2 * DINPROJ]), w1, acc);
  if (l >= 3) acc = fmaf(bf2f(base[-3 * DINPROJ]), w0, acc);
  const float s = acc / (1.f + expf(-acc));
  if (c < DINNER)                    xyB[(size_t)bl * DINNER + c] = bf1(s);
  else if (c < DINNER + NS)          Bm[bl * NS + (c - DINNER)] = s;
  else                               Cm[bl * NS + (c - DINNER - NS)] = s;
}

// ---- SSD intra-chunk via bf16 MFMA; bf16 x in, bf16 y_intra + bf16 chunk-state out ----
__global__ __launch_bounds__(256) void ssd_intra(const ushort* __restrict__ xyB,
                                                 const float* __restrict__ Bm,
                                                 const float* __restrict__ Cm,
                                                 const float* __restrict__ dtv,
                                                 const float* __restrict__ clog,
                                                 ushort* __restrict__ yIB,
                                                 ushort* __restrict__ SB) {
  __shared__ __align__(16) ushort sC[64 * LSTR];
  __shared__ __align__(16) ushort sB[64 * LSTR];
  __shared__ __align__(16) ushort sBT[64 * LSTR];
  __shared__ __align__(16) ushort sXT[128 * LSTR];
  __shared__ __align__(16) ushort sP[64 * LSTR];
  __shared__ float scl[QC], sdt[QC], swdt[QC];
  const int blk = blockIdx.x;
  const int bh = blk >> 4, c = blk & (NCH - 1);
  const int b = bh >> 4, h = bh & (NH - 1);
  const int t0 = c * QC;
  const int tid = threadIdx.x;
  const int w = tid >> 6, lane = tid & 63, l15 = lane & 15, lg = lane >> 4;

  if (tid < QC) {
    const float cl = clog[(size_t)bh * LL + t0 + tid];
    const float clend = clog[(size_t)bh * LL + t0 + QC - 1];
    const float dt = dtv[(size_t)(b * LL + t0 + tid) * NH + h];
    scl[tid] = cl; sdt[tid] = dt;
    swdt[tid] = __expf(clend - cl) * dt;
  }
  __syncthreads();

  const float* Bg = Bm + (size_t)(b * LL + t0) * NS;
  const float* Cg = Cm + (size_t)(b * LL + t0) * NS;
#pragma unroll
  for (int j = 0; j < 4; ++j) {
    const int f = j * 256 + tid;
    const int r = f >> 4, c4 = f & 15;
    const float4 bv = *(const float4*)(Bg + r * NS + c4 * 4);
    const float4 cv = *(const float4*)(Cg + r * NS + c4 * 4);
    *(uint2*)(sB + r * LSTR + c4 * 4) = make_uint2(bfpair(bv.x, bv.y), bfpair(bv.z, bv.w));
    *(uint2*)(sC + r * LSTR + c4 * 4) = make_uint2(bfpair(cv.x, cv.y), bfpair(cv.z, cv.w));
  }
  {
    const int n = tid & 63, sg = tid >> 6;
    float bw[16];
#pragma unroll
    for (int j = 0; j < 16; ++j) {
      const int s = sg * 16 + j;
      bw[j] = swdt[s] * Bg[(size_t)s * NS + n];
    }
    *(uint4*)(sBT + n * LSTR + sg * 16) = pack8(bw);
    *(uint4*)(sBT + n * LSTR + sg * 16 + 8) = pack8(bw + 8);
  }
  {
    const int p = tid & 127, sh = tid >> 7;
    const ushort* xg = xyB + (size_t)(b * LL + t0 + sh * 32) * DINNER + h * HD + p;
    ushort xv[32];
#pragma unroll
    for (int j = 0; j < 32; ++j) xv[j] = xg[(size_t)j * DINNER];
#pragma unroll
    for (int q = 0; q < 4; ++q) {
      uint4 pk;
      pk.x = (unsigned)xv[q * 8 + 0] | ((unsigned)xv[q * 8 + 1] << 16);
      pk.y = (unsigned)xv[q * 8 + 2] | ((unsigned)xv[q * 8 + 3] << 16);
      pk.z = (unsigned)xv[q * 8 + 4] | ((unsigned)xv[q * 8 + 5] << 16);
      pk.w = (unsigned)xv[q * 8 + 6] | ((unsigned)xv[q * 8 + 7] << 16);
      *(uint4*)(sXT + p * LSTR + sh * 32 + q * 8) = pk;
    }
  }
  __syncthreads();

  f32x4 g[4] = {};
#pragma unroll
  for (int ks = 0; ks < 2; ++ks) {
    const bf16x8 ca = *(const bf16x8*)((const char*)sC + (w * 16 + l15) * 144 + ks * 64 + lg * 16);
#pragma unroll
    for (int ni = 0; ni < 4; ++ni) {
      const bf16x8 bb = *(const bf16x8*)((const char*)sB + (ni * 16 + l15) * 144 + ks * 64 + lg * 16);
      g[ni] = __builtin_amdgcn_mfma_f32_16x16x32_bf16(ca, bb, g[ni], 0, 0, 0);
    }
  }
#pragma unroll
  for (int ni = 0; ni < 4; ++ni) {
    const int s = ni * 16 + l15;
    const float cls = scl[s], dts = sdt[s];
#pragma unroll
    for (int j = 0; j < 4; ++j) {
      const int t = w * 16 + lg * 4 + j;
      const float v = (s <= t) ? g[ni][j] * __expf(scl[t] - cls) * dts : 0.f;
      sP[t * LSTR + s] = bf1(v);
    }
  }
  f32x4 sa[2][4] = {};
#pragma unroll
  for (int ks = 0; ks < 2; ++ks) {
    const bf16x8 a0 = *(const bf16x8*)((const char*)sXT + (w * 32 + l15) * 144 + ks * 64 + lg * 16);
    const bf16x8 a1 = *(const bf16x8*)((const char*)sXT + (w * 32 + 16 + l15) * 144 + ks * 64 + lg * 16);
#pragma unroll
    for (int nj = 0; nj < 4; ++nj) {
      const bf16x8 bb = *(const bf16x8*)((const char*)sBT + (nj * 16 + l15) * 144 + ks * 64 + lg * 16);
      sa[0][nj] = __builtin_amdgcn_mfma_f32_16x16x32_bf16(a0, bb, sa[0][nj], 0, 0, 0);
      sa[1][nj] = __builtin_amdgcn_mfma_f32_16x16x32_bf16(a1, bb, sa[1][nj], 0, 0, 0);
    }
  }
  ushort* Sg = SB + (size_t)blk * (HD * NS);
#pragma unroll
  for (int mi = 0; mi < 2; ++mi)
#pragma unroll
    for (int nj = 0; nj < 4; ++nj)
#pragma unroll
      for (int j = 0; j < 4; ++j)
        Sg[(size_t)(w * 32 + mi * 16 + lg * 4 + j) * NS + nj * 16 + l15] = bf1(sa[mi][nj][j]);
  __syncthreads();

  f32x4 y[8] = {};
#pragma unroll
  for (int ks = 0; ks < 2; ++ks) {
    const bf16x8 pa = *(const bf16x8*)((const char*)sP + (w * 16 + l15) * 144 + ks * 64 + lg * 16);
#pragma unroll
    for (int ni = 0; ni < 8; ++ni) {
      const bf16x8 xb = *(const bf16x8*)((const char*)sXT + (ni * 16 + l15) * 144 + ks * 64 + lg * 16);
      y[ni] = __builtin_amdgcn_mfma_f32_16x16x32_bf16(pa, xb, y[ni], 0, 0, 0);
    }
  }
  ushort* yg = yIB + (size_t)(b * LL + t0) * DINNER + h * HD;
#pragma unroll
  for (int ni = 0; ni < 8; ++ni)
#pragma unroll
    for (int j = 0; j < 4; ++j)
      yg[(size_t)(w * 16 + lg * 4 + j) * DINNER + ni * 16 + l15] = bf1(y[ni][j]);
}

// ---- inter-chunk scan over bf16 chunk states (fp32 accumulator in registers) ----
__global__ __launch_bounds__(256) void ssd_scan(ushort* __restrict__ SB,
                                                const float* __restrict__ clog) {
  const int idx = blockIdx.x * 256 + threadIdx.x;
  const int pn = idx & (HD * NS - 1);
  const int bh = idx >> 13;
  ushort* Sp = SB + (size_t)bh * NCH * (HD * NS) + pn;
  const float* cl = clog + (size_t)bh * LL;
  float H = 0.f;
#pragma unroll
  for (int c = 0; c < NCH; ++c) {
    const float dec = __expf(cl[c * QC + QC - 1]);
    const float s = bf2f(Sp[(size_t)c * (HD * NS)]);
    Sp[(size_t)c * (HD * NS)] = bf1(H);
    H = dec * H + s;
  }
}

// ---- y = yI + exp(cl)*C.H^T + D*x (bf16 MFMA); in-place bf16 on xyB ----
__global__ __launch_bounds__(256) void ssd_out(ushort* __restrict__ xyB,
                                               const ushort* __restrict__ yIB,
                                               const float* __restrict__ Cm,
                                               const float* __restrict__ clog,
                                               const ushort* __restrict__ SB,
                                               const float* __restrict__ Dp_) {
  __shared__ __align__(16) ushort sC[64 * LSTR];
  __shared__ __align__(16) ushort sH[128 * LSTR];
  __shared__ float sE[QC];
  const int blk = blockIdx.x;
  const int bh = blk >> 4, c = blk & (NCH - 1);
  const int b = bh >> 4, h = bh & (NH - 1);
  const int t0 = c * QC;
  const int tid = threadIdx.x;
  const int w = tid >> 6, lane = tid & 63, l15 = lane & 15, lg = lane >> 4;

  if (tid < QC) sE[tid] = __expf(clog[(size_t)bh * LL + t0 + tid]);
  const float* Cg = Cm + (size_t)(b * LL + t0) * NS;
#pragma unroll
  for (int j = 0; j < 4; ++j) {
    const int f = j * 256 + tid, r = f >> 4, c4 = f & 15;
    const float4 cv = *(const float4*)(Cg + r * NS + c4 * 4);
    *(uint2*)(sC + r * LSTR + c4 * 4) = make_uint2(bfpair(cv.x, cv.y), bfpair(cv.z, cv.w));
  }
  const ushort* Hg = SB + (size_t)blk * (HD * NS);
#pragma unroll
  for (int j = 0; j < 8; ++j) {
    const int f = j * 256 + tid, p = f >> 4, n4 = f & 15;
    const uint2 hv = *(const uint2*)(Hg + (size_t)p * NS + n4 * 4);
    *(uint2*)(sH + p * LSTR + n4 * 4) = hv;
  }
  __syncthreads();

  f32x4 y2[8] = {};
#pragma unroll
  for (int ks = 0; ks < 2; ++ks) {
    const bf16x8 ca = *(const bf16x8*)((const char*)sC + (w * 16 + l15) * 144 + ks * 64 + lg * 16);
#pragma unroll
    for (int ni = 0; ni < 8; ++ni) {
      const bf16x8 hb = *(const bf16x8*)((const char*)sH + (ni * 16 + l15) * 144 + ks * 64 + lg * 16);
      y2[ni] = __builtin_amdgcn_mfma_f32_16x16x32_bf16(ca, hb, y2[ni], 0, 0, 0);
    }
  }
  const float Dv = Dp_[h];
#pragma unroll
  for (int ni = 0; ni < 8; ++ni) {
    const int p = ni * 16 + l15;
#pragma unroll
    for (int j = 0; j < 4; ++j) {
      const int t = w * 16 + lg * 4 + j;
      const size_t row = (size_t)(b * LL + t0 + t);
      const float yi = bf2f(yIB[row * DINNER + h * HD + p]);
      ushort* xp = xyB + row * DINNER + h * HD + p;
      const float xval = bf2f(*xp);
      *xp = bf1(yi + sE[t] * y2[ni][j] + Dv * xval);
    }
  }
}

// ---- y *= silu(z); RMSNorm; emit packed bf16 128-row tiles (+ tail blocks pack W_out) ----
#define GN_ROWS (BB * LL)
#define GN_WOUT 1024
__global__ __launch_bounds__(256) void gate_norm_pack(const ushort* __restrict__ xyB,
                                                      const ushort* __restrict__ zx,
                                                      const float* __restrict__ nw,
                                                      const float* __restrict__ W_out,
                                                      ushort* __restrict__ yP,
                                                      ushort* __restrict__ WoutP) {
  __shared__ float red[4];
  const int m = blockIdx.x;
  const int t = threadIdx.x;
  if (m >= GN_ROWS) {
    pack_tiles(W_out, WoutP, (m - GN_ROWS) * 256 + t, 2048);
    return;
  }
  const ushort* yrow = xyB + (size_t)m * DINNER;
  const ushort* zrow = zx + (size_t)m * DINPROJ;
  const int e = t * 8;
  const uint4 yv4 = *(const uint4*)(yrow + e);
  const uint4 zv = *(const uint4*)(zrow + e);
  float yv[8], z[8];
  yv[0] = bf2f(yv4.x & 0xffffu); yv[1] = bf2f(yv4.x >> 16);
  yv[2] = bf2f(yv4.y & 0xffffu); yv[3] = bf2f(yv4.y >> 16);
  yv[4] = bf2f(yv4.z & 0xffffu); yv[5] = bf2f(yv4.z >> 16);
  yv[6] = bf2f(yv4.w & 0xffffu); yv[7] = bf2f(yv4.w >> 16);
  z[0] = bf2f(zv.x & 0xffffu); z[1] = bf2f(zv.x >> 16);
  z[2] = bf2f(zv.y & 0xffffu); z[3] = bf2f(zv.y >> 16);
  z[4] = bf2f(zv.z & 0xffffu); z[5] = bf2f(zv.z >> 16);
  z[6] = bf2f(zv.w & 0xffffu); z[7] = bf2f(zv.w >> 16);
  float v[8];
#pragma unroll
  for (int j = 0; j < 8; ++j) v[j] = yv[j] * (z[j] / (1.f + __expf(-z[j])));
  float ss = 0.f;
#pragma unroll
  for (int j = 0; j < 8; ++j) ss += v[j] * v[j];
#pragma unroll
  for (int off = 32; off; off >>= 1) ss += __shfl_down(ss, off);
  const int lane = t & 63, wid = t >> 6;
  if (lane == 0) red[wid] = ss;
  __syncthreads();
  const float tot = red[0] + red[1] + red[2] + red[3];
  const float rstd = rsqrtf(tot * (1.f / DINNER) + 1e-5f);
  const float4 w0 = *(const float4*)(nw + e), w1 = *(const float4*)(nw + e + 4);
  v[0] *= rstd * w0.x; v[1] *= rstd * w0.y; v[2] *= rstd * w0.z; v[3] *= rstd * w0.w;
  v[4] *= rstd * w1.x; v[5] *= rstd * w1.y; v[6] *= rstd * w1.z; v[7] *= rstd * w1.w;
  const int r = m & 127;
  const int tk = t >> 2;
  const int s = (t ^ (r >> 1)) & 3;
  uint4 pk;
  pk.x = bfpair(v[0], v[1]); pk.y = bfpair(v[2], v[3]);
  pk.z = bfpair(v[4], v[5]); pk.w = bfpair(v[6], v[7]);
  *(uint4*)(yP + (size_t)((m >> 7) * 64 + tk) * 4096 + r * 32 + s * 8) = pk;
}

extern "C" void kernel_launch(void* const* d_in, const int* in_sizes, int n_in,
                              void* d_out, int out_size, void* d_ws, size_t ws_size,
                              hipStream_t stream) {
  const float* hs      = (const float*)d_in[0];
  const float* W_in    = (const float*)d_in[1];
  const float* conv_w  = (const float*)d_in[2];
  const float* conv_b  = (const float*)d_in[3];
  const float* dt_bias = (const float*)d_in[4];
  const float* A_log   = (const float*)d_in[5];
  const float* D_param = (const float*)d_in[6];
  const float* norm_w  = (const float*)d_in[7];
  const float* W_out   = (const float*)d_in[8];
  float* out = (float*)d_out;

  // fp32 region first, then bf16 buffers
  float* ws   = (float*)d_ws;
  float* Bm   = ws;                                      // (2048, 64)
  float* Cm   = Bm + (size_t)BB * LL * NS;               // (2048, 64)
  float* dtv  = Cm + (size_t)BB * LL * NS;               // (2048, 16)
  float* clog = dtv + (size_t)BB * LL * NH;              // (32, 1024)
  ushort* SB    = (ushort*)(clog + (size_t)BB * LL * NH); // (512, 8192) bf16 chunk states
  ushort* zx    = SB + (size_t)512 * 8192;               // (2048, 4240) bf16 in-proj out
  ushort* xyB   = zx + (size_t)BB * LL * DINPROJ;        // (2048, 2048) bf16 x -> y
  ushort* yIB   = xyB + (size_t)BB * LL * DINNER;        // (2048, 2048) bf16 y_intra
  ushort* hsP   = yIB + (size_t)BB * LL * DINNER;        // 2048x1024 bf16 tiles
  ushort* WinP  = hsP + (size_t)2048 * 1024;             // 4224x1024 bf16 tiles
  ushort* WoutP = WinP + (size_t)4224 * 1024;            // 1024x2048 bf16 tiles
  ushort* yP    = WoutP + (size_t)1024 * 2048;           // 2048x2048 bf16 (128-row tiles)
  ushort* CpartB = yP + (size_t)2048 * 2048;             // 4 x 2048x1024 bf16

  const int M = BB * LL;

  prep_kernel<<<PREP_HS + PREP_WIN + M, 256, 0, stream>>>(
      hs, W_in, dt_bias, hsP, WinP, dtv);
  mfma_gemm_p16<<<dim3(33, 16, 1), 256, 0, stream>>>(hsP, WinP, zx, DINPROJ, 32, 32, 0, 33);
  conv_cumlog<<<CONV_BLKS + 2, 256, 0, stream>>>(zx, conv_w, conv_b, xyB, Bm, Cm, dtv, A_log, clog);
  ssd_intra<<<BB * NH * NCH, 256, 0, stream>>>(xyB, Bm, Cm, dtv, clog, yIB, SB);
  ssd_scan<<<(BB * NH * HD * NS) / 256, 256, 0, stream>>>(SB, clog);
  ssd_out<<<BB * NH * NCH, 256, 0, stream>>>(xyB, yIB, Cm, clog, SB, D_param);
  gate_norm_pack<<<GN_ROWS + GN_WOUT, 256, 0, stream>>>(xyB, zx, norm_w, W_out, yP, WoutP);
  mfma_gemm_p16<<<dim3(8, 16, 4), 256, 0, stream>>>(yP, WoutP, CpartB, DMODEL, 64, 16,
                                                    (size_t)DMODEL * BB * LL, 8);
  reduce4b<<<(BB * LL * DMODEL) / 2048, 256, 0, stream>>>(CpartB, out);
}